// Round 1
// baseline (5939.244 us; speedup 1.0000x reference)
//
#include <hip/hip_runtime.h>

#define EPS 1e-5f

__device__ __forceinline__ float siluf(float x) { return x / (1.0f + __expf(-x)); }
__device__ __forceinline__ float geluf(float x) {
    float u = 0.7978845608028654f * (x + 0.044715f * x * x * x);
    return 0.5f * x * (1.0f + tanhf(u));
}

// ---------------- embedding + positional ----------------
__global__ void k_embed(const int* __restrict__ tok, const float* __restrict__ emb,
                        const float* __restrict__ pos, float* __restrict__ out) {
    int idx = blockIdx.x * 256 + threadIdx.x;   // 8192*512 total, exact
    int d  = idx & 511;
    int bl = idx >> 9;
    int l  = bl & 1023;
    out[idx] = emb[tok[bl] * 512 + d] + pos[l * 512 + d];
}

// ---------------- GEMM NT: C[m,n] = sum_k A[m,k]*B[n,k] ----------------
// MODE: 0 = plain store, 1 = +bias[n], 2 = C = (C + acc) * mask[m]
template <int MODE>
__global__ __launch_bounds__(256) void k_gemm_nt(
    const float* __restrict__ A, const float* __restrict__ B,
    const float* __restrict__ bias, float* __restrict__ C,
    const float* __restrict__ mask, int M, int N, int K) {
    __shared__ __align__(16) float As[16][132];
    __shared__ __align__(16) float Bs[16][132];
    const int m0 = blockIdx.y * 128;
    const int n0 = blockIdx.x * 128;
    const int t  = threadIdx.x;
    const int tn = t & 15, tm = t >> 4;
    const int lr = t >> 2, lc = (t & 3) << 2;

    float acc[8][8];
#pragma unroll
    for (int i = 0; i < 8; i++)
#pragma unroll
        for (int j = 0; j < 8; j++) acc[i][j] = 0.f;

    for (int k0 = 0; k0 < K; k0 += 16) {
#pragma unroll
        for (int half = 0; half < 2; ++half) {
            int r = lr + half * 64;
            float4 va = *(const float4*)(A + (size_t)(m0 + r) * K + (k0 + lc));
            As[lc + 0][r] = va.x; As[lc + 1][r] = va.y;
            As[lc + 2][r] = va.z; As[lc + 3][r] = va.w;
            int n = n0 + r;
            float4 vb = make_float4(0.f, 0.f, 0.f, 0.f);
            if (n < N) vb = *(const float4*)(B + (size_t)n * K + (k0 + lc));
            Bs[lc + 0][r] = vb.x; Bs[lc + 1][r] = vb.y;
            Bs[lc + 2][r] = vb.z; Bs[lc + 3][r] = vb.w;
        }
        __syncthreads();
#pragma unroll
        for (int k = 0; k < 16; ++k) {
            float a[8], b[8];
            *(float4*)&a[0] = *(const float4*)&As[k][tm * 8];
            *(float4*)&a[4] = *(const float4*)&As[k][tm * 8 + 4];
            *(float4*)&b[0] = *(const float4*)&Bs[k][tn * 8];
            *(float4*)&b[4] = *(const float4*)&Bs[k][tn * 8 + 4];
#pragma unroll
            for (int i = 0; i < 8; i++)
#pragma unroll
                for (int j = 0; j < 8; j++) acc[i][j] = fmaf(a[i], b[j], acc[i][j]);
        }
        __syncthreads();
    }

#pragma unroll
    for (int i = 0; i < 8; i++) {
        int m = m0 + tm * 8 + i;
        float mk = (MODE == 2) ? mask[m] : 0.f;
#pragma unroll
        for (int j = 0; j < 8; j++) {
            int n = n0 + tn * 8 + j;
            if (n < N) {
                float v = acc[i][j];
                if (MODE == 1) v += bias[n];
                size_t o = (size_t)m * N + n;
                if (MODE == 2) v = (C[o] + v) * mk;
                C[o] = v;
            }
        }
    }
}

// ---------------- LayerNorm (rows of 512) + mask, in place ----------------
__global__ __launch_bounds__(128) void k_layernorm(
    float* __restrict__ x, const float* __restrict__ g,
    const float* __restrict__ b, const float* __restrict__ mask) {
    __shared__ float2 sbuf[2];
    int bl = blockIdx.x;
    int t  = threadIdx.x;
    float4 v = *(float4*)(x + (size_t)bl * 512 + t * 4);
    float s = v.x + v.y + v.z + v.w;
    float q = v.x * v.x + v.y * v.y + v.z * v.z + v.w * v.w;
    for (int off = 32; off; off >>= 1) {
        s += __shfl_xor(s, off, 64);
        q += __shfl_xor(q, off, 64);
    }
    int wid = t >> 6, lane = t & 63;
    if (lane == 0) sbuf[wid] = make_float2(s, q);
    __syncthreads();
    float ts = sbuf[0].x + sbuf[1].x;
    float tq = sbuf[0].y + sbuf[1].y;
    float mu  = ts * (1.f / 512.f);
    float var = tq * (1.f / 512.f) - mu * mu;
    float inv = 1.0f / sqrtf(var + EPS);
    float mk  = mask[bl];
    float4 gg = *(const float4*)(g + t * 4);
    float4 bb = *(const float4*)(b + t * 4);
    float4 o;
    o.x = ((v.x - mu) * inv * gg.x + bb.x) * mk;
    o.y = ((v.y - mu) * inv * gg.y + bb.y) * mk;
    o.z = ((v.z - mu) * inv * gg.z + bb.z) * mk;
    o.w = ((v.w - mu) * inv * gg.w + bb.w) * mk;
    *(float4*)(x + (size_t)bl * 512 + t * 4) = o;
}

// ---------------- causal depthwise conv (k=4) + bias + SiLU ----------------
__global__ void k_conv(const float* __restrict__ zx, const float* __restrict__ cw,
                       const float* __restrict__ cb, float* __restrict__ xbc) {
    int idx = blockIdx.x * 256 + threadIdx.x;   // 8*1024*1280 total, exact
    int c  = idx % 1280;
    int l  = (idx / 1280) & 1023;
    int bl = idx / 1280;
    float acc = cb[c];
    const float* w = cw + c * 4;
#pragma unroll
    for (int k = 0; k < 4; k++) {
        int ll = l + k - 3;
        if (ll >= 0) acc += zx[(size_t)(bl + k - 3) * 2320 + 1024 + c] * w[k];
    }
    xbc[idx] = siluf(acc);
}

// ---------------- dt = softplus(raw + bias), dA = exp(dt * -exp(A_log)) ----------------
__global__ void k_dt(const float* __restrict__ zx, const float* __restrict__ dtb,
                     const float* __restrict__ alog, float* __restrict__ dt,
                     float* __restrict__ dA) {
    int idx = blockIdx.x * 256 + threadIdx.x;   // 8192*16, exact
    int h  = idx & 15;
    int bl = idx >> 4;
    float raw = zx[(size_t)bl * 2320 + 2304 + h] + dtb[h];
    float s = (raw > 20.f) ? raw : log1pf(__expf(raw));
    float A = -__expf(alog[h]);
    dt[idx] = s;
    dA[idx] = __expf(s * A);
}

// ---------------- SSM scan: block = (b,h), 512 thr, 16 states/thr ----------------
__global__ __launch_bounds__(512) void k_scan(
    const float* __restrict__ xbc, const float* __restrict__ dt,
    const float* __restrict__ dA, const float* __restrict__ Dp,
    float* __restrict__ y) {
    const int b = blockIdx.x >> 4;
    const int h = blockIdx.x & 15;
    const int t = threadIdx.x;
    const int p = t >> 3;
    const int g = t & 7;
    const int n0 = g * 16;
    const float* base = xbc + (size_t)b * 1024 * 1280;
    const float* dtp  = dt + (size_t)(b * 1024) * 16 + h;
    const float* dAp  = dA + (size_t)(b * 1024) * 16 + h;
    float* yout = y + (size_t)(b * 1024) * 1024 + h * 64 + p;
    const float Dv = Dp[h];

    float hs[16];
#pragma unroll
    for (int j = 0; j < 16; j++) hs[j] = 0.f;

    float Bv[16], Cv[16];
    {
        const float* row = base;
#pragma unroll
        for (int q = 0; q < 4; q++) {
            float4 tB = *(const float4*)(row + 1024 + n0 + q * 4);
            float4 tC = *(const float4*)(row + 1152 + n0 + q * 4);
            Bv[q * 4 + 0] = tB.x; Bv[q * 4 + 1] = tB.y; Bv[q * 4 + 2] = tB.z; Bv[q * 4 + 3] = tB.w;
            Cv[q * 4 + 0] = tC.x; Cv[q * 4 + 1] = tC.y; Cv[q * 4 + 2] = tC.z; Cv[q * 4 + 3] = tC.w;
        }
    }
    float xv  = base[h * 64 + p];
    float dtv = dtp[0], dAv = dAp[0];

    for (int l = 0; l < 1024; ++l) {
        float Bn[16], Cn[16];
        float xn = 0.f, dtn = 0.f, dAn = 0.f;
#pragma unroll
        for (int j = 0; j < 16; j++) { Bn[j] = 0.f; Cn[j] = 0.f; }
        if (l + 1 < 1024) {
            const float* r2 = base + (size_t)(l + 1) * 1280;
#pragma unroll
            for (int q = 0; q < 4; q++) {
                float4 tB = *(const float4*)(r2 + 1024 + n0 + q * 4);
                float4 tC = *(const float4*)(r2 + 1152 + n0 + q * 4);
                Bn[q * 4 + 0] = tB.x; Bn[q * 4 + 1] = tB.y; Bn[q * 4 + 2] = tB.z; Bn[q * 4 + 3] = tB.w;
                Cn[q * 4 + 0] = tC.x; Cn[q * 4 + 1] = tC.y; Cn[q * 4 + 2] = tC.z; Cn[q * 4 + 3] = tC.w;
            }
            xn  = r2[h * 64 + p];
            dtn = dtp[(size_t)(l + 1) * 16];
            dAn = dAp[(size_t)(l + 1) * 16];
        }

        float coef = dtv * xv;
        float accv = 0.f;
#pragma unroll
        for (int j = 0; j < 16; j++) {
            hs[j] = fmaf(hs[j], dAv, coef * Bv[j]);
            accv  = fmaf(hs[j], Cv[j], accv);
        }
        accv += __shfl_xor(accv, 1, 64);
        accv += __shfl_xor(accv, 2, 64);
        accv += __shfl_xor(accv, 4, 64);
        if (g == 0) yout[(size_t)l * 1024] = fmaf(Dv, xv, accv);

        xv = xn; dtv = dtn; dAv = dAn;
#pragma unroll
        for (int j = 0; j < 16; j++) { Bv[j] = Bn[j]; Cv[j] = Cn[j]; }
    }
}

// ---------------- gate: y = rmsnorm(y * silu(z)) * norm_w, in place ----------------
__global__ __launch_bounds__(256) void k_gate(
    float* __restrict__ y, const float* __restrict__ zx, const float* __restrict__ nw) {
    __shared__ float sbuf[4];
    int bl = blockIdx.x;
    int t  = threadIdx.x;
    float4 yv = *(float4*)(y + (size_t)bl * 1024 + t * 4);
    float4 zv = *(const float4*)(zx + (size_t)bl * 2320 + t * 4);
    float4 gv;
    gv.x = yv.x * siluf(zv.x);
    gv.y = yv.y * siluf(zv.y);
    gv.z = yv.z * siluf(zv.z);
    gv.w = yv.w * siluf(zv.w);
    float q = gv.x * gv.x + gv.y * gv.y + gv.z * gv.z + gv.w * gv.w;
    for (int off = 32; off; off >>= 1) q += __shfl_xor(q, off, 64);
    int wid = t >> 6, lane = t & 63;
    if (lane == 0) sbuf[wid] = q;
    __syncthreads();
    float tot = sbuf[0] + sbuf[1] + sbuf[2] + sbuf[3];
    float scale = 1.0f / sqrtf(tot * (1.f / 1024.f) + EPS);
    float4 nv = *(const float4*)(nw + t * 4);
    float4 o;
    o.x = gv.x * scale * nv.x;
    o.y = gv.y * scale * nv.y;
    o.z = gv.z * scale * nv.z;
    o.w = gv.w * scale * nv.w;
    *(float4*)(y + (size_t)bl * 1024 + t * 4) = o;
}

// ---------------- pool: 0.5*(mean_l + max_l) ----------------
__global__ __launch_bounds__(256) void k_pool(const float* __restrict__ x,
                                              float* __restrict__ pooled) {
    __shared__ float ss[256], sm[256];
    int b  = blockIdx.x >> 3;
    int d0 = (blockIdx.x & 7) * 64;
    int d   = threadIdx.x & 63;
    int seg = threadIdx.x >> 6;
    const float* px = x + (size_t)b * 1024 * 512 + d0 + d;
    float s = 0.f, mx = -3.0e38f;
    for (int l = seg * 256; l < (seg + 1) * 256; ++l) {
        float v = px[(size_t)l * 512];
        s += v;
        mx = fmaxf(mx, v);
    }
    ss[threadIdx.x] = s;
    sm[threadIdx.x] = mx;
    __syncthreads();
    if (threadIdx.x < 64) {
        float st = ss[d] + ss[64 + d] + ss[128 + d] + ss[192 + d];
        float mt = fmaxf(fmaxf(sm[d], sm[64 + d]), fmaxf(sm[128 + d], sm[192 + d]));
        pooled[b * 512 + d0 + d] = 0.5f * (st * (1.f / 1024.f) + mt);
    }
}

// ---------------- small FC: out[b,n] = act(bias[n] + dot(in[b,:], W[n,:])) ----------------
template <int ACT>
__global__ void k_fc(const float* __restrict__ in, const float* __restrict__ W,
                     const float* __restrict__ bias, float* __restrict__ out,
                     int BN, int N, int K) {
    int idx = blockIdx.x * 64 + threadIdx.x;
    if (idx >= BN) return;
    int b = idx / N, n = idx % N;
    const float* a = in + (size_t)b * K;
    const float* w = W + (size_t)n * K;
    float acc = 0.f;
    for (int k = 0; k < K; k += 4) {
        float4 av = *(const float4*)(a + k);
        float4 wv = *(const float4*)(w + k);
        acc += av.x * wv.x + av.y * wv.y + av.z * wv.z + av.w * wv.w;
    }
    float v = acc + bias[n];
    if (ACT == 1) v = geluf(v);
    out[idx] = v;
}

extern "C" void kernel_launch(void* const* d_in, const int* in_sizes, int n_in,
                              void* d_out, int out_size, void* d_ws, size_t ws_size,
                              hipStream_t stream) {
    (void)in_sizes; (void)n_in; (void)out_size; (void)ws_size;
    const int*   tok        = (const int*)  d_in[0];
    const float* mask       = (const float*)d_in[1];
    const float* emb        = (const float*)d_in[2];
    const float* pos        = (const float*)d_in[3];
    const float* inp_w      = (const float*)d_in[4];
    const float* inp_b      = (const float*)d_in[5];
    const float* ln_g       = (const float*)d_in[6];
    const float* ln_b       = (const float*)d_in[7];
    const float* in_proj_w  = (const float*)d_in[8];
    const float* conv_w     = (const float*)d_in[9];
    const float* conv_b     = (const float*)d_in[10];
    const float* dt_bias    = (const float*)d_in[11];
    const float* A_log      = (const float*)d_in[12];
    const float* Dparam     = (const float*)d_in[13];
    const float* norm_w     = (const float*)d_in[14];
    const float* out_proj_w = (const float*)d_in[15];
    const float* pooler_w   = (const float*)d_in[16];
    const float* pooler_b   = (const float*)d_in[17];
    const float* cls_w1     = (const float*)d_in[18];
    const float* cls_b1     = (const float*)d_in[19];
    const float* cls_w2     = (const float*)d_in[20];
    const float* cls_b2     = (const float*)d_in[21];
    float* out = (float*)d_out;

    float* ws     = (float*)d_ws;
    float* x      = ws;                                 // 8192*512
    float* xbuf   = x    + (size_t)8192 * 512;          // 8192*512
    float* zx     = xbuf + (size_t)8192 * 512;          // 8192*2320
    float* xbc    = zx   + (size_t)8192 * 2320;         // 8192*1280
    float* y      = xbc  + (size_t)8192 * 1280;         // 8192*1024
    float* dtb    = y    + (size_t)8192 * 1024;         // 131072
    float* dab    = dtb  + 131072;                      // 131072
    float* pooled = dab  + 131072;                      // 4096
    float* pbuf   = pooled + 4096;                      // 4096
    float* cbuf   = pbuf + 4096;                        // 2048

    // embedding + positional
    k_embed<<<16384, 256, 0, stream>>>(tok, emb, pos, xbuf);
    // x = xbuf @ inp_w^T + inp_b
    {
        dim3 g(4, 64);
        k_gemm_nt<1><<<g, 256, 0, stream>>>(xbuf, inp_w, inp_b, x, nullptr, 8192, 512, 512);
    }
    // LayerNorm + mask (in place)
    k_layernorm<<<8192, 128, 0, stream>>>(x, ln_g, ln_b, mask);

    for (int i = 0; i < 4; i++) {
        {   // zxbcdt = x @ in_proj_w[i]^T
            dim3 g(19, 64);
            k_gemm_nt<0><<<g, 256, 0, stream>>>(x, in_proj_w + (size_t)i * 2320 * 512,
                                                nullptr, zx, nullptr, 8192, 2320, 512);
        }
        k_conv<<<40960, 256, 0, stream>>>(zx, conv_w + (size_t)i * 1280 * 4,
                                          conv_b + (size_t)i * 1280, xbc);
        k_dt<<<512, 256, 0, stream>>>(zx, dt_bias + i * 16, A_log + i * 16, dtb, dab);
        k_scan<<<128, 512, 0, stream>>>(xbc, dtb, dab, Dparam + i * 16, y);
        k_gate<<<8192, 256, 0, stream>>>(y, zx, norm_w + (size_t)i * 1024);
        {   // x = (x + y @ out_proj_w[i]^T) * mask
            dim3 g(4, 64);
            k_gemm_nt<2><<<g, 256, 0, stream>>>(y, out_proj_w + (size_t)i * 512 * 1024,
                                                nullptr, x, mask, 8192, 512, 1024);
        }
    }

    k_pool<<<64, 256, 0, stream>>>(x, pooled);
    k_fc<1><<<64, 64, 0, stream>>>(pooled, pooler_w, pooler_b, pbuf, 8 * 512, 512, 512);
    k_fc<1><<<32, 64, 0, stream>>>(pbuf, cls_w1, cls_b1, cbuf, 8 * 256, 256, 512);
    k_fc<0><<<1, 64, 0, stream>>>(cbuf, cls_w2, cls_b2, out, 8 * 2, 2, 256);
}

// Round 2
// 2961.146 us; speedup vs baseline: 2.0057x; 2.0057x over previous
//
#include <hip/hip_runtime.h>

#define EPS 1e-5f

__device__ __forceinline__ float siluf(float x) { return x / (1.0f + __expf(-x)); }
__device__ __forceinline__ float geluf(float x) {
    float u = 0.7978845608028654f * (x + 0.044715f * x * x * x);
    return 0.5f * x * (1.0f + tanhf(u));
}

// ---------------- embedding + positional ----------------
__global__ void k_embed(const int* __restrict__ tok, const float* __restrict__ emb,
                        const float* __restrict__ pos, float* __restrict__ out) {
    int idx = blockIdx.x * 256 + threadIdx.x;   // 8192*512 total, exact
    int d  = idx & 511;
    int bl = idx >> 9;
    int l  = bl & 1023;
    out[idx] = emb[tok[bl] * 512 + d] + pos[l * 512 + d];
}

// ---------------- GEMM NT: C[m,n] = sum_k A[m,k]*B[n,k] ----------------
// MODE: 0 = plain store, 1 = +bias[n], 2 = C = (C + acc) * mask[m]
template <int MODE>
__global__ __launch_bounds__(256) void k_gemm_nt(
    const float* __restrict__ A, const float* __restrict__ B,
    const float* __restrict__ bias, float* __restrict__ C,
    const float* __restrict__ mask, int M, int N, int K) {
    __shared__ __align__(16) float As[16][132];
    __shared__ __align__(16) float Bs[16][132];
    const int m0 = blockIdx.y * 128;
    const int n0 = blockIdx.x * 128;
    const int t  = threadIdx.x;
    const int tn = t & 15, tm = t >> 4;
    const int lr = t >> 2, lc = (t & 3) << 2;

    float acc[8][8];
#pragma unroll
    for (int i = 0; i < 8; i++)
#pragma unroll
        for (int j = 0; j < 8; j++) acc[i][j] = 0.f;

    for (int k0 = 0; k0 < K; k0 += 16) {
#pragma unroll
        for (int half = 0; half < 2; ++half) {
            int r = lr + half * 64;
            float4 va = *(const float4*)(A + (size_t)(m0 + r) * K + (k0 + lc));
            As[lc + 0][r] = va.x; As[lc + 1][r] = va.y;
            As[lc + 2][r] = va.z; As[lc + 3][r] = va.w;
            int n = n0 + r;
            float4 vb = make_float4(0.f, 0.f, 0.f, 0.f);
            if (n < N) vb = *(const float4*)(B + (size_t)n * K + (k0 + lc));
            Bs[lc + 0][r] = vb.x; Bs[lc + 1][r] = vb.y;
            Bs[lc + 2][r] = vb.z; Bs[lc + 3][r] = vb.w;
        }
        __syncthreads();
#pragma unroll
        for (int k = 0; k < 16; ++k) {
            float a[8], b[8];
            *(float4*)&a[0] = *(const float4*)&As[k][tm * 8];
            *(float4*)&a[4] = *(const float4*)&As[k][tm * 8 + 4];
            *(float4*)&b[0] = *(const float4*)&Bs[k][tn * 8];
            *(float4*)&b[4] = *(const float4*)&Bs[k][tn * 8 + 4];
#pragma unroll
            for (int i = 0; i < 8; i++)
#pragma unroll
                for (int j = 0; j < 8; j++) acc[i][j] = fmaf(a[i], b[j], acc[i][j]);
        }
        __syncthreads();
    }

#pragma unroll
    for (int i = 0; i < 8; i++) {
        int m = m0 + tm * 8 + i;
        float mk = (MODE == 2) ? mask[m] : 0.f;
#pragma unroll
        for (int j = 0; j < 8; j++) {
            int n = n0 + tn * 8 + j;
            if (n < N) {
                float v = acc[i][j];
                if (MODE == 1) v += bias[n];
                size_t o = (size_t)m * N + n;
                if (MODE == 2) v = (C[o] + v) * mk;
                C[o] = v;
            }
        }
    }
}

// ---------------- LayerNorm (rows of 512) + mask, in place ----------------
__global__ __launch_bounds__(128) void k_layernorm(
    float* __restrict__ x, const float* __restrict__ g,
    const float* __restrict__ b, const float* __restrict__ mask) {
    __shared__ float2 sbuf[2];
    int bl = blockIdx.x;
    int t  = threadIdx.x;
    float4 v = *(float4*)(x + (size_t)bl * 512 + t * 4);
    float s = v.x + v.y + v.z + v.w;
    float q = v.x * v.x + v.y * v.y + v.z * v.z + v.w * v.w;
    for (int off = 32; off; off >>= 1) {
        s += __shfl_xor(s, off, 64);
        q += __shfl_xor(q, off, 64);
    }
    int wid = t >> 6, lane = t & 63;
    if (lane == 0) sbuf[wid] = make_float2(s, q);
    __syncthreads();
    float ts = sbuf[0].x + sbuf[1].x;
    float tq = sbuf[0].y + sbuf[1].y;
    float mu  = ts * (1.f / 512.f);
    float var = tq * (1.f / 512.f) - mu * mu;
    float inv = 1.0f / sqrtf(var + EPS);
    float mk  = mask[bl];
    float4 gg = *(const float4*)(g + t * 4);
    float4 bb = *(const float4*)(b + t * 4);
    float4 o;
    o.x = ((v.x - mu) * inv * gg.x + bb.x) * mk;
    o.y = ((v.y - mu) * inv * gg.y + bb.y) * mk;
    o.z = ((v.z - mu) * inv * gg.z + bb.z) * mk;
    o.w = ((v.w - mu) * inv * gg.w + bb.w) * mk;
    *(float4*)(x + (size_t)bl * 512 + t * 4) = o;
}

// ---------------- causal depthwise conv (k=4) + bias + SiLU ----------------
__global__ void k_conv(const float* __restrict__ zx, const float* __restrict__ cw,
                       const float* __restrict__ cb, float* __restrict__ xbc) {
    int idx = blockIdx.x * 256 + threadIdx.x;   // 8*1024*1280 total, exact
    int c  = idx % 1280;
    int l  = (idx / 1280) & 1023;
    int bl = idx / 1280;
    float acc = cb[c];
    const float* w = cw + c * 4;
#pragma unroll
    for (int k = 0; k < 4; k++) {
        int ll = l + k - 3;
        if (ll >= 0) acc += zx[(size_t)(bl + k - 3) * 2320 + 1024 + c] * w[k];
    }
    xbc[idx] = siluf(acc);
}

// ---------------- dt = softplus(raw + bias) ----------------
__global__ void k_dt(const float* __restrict__ zx, const float* __restrict__ dtbias,
                     float* __restrict__ dt) {
    int idx = blockIdx.x * 256 + threadIdx.x;   // 8192*16, exact
    int h  = idx & 15;
    int bl = idx >> 4;
    float raw = zx[(size_t)bl * 2320 + 2304 + h] + dtbias[h];
    float s = (raw > 20.f) ? raw : log1pf(__expf(raw));
    dt[idx] = s;
}

// ============ chunked SSD scan (Q=128, 8 chunks) ============
// cum[bhc*128 + l] = inclusive cumsum of dt*A within chunk
__global__ __launch_bounds__(128) void k_cum(const float* __restrict__ dtb,
                                             const float* __restrict__ alog,
                                             float* __restrict__ cum) {
    int bhc = blockIdx.x;                 // (b*16+h)*8+c
    int c = bhc & 7, h = (bhc >> 3) & 15, b = bhc >> 7;
    int l = threadIdx.x;
    float A = -__expf(alog[h]);
    float v = dtb[((size_t)(b * 1024 + c * 128 + l)) * 16 + h] * A;
    int lane = l & 63;
#pragma unroll
    for (int off = 1; off < 64; off <<= 1) {
        float o = __shfl_up(v, off, 64);
        if (lane >= off) v += o;
    }
    __shared__ float wsum;
    if (l == 63) wsum = v;
    __syncthreads();
    if (l >= 64) v += wsum;
    cum[(size_t)bhc * 128 + l] = v;
}

// G[b][c][l][j] = sum_n C[b,cQ+l,n]*B[b,cQ+j,n]  (shared across heads)
__global__ __launch_bounds__(256) void k_gmat(const float* __restrict__ xbc,
                                              float* __restrict__ G) {
    int bc = blockIdx.z;                   // b*8+c
    int b = bc >> 3, c = bc & 7;
    const float* base = xbc + ((size_t)b * 1024 + c * 128) * 1280;
    int l0 = blockIdx.y * 64, j0 = blockIdx.x * 64;
    __shared__ float Cs[16][68], Bsh[16][68];
    int t = threadIdx.x;
    int row = t >> 2, kk = (t & 3) * 4;
    int tl = t >> 4, tj = t & 15;
    float acc[4][4] = {};
    for (int k0 = 0; k0 < 128; k0 += 16) {
        float4 vc = *(const float4*)(base + (size_t)(l0 + row) * 1280 + 1152 + k0 + kk);
        float4 vb = *(const float4*)(base + (size_t)(j0 + row) * 1280 + 1024 + k0 + kk);
        Cs[kk + 0][row] = vc.x; Cs[kk + 1][row] = vc.y;
        Cs[kk + 2][row] = vc.z; Cs[kk + 3][row] = vc.w;
        Bsh[kk + 0][row] = vb.x; Bsh[kk + 1][row] = vb.y;
        Bsh[kk + 2][row] = vb.z; Bsh[kk + 3][row] = vb.w;
        __syncthreads();
#pragma unroll
        for (int k = 0; k < 16; k++) {
            float a[4], bb[4];
            *(float4*)&a[0]  = *(const float4*)&Cs[k][tl * 4];
            *(float4*)&bb[0] = *(const float4*)&Bsh[k][tj * 4];
#pragma unroll
            for (int i = 0; i < 4; i++)
#pragma unroll
                for (int j = 0; j < 4; j++) acc[i][j] = fmaf(a[i], bb[j], acc[i][j]);
        }
        __syncthreads();
    }
    float* g = G + (size_t)bc * 16384;
#pragma unroll
    for (int i = 0; i < 4; i++)
#pragma unroll
        for (int j = 0; j < 4; j++)
            g[(size_t)(l0 + tl * 4 + i) * 128 + j0 + tj * 4 + j] = acc[i][j];
}

// Sc overlay into zx's dead xBC region: flat f -> zx[(f>>10)*2320 + 1024 + (f&1023)]
__device__ __forceinline__ float* sc_addr(float* zx, size_t f) {
    return zx + (f >> 10) * 2320 + 1024 + (f & 1023);
}
__device__ __forceinline__ const float* sc_addr_c(const float* zx, size_t f) {
    return zx + (f >> 10) * 2320 + 1024 + (f & 1023);
}

// y_intra + chunk summary S_c
__global__ __launch_bounds__(256) void k_intra(
    const float* __restrict__ xbc, const float* __restrict__ dtb,
    const float* __restrict__ cum, const float* __restrict__ G,
    float* __restrict__ y, float* __restrict__ zx) {
    int bhc = blockIdx.x;                 // (b*16+h)*8+c
    int c = bhc & 7, h = (bhc >> 3) & 15, b = bhc >> 7;
    int t = threadIdx.x;
    const size_t row0 = (size_t)b * 1024 + c * 128;
    __shared__ float cl[128], wv[128], dtl[128];
    __shared__ __align__(16) float Us[128][68];
    __shared__ __align__(16) float Ms[16][132];
    __shared__ __align__(16) float Bs[16][132];

    if (t < 128) {
        cl[t]  = cum[(size_t)bhc * 128 + t];
        dtl[t] = dtb[(row0 + t) * 16 + h];
    }
    __syncthreads();
    if (t < 128) wv[t] = __expf(cl[127] - cl[t]);
#pragma unroll
    for (int rep = 0; rep < 8; rep++) {
        int j = (t >> 4) + rep * 16;
        int p = (t & 15) * 4;
        float4 xv = *(const float4*)(xbc + (row0 + j) * 1280 + h * 64 + p);
        float d = dtl[j];
        Us[j][p + 0] = xv.x * d; Us[j][p + 1] = xv.y * d;
        Us[j][p + 2] = xv.z * d; Us[j][p + 3] = xv.w * d;
    }
    __syncthreads();

    // GEMM1: y_intra[l][p] = sum_j mask*exp(cl[l]-cl[j])*G[l,j] * Us[j][p]
    int tl = t >> 4, tp = t & 15;
    float acc[8][4] = {};
    const float* g = G + (size_t)(b * 8 + c) * 16384;
    for (int j0 = 0; j0 < 128; j0 += 16) {
#pragma unroll
        for (int pass = 0; pass < 2; pass++) {
            int l = (t >> 2) + pass * 64;
            int j4 = (t & 3) * 4;
            float4 gv = *(const float4*)(g + (size_t)l * 128 + j0 + j4);
            float cll = cl[l];
            float gvv[4] = {gv.x, gv.y, gv.z, gv.w};
#pragma unroll
            for (int i = 0; i < 4; i++) {
                int j = j0 + j4 + i;
                Ms[j4 + i][l] = (j <= l) ? gvv[i] * __expf(cll - cl[j]) : 0.f;
            }
        }
        __syncthreads();
#pragma unroll
        for (int k = 0; k < 16; k++) {
            float a[8], bb[4];
            *(float4*)&a[0] = *(const float4*)&Ms[k][tl * 8];
            *(float4*)&a[4] = *(const float4*)&Ms[k][tl * 8 + 4];
            *(float4*)&bb[0] = *(const float4*)&Us[j0 + k][tp * 4];
#pragma unroll
            for (int i = 0; i < 8; i++)
#pragma unroll
                for (int jj = 0; jj < 4; jj++) acc[i][jj] = fmaf(a[i], bb[jj], acc[i][jj]);
        }
        __syncthreads();
    }
#pragma unroll
    for (int i = 0; i < 8; i++) {
        size_t yo = (row0 + tl * 8 + i) * 1024 + h * 64 + tp * 4;
#pragma unroll
        for (int jj = 0; jj < 4; jj++) y[yo + jj] = acc[i][jj];
    }

    // GEMM2: Sc[p][n] = sum_j wv[j]*Us[j][p] * B[j][n]
    float acc2[4][8] = {};
    for (int j0 = 0; j0 < 128; j0 += 16) {
        {
            int j = t >> 4;
            int n = (t & 15) * 8;
            const float* src = xbc + (row0 + j0 + j) * 1280 + 1024 + n;
            float4 v0 = *(const float4*)(src);
            float4 v1 = *(const float4*)(src + 4);
            Bs[j][n + 0] = v0.x; Bs[j][n + 1] = v0.y; Bs[j][n + 2] = v0.z; Bs[j][n + 3] = v0.w;
            Bs[j][n + 4] = v1.x; Bs[j][n + 5] = v1.y; Bs[j][n + 6] = v1.z; Bs[j][n + 7] = v1.w;
        }
        __syncthreads();
#pragma unroll
        for (int k = 0; k < 16; k++) {
            float w = wv[j0 + k];
            float a[4], bb[8];
            *(float4*)&a[0] = *(const float4*)&Us[j0 + k][tp * 4];
            *(float4*)&bb[0] = *(const float4*)&Bs[k][tl * 8];
            *(float4*)&bb[4] = *(const float4*)&Bs[k][tl * 8 + 4];
#pragma unroll
            for (int i = 0; i < 4; i++) {
                float aw = w * a[i];
#pragma unroll
                for (int jj = 0; jj < 8; jj++) acc2[i][jj] = fmaf(aw, bb[jj], acc2[i][jj]);
            }
        }
        __syncthreads();
    }
#pragma unroll
    for (int i = 0; i < 4; i++) {
        int p = tp * 4 + i;
        size_t f = (size_t)bhc * 8192 + (size_t)p * 128 + tl * 8;
        float* dst = sc_addr(zx, f);
#pragma unroll
        for (int jj = 0; jj < 8; jj++) dst[jj] = acc2[i][jj];
    }
}

// sequential chunk-state recurrence; Sc slots become h_start in place
__global__ __launch_bounds__(512) void k_states(float* __restrict__ zx,
                                                const float* __restrict__ cum) {
    int bh = blockIdx.x;                  // b*16+h
    int t = threadIdx.x;
    float4 h0 = {0, 0, 0, 0}, h1 = h0, h2 = h0, h3 = h0;
    size_t o = (size_t)t * 16;
    for (int c = 0; c < 8; c++) {
        int bhc = bh * 8 + c;
        float Tc = __expf(cum[(size_t)bhc * 128 + 127]);
        float* p = sc_addr(zx, (size_t)bhc * 8192 + o);
        float4 s0 = *(float4*)(p + 0), s1 = *(float4*)(p + 4);
        float4 s2 = *(float4*)(p + 8), s3 = *(float4*)(p + 12);
        *(float4*)(p + 0) = h0; *(float4*)(p + 4) = h1;
        *(float4*)(p + 8) = h2; *(float4*)(p + 12) = h3;
        h0.x = fmaf(Tc, h0.x, s0.x); h0.y = fmaf(Tc, h0.y, s0.y);
        h0.z = fmaf(Tc, h0.z, s0.z); h0.w = fmaf(Tc, h0.w, s0.w);
        h1.x = fmaf(Tc, h1.x, s1.x); h1.y = fmaf(Tc, h1.y, s1.y);
        h1.z = fmaf(Tc, h1.z, s1.z); h1.w = fmaf(Tc, h1.w, s1.w);
        h2.x = fmaf(Tc, h2.x, s2.x); h2.y = fmaf(Tc, h2.y, s2.y);
        h2.z = fmaf(Tc, h2.z, s2.z); h2.w = fmaf(Tc, h2.w, s2.w);
        h3.x = fmaf(Tc, h3.x, s3.x); h3.y = fmaf(Tc, h3.y, s3.y);
        h3.z = fmaf(Tc, h3.z, s3.z); h3.w = fmaf(Tc, h3.w, s3.w);
    }
}

// y[l,p] += exp(cum[l]) * (C[l]·h_start[p,:]) + D*x[l,p]
__global__ __launch_bounds__(256) void k_inter(
    const float* __restrict__ xbc, const float* __restrict__ cum,
    const float* __restrict__ zx, const float* __restrict__ Dp,
    float* __restrict__ y) {
    int bhc = blockIdx.x;
    int c = bhc & 7, h = (bhc >> 3) & 15, b = bhc >> 7;
    int t = threadIdx.x;
    __shared__ __align__(16) float Cs[16][132];
    __shared__ __align__(16) float Hs[16][68];
    __shared__ float el[128];
    if (t < 128) el[t] = __expf(cum[(size_t)bhc * 128 + t]);
    float Dv = Dp[h];
    const size_t row0 = (size_t)b * 1024 + c * 128;
    int tl = t >> 4, tp = t & 15;
    float acc[8][4] = {};
    for (int n0 = 0; n0 < 128; n0 += 16) {
#pragma unroll
        for (int pass = 0; pass < 2; pass++) {
            int l = (t >> 2) + pass * 64, nn = (t & 3) * 4;
            float4 v = *(const float4*)(xbc + (row0 + l) * 1280 + 1152 + n0 + nn);
            Cs[nn + 0][l] = v.x; Cs[nn + 1][l] = v.y;
            Cs[nn + 2][l] = v.z; Cs[nn + 3][l] = v.w;
        }
        {
            int p = t >> 2, nn = (t & 3) * 4;
            const float* src = sc_addr_c(zx, (size_t)bhc * 8192 + (size_t)p * 128 + n0 + nn);
            float4 v = *(const float4*)src;
            Hs[nn + 0][p] = v.x; Hs[nn + 1][p] = v.y;
            Hs[nn + 2][p] = v.z; Hs[nn + 3][p] = v.w;
        }
        __syncthreads();
#pragma unroll
        for (int k = 0; k < 16; k++) {
            float a[8], bb[4];
            *(float4*)&a[0] = *(const float4*)&Cs[k][tl * 8];
            *(float4*)&a[4] = *(const float4*)&Cs[k][tl * 8 + 4];
            *(float4*)&bb[0] = *(const float4*)&Hs[k][tp * 4];
#pragma unroll
            for (int i = 0; i < 8; i++)
#pragma unroll
                for (int jj = 0; jj < 4; jj++) acc[i][jj] = fmaf(a[i], bb[jj], acc[i][jj]);
        }
        __syncthreads();
    }
#pragma unroll
    for (int i = 0; i < 8; i++) {
        int l = tl * 8 + i;
        size_t yo = (row0 + l) * 1024 + h * 64 + tp * 4;
        const float* xr = xbc + (row0 + l) * 1280 + h * 64 + tp * 4;
        float e = el[l];
#pragma unroll
        for (int jj = 0; jj < 4; jj++)
            y[yo + jj] = y[yo + jj] + e * acc[i][jj] + Dv * xr[jj];
    }
}

// ---------------- gate: y = rmsnorm(y * silu(z)) * norm_w, in place ----------------
__global__ __launch_bounds__(256) void k_gate(
    float* __restrict__ y, const float* __restrict__ zx, const float* __restrict__ nw) {
    __shared__ float sbuf[4];
    int bl = blockIdx.x;
    int t  = threadIdx.x;
    float4 yv = *(float4*)(y + (size_t)bl * 1024 + t * 4);
    float4 zv = *(const float4*)(zx + (size_t)bl * 2320 + t * 4);
    float4 gv;
    gv.x = yv.x * siluf(zv.x);
    gv.y = yv.y * siluf(zv.y);
    gv.z = yv.z * siluf(zv.z);
    gv.w = yv.w * siluf(zv.w);
    float q = gv.x * gv.x + gv.y * gv.y + gv.z * gv.z + gv.w * gv.w;
    for (int off = 32; off; off >>= 1) q += __shfl_xor(q, off, 64);
    int wid = t >> 6, lane = t & 63;
    if (lane == 0) sbuf[wid] = q;
    __syncthreads();
    float tot = sbuf[0] + sbuf[1] + sbuf[2] + sbuf[3];
    float scale = 1.0f / sqrtf(tot * (1.f / 1024.f) + EPS);
    float4 nv = *(const float4*)(nw + t * 4);
    float4 o;
    o.x = gv.x * scale * nv.x;
    o.y = gv.y * scale * nv.y;
    o.z = gv.z * scale * nv.z;
    o.w = gv.w * scale * nv.w;
    *(float4*)(y + (size_t)bl * 1024 + t * 4) = o;
}

// ---------------- pool: 0.5*(mean_l + max_l) ----------------
__global__ __launch_bounds__(256) void k_pool(const float* __restrict__ x,
                                              float* __restrict__ pooled) {
    __shared__ float ss[256], sm[256];
    int b  = blockIdx.x >> 3;
    int d0 = (blockIdx.x & 7) * 64;
    int d   = threadIdx.x & 63;
    int seg = threadIdx.x >> 6;
    const float* px = x + (size_t)b * 1024 * 512 + d0 + d;
    float s = 0.f, mx = -3.0e38f;
    for (int l = seg * 256; l < (seg + 1) * 256; ++l) {
        float v = px[(size_t)l * 512];
        s += v;
        mx = fmaxf(mx, v);
    }
    ss[threadIdx.x] = s;
    sm[threadIdx.x] = mx;
    __syncthreads();
    if (threadIdx.x < 64) {
        float st = ss[d] + ss[64 + d] + ss[128 + d] + ss[192 + d];
        float mt = fmaxf(fmaxf(sm[d], sm[64 + d]), fmaxf(sm[128 + d], sm[192 + d]));
        pooled[b * 512 + d0 + d] = 0.5f * (st * (1.f / 1024.f) + mt);
    }
}

// ---------------- small FC ----------------
template <int ACT>
__global__ void k_fc(const float* __restrict__ in, const float* __restrict__ W,
                     const float* __restrict__ bias, float* __restrict__ out,
                     int BN, int N, int K) {
    int idx = blockIdx.x * 64 + threadIdx.x;
    if (idx >= BN) return;
    int b = idx / N, n = idx % N;
    const float* a = in + (size_t)b * K;
    const float* w = W + (size_t)n * K;
    float acc = 0.f;
    for (int k = 0; k < K; k += 4) {
        float4 av = *(const float4*)(a + k);
        float4 wv = *(const float4*)(w + k);
        acc += av.x * wv.x + av.y * wv.y + av.z * wv.z + av.w * wv.w;
    }
    float v = acc + bias[n];
    if (ACT == 1) v = geluf(v);
    out[idx] = v;
}

extern "C" void kernel_launch(void* const* d_in, const int* in_sizes, int n_in,
                              void* d_out, int out_size, void* d_ws, size_t ws_size,
                              hipStream_t stream) {
    (void)in_sizes; (void)n_in; (void)out_size; (void)ws_size;
    const int*   tok        = (const int*)  d_in[0];
    const float* mask       = (const float*)d_in[1];
    const float* emb        = (const float*)d_in[2];
    const float* pos        = (const float*)d_in[3];
    const float* inp_w      = (const float*)d_in[4];
    const float* inp_b      = (const float*)d_in[5];
    const float* ln_g       = (const float*)d_in[6];
    const float* ln_b       = (const float*)d_in[7];
    const float* in_proj_w  = (const float*)d_in[8];
    const float* conv_w     = (const float*)d_in[9];
    const float* conv_b     = (const float*)d_in[10];
    const float* dt_bias    = (const float*)d_in[11];
    const float* A_log      = (const float*)d_in[12];
    const float* Dparam     = (const float*)d_in[13];
    const float* norm_w     = (const float*)d_in[14];
    const float* out_proj_w = (const float*)d_in[15];
    const float* pooler_w   = (const float*)d_in[16];
    const float* pooler_b   = (const float*)d_in[17];
    const float* cls_w1     = (const float*)d_in[18];
    const float* cls_b1     = (const float*)d_in[19];
    const float* cls_w2     = (const float*)d_in[20];
    const float* cls_b2     = (const float*)d_in[21];
    float* out = (float*)d_out;

    float* ws     = (float*)d_ws;
    float* x      = ws;                                 // 8192*512
    float* xbuf   = x    + (size_t)8192 * 512;          // 8192*512 (prologue only)
    float* zx     = xbuf + (size_t)8192 * 512;          // 8192*2320
    float* xbc    = zx   + (size_t)8192 * 2320;         // 8192*1280
    float* y      = xbc  + (size_t)8192 * 1280;         // 8192*1024
    float* dtb    = y    + (size_t)8192 * 1024;         // 131072
    float* pooled = dtb  + 131072;                      // 4096
    float* pbuf   = pooled + 4096;                      // 4096
    float* cbuf   = pbuf + 4096;                        // 2048
    // xbuf is dead after the prologue: reuse for cum + G
    float* cum    = xbuf;                               // 8*16*8*128 = 131072
    float* G      = xbuf + 131072;                      // 8*8*128*128 = 1048576

    k_embed<<<16384, 256, 0, stream>>>(tok, emb, pos, xbuf);
    {
        dim3 g(4, 64);
        k_gemm_nt<1><<<g, 256, 0, stream>>>(xbuf, inp_w, inp_b, x, nullptr, 8192, 512, 512);
    }
    k_layernorm<<<8192, 128, 0, stream>>>(x, ln_g, ln_b, mask);

    for (int i = 0; i < 4; i++) {
        {
            dim3 g(19, 64);
            k_gemm_nt<0><<<g, 256, 0, stream>>>(x, in_proj_w + (size_t)i * 2320 * 512,
                                                nullptr, zx, nullptr, 8192, 2320, 512);
        }
        k_conv<<<40960, 256, 0, stream>>>(zx, conv_w + (size_t)i * 1280 * 4,
                                          conv_b + (size_t)i * 1280, xbc);
        k_dt<<<512, 256, 0, stream>>>(zx, dt_bias + i * 16, dtb);
        k_cum<<<1024, 128, 0, stream>>>(dtb, A_log + i * 16, cum);
        {
            dim3 g(2, 2, 64);
            k_gmat<<<g, 256, 0, stream>>>(xbc, G);
        }
        k_intra<<<1024, 256, 0, stream>>>(xbc, dtb, cum, G, y, zx);
        k_states<<<128, 512, 0, stream>>>(zx, cum);
        k_inter<<<1024, 256, 0, stream>>>(xbc, cum, zx, Dparam + (size_t)i * 16, y);
        k_gate<<<8192, 256, 0, stream>>>(y, zx, norm_w + (size_t)i * 1024);
        {
            dim3 g(4, 64);
            k_gemm_nt<2><<<g, 256, 0, stream>>>(y, out_proj_w + (size_t)i * 512 * 1024,
                                                nullptr, x, mask, 8192, 512, 1024);
        }
    }

    k_pool<<<64, 256, 0, stream>>>(x, pooled);
    k_fc<1><<<64, 64, 0, stream>>>(pooled, pooler_w, pooler_b, pbuf, 8 * 512, 512, 512);
    k_fc<1><<<32, 64, 0, stream>>>(pbuf, cls_w1, cls_b1, cbuf, 8 * 256, 256, 512);
    k_fc<0><<<1, 64, 0, stream>>>(cbuf, cls_w2, cls_b2, out, 8 * 2, 2, 256);
}

// Round 3
// 1427.733 us; speedup vs baseline: 4.1599x; 2.0740x over previous
//
#include <hip/hip_runtime.h>

#define EPS 1e-5f
typedef unsigned short u16;
typedef short s16x8 __attribute__((ext_vector_type(8)));
typedef float f32x4 __attribute__((ext_vector_type(4)));

__device__ __forceinline__ float siluf(float x) { return x / (1.0f + __expf(-x)); }
__device__ __forceinline__ float geluf(float x) {
    float u = 0.7978845608028654f * (x + 0.044715f * x * x * x);
    return 0.5f * x * (1.0f + tanhf(u));
}
__device__ __forceinline__ u16 f2bf(float f) {
    unsigned u = __float_as_uint(f);
    return (u16)((u + 0x7fffu + ((u >> 16) & 1u)) >> 16);
}
struct u16x4 { u16 x, y, z, w; };
__device__ __forceinline__ u16x4 f2bf4(float4 v) {
    u16x4 r; r.x = f2bf(v.x); r.y = f2bf(v.y); r.z = f2bf(v.z); r.w = f2bf(v.w);
    return r;
}

#define GLOAD_LDS16(gp, lp) __builtin_amdgcn_global_load_lds( \
    (const __attribute__((address_space(1))) void*)(gp),      \
    (__attribute__((address_space(3))) void*)(lp), 16, 0, 0)

// ---------------- weight casts ----------------
// in_proj: [4][2320][512] f32 -> [4][2432][512] bf16, zero-pad rows >= 2320
__global__ void k_cast_pad(const float* __restrict__ src, u16* __restrict__ dst) {
    int idx = blockIdx.x * 256 + threadIdx.x;    // over 4*2432*512/4 = 1245184
    if (idx >= 1245184) return;
    int e4 = idx * 4;
    int layer = e4 / 1245184;
    int rem   = e4 - layer * 1245184;
    int row   = rem >> 9;
    int k     = rem & 511;
    float4 v = make_float4(0.f, 0.f, 0.f, 0.f);
    if (row < 2320)
        v = *(const float4*)(src + (size_t)layer * 1187840 + (size_t)row * 512 + k);
    *(u16x4*)(dst + e4) = f2bf4(v);
}
__global__ void k_cast(const float* __restrict__ src, u16* __restrict__ dst, int n4) {
    int idx = blockIdx.x * 256 + threadIdx.x;
    if (idx >= n4) return;
    float4 v = *(const float4*)(src + (size_t)idx * 4);
    *(u16x4*)(dst + (size_t)idx * 4) = f2bf4(v);
}

// ---------------- embedding + positional -> bf16 ----------------
__global__ void k_embed(const int* __restrict__ tok, const float* __restrict__ emb,
                        const float* __restrict__ pos, u16* __restrict__ out) {
    int idx = blockIdx.x * 256 + threadIdx.x;   // over 8192*512/4 = 1048576
    int d4 = idx & 127;
    int bl = idx >> 7;
    int l  = bl & 1023;
    float4 e = *(const float4*)(emb + tok[bl] * 512 + d4 * 4);
    float4 p = *(const float4*)(pos + l * 512 + d4 * 4);
    float4 v = make_float4(e.x + p.x, e.y + p.y, e.z + p.z, e.w + p.w);
    *(u16x4*)(out + (size_t)idx * 4) = f2bf4(v);
}

// ---------------- MFMA GEMM NT: C[m,n] = sum_k A[m,k]*B[n,k], bf16 in fp32 out ----
// MODE: 0 = plain store, 1 = +bias[n], 2 = C = (C + acc) * mask[m], also Cbf
template <int MODE>
__global__ __launch_bounds__(256) void k_gemm_mfma(
    const u16* __restrict__ A, const u16* __restrict__ B,
    const float* __restrict__ bias, float* __restrict__ C,
    u16* __restrict__ Cbf, const float* __restrict__ mask,
    int M, int N, int K) {
    __shared__ u16 Asm[4096];   // 8 groups x [kb4][row16][8]
    __shared__ u16 Bsm[4096];
    const int t = threadIdx.x;
    const int w = t >> 6, l = t & 63;
    const int wr = w >> 1, wc = w & 1;
    const int lr = l & 15, lk = (l >> 4) * 8;
    const int m0 = blockIdx.y * 128;
    const int n0 = blockIdx.x * 128;

    f32x4 acc[4][4] = {};

    for (int k0 = 0; k0 < K; k0 += 32) {
#pragma unroll
        for (int s = 0; s < 2; s++) {
            int g = w * 2 + s;
            const u16* ga = A + (size_t)(m0 + g * 16 + lr) * K + k0 + lk;
            GLOAD_LDS16(ga, &Asm[g * 512]);
            const u16* gb = B + (size_t)(n0 + g * 16 + lr) * K + k0 + lk;
            GLOAD_LDS16(gb, &Bsm[g * 512]);
        }
        __syncthreads();
        s16x8 af[4], bfr[4];
#pragma unroll
        for (int i = 0; i < 4; i++) {
            af[i]  = *(const s16x8*)&Asm[(wr * 4 + i) * 512 + l * 8];
            bfr[i] = *(const s16x8*)&Bsm[(wc * 4 + i) * 512 + l * 8];
        }
#pragma unroll
        for (int i = 0; i < 4; i++)
#pragma unroll
            for (int j = 0; j < 4; j++)
                acc[i][j] = __builtin_amdgcn_mfma_f32_16x16x32_bf16(af[i], bfr[j], acc[i][j], 0, 0, 0);
        __syncthreads();
    }

#pragma unroll
    for (int i = 0; i < 4; i++) {
        int mb = m0 + wr * 64 + i * 16 + (l >> 4) * 4;
#pragma unroll
        for (int j = 0; j < 4; j++) {
            int n = n0 + wc * 64 + j * 16 + (l & 15);
            if (n < N) {
#pragma unroll
                for (int r = 0; r < 4; r++) {
                    int m = mb + r;
                    float v = acc[i][j][r];
                    if (MODE == 1) v += bias[n];
                    size_t o = (size_t)m * N + n;
                    if (MODE == 2) {
                        v = (C[o] + v) * mask[m];
                        Cbf[o] = f2bf(v);
                    }
                    C[o] = v;
                }
            }
        }
    }
}

// ---------------- LayerNorm (rows of 512) + mask, in place, + bf16 mirror ----------
__global__ __launch_bounds__(128) void k_layernorm(
    float* __restrict__ x, const float* __restrict__ g,
    const float* __restrict__ b, const float* __restrict__ mask,
    u16* __restrict__ xbf) {
    __shared__ float2 sbuf[2];
    int bl = blockIdx.x;
    int t  = threadIdx.x;
    float4 v = *(float4*)(x + (size_t)bl * 512 + t * 4);
    float s = v.x + v.y + v.z + v.w;
    float q = v.x * v.x + v.y * v.y + v.z * v.z + v.w * v.w;
    for (int off = 32; off; off >>= 1) {
        s += __shfl_xor(s, off, 64);
        q += __shfl_xor(q, off, 64);
    }
    int wid = t >> 6, lane = t & 63;
    if (lane == 0) sbuf[wid] = make_float2(s, q);
    __syncthreads();
    float ts = sbuf[0].x + sbuf[1].x;
    float tq = sbuf[0].y + sbuf[1].y;
    float mu  = ts * (1.f / 512.f);
    float var = tq * (1.f / 512.f) - mu * mu;
    float inv = 1.0f / sqrtf(var + EPS);
    float mk  = mask[bl];
    float4 gg = *(const float4*)(g + t * 4);
    float4 bb = *(const float4*)(b + t * 4);
    float4 o;
    o.x = ((v.x - mu) * inv * gg.x + bb.x) * mk;
    o.y = ((v.y - mu) * inv * gg.y + bb.y) * mk;
    o.z = ((v.z - mu) * inv * gg.z + bb.z) * mk;
    o.w = ((v.w - mu) * inv * gg.w + bb.w) * mk;
    *(float4*)(x + (size_t)bl * 512 + t * 4) = o;
    *(u16x4*)(xbf + (size_t)bl * 512 + t * 4) = f2bf4(o);
}

// ---------------- causal depthwise conv (k=4) + bias + SiLU ----------------
__global__ void k_conv(const float* __restrict__ zx, const float* __restrict__ cw,
                       const float* __restrict__ cb, float* __restrict__ xbc) {
    int idx = blockIdx.x * 256 + threadIdx.x;   // 8*1024*1280 total, exact
    int c  = idx % 1280;
    int l  = (idx / 1280) & 1023;
    int bl = idx / 1280;
    float acc = cb[c];
    const float* w = cw + c * 4;
#pragma unroll
    for (int k = 0; k < 4; k++) {
        int ll = l + k - 3;
        if (ll >= 0) acc += zx[(size_t)(bl + k - 3) * 2320 + 1024 + c] * w[k];
    }
    xbc[idx] = siluf(acc);
}

// ---------------- dt = softplus(raw + bias) ----------------
__global__ void k_dt(const float* __restrict__ zx, const float* __restrict__ dtbias,
                     float* __restrict__ dt) {
    int idx = blockIdx.x * 256 + threadIdx.x;   // 8192*16, exact
    int h  = idx & 15;
    int bl = idx >> 4;
    float raw = zx[(size_t)bl * 2320 + 2304 + h] + dtbias[h];
    float s = (raw > 20.f) ? raw : log1pf(__expf(raw));
    dt[idx] = s;
}

// ============ chunked SSD scan (Q=128, 8 chunks) ============
__global__ __launch_bounds__(128) void k_cum(const float* __restrict__ dtb,
                                             const float* __restrict__ alog,
                                             float* __restrict__ cum) {
    int bhc = blockIdx.x;                 // (b*16+h)*8+c
    int c = bhc & 7, h = (bhc >> 3) & 15, b = bhc >> 7;
    int l = threadIdx.x;
    float A = -__expf(alog[h]);
    float v = dtb[((size_t)(b * 1024 + c * 128 + l)) * 16 + h] * A;
    int lane = l & 63;
#pragma unroll
    for (int off = 1; off < 64; off <<= 1) {
        float o = __shfl_up(v, off, 64);
        if (lane >= off) v += o;
    }
    __shared__ float wsum;
    if (l == 63) wsum = v;
    __syncthreads();
    if (l >= 64) v += wsum;
    cum[(size_t)bhc * 128 + l] = v;
}

// G[b][c][l][j] = sum_n C[b,cQ+l,n]*B[b,cQ+j,n]
__global__ __launch_bounds__(256) void k_gmat(const float* __restrict__ xbc,
                                              float* __restrict__ G) {
    int bc = blockIdx.z;                   // b*8+c
    int b = bc >> 3, c = bc & 7;
    const float* base = xbc + ((size_t)b * 1024 + c * 128) * 1280;
    int l0 = blockIdx.y * 64, j0 = blockIdx.x * 64;
    __shared__ float Cs[16][68], Bsh[16][68];
    int t = threadIdx.x;
    int row = t >> 2, kk = (t & 3) * 4;
    int tl = t >> 4, tj = t & 15;
    float acc[4][4] = {};
    for (int k0 = 0; k0 < 128; k0 += 16) {
        float4 vc = *(const float4*)(base + (size_t)(l0 + row) * 1280 + 1152 + k0 + kk);
        float4 vb = *(const float4*)(base + (size_t)(j0 + row) * 1280 + 1024 + k0 + kk);
        Cs[kk + 0][row] = vc.x; Cs[kk + 1][row] = vc.y;
        Cs[kk + 2][row] = vc.z; Cs[kk + 3][row] = vc.w;
        Bsh[kk + 0][row] = vb.x; Bsh[kk + 1][row] = vb.y;
        Bsh[kk + 2][row] = vb.z; Bsh[kk + 3][row] = vb.w;
        __syncthreads();
#pragma unroll
        for (int k = 0; k < 16; k++) {
            float a[4], bb[4];
            *(float4*)&a[0]  = *(const float4*)&Cs[k][tl * 4];
            *(float4*)&bb[0] = *(const float4*)&Bsh[k][tj * 4];
#pragma unroll
            for (int i = 0; i < 4; i++)
#pragma unroll
                for (int j = 0; j < 4; j++) acc[i][j] = fmaf(a[i], bb[j], acc[i][j]);
        }
        __syncthreads();
    }
    float* g = G + (size_t)bc * 16384;
#pragma unroll
    for (int i = 0; i < 4; i++)
#pragma unroll
        for (int j = 0; j < 4; j++)
            g[(size_t)(l0 + tl * 4 + i) * 128 + j0 + tj * 4 + j] = acc[i][j];
}

// Sc overlay into zx's dead xBC region
__device__ __forceinline__ float* sc_addr(float* zx, size_t f) {
    return zx + (f >> 10) * 2320 + 1024 + (f & 1023);
}
__device__ __forceinline__ const float* sc_addr_c(const float* zx, size_t f) {
    return zx + (f >> 10) * 2320 + 1024 + (f & 1023);
}

// y_intra + chunk summary S_c
__global__ __launch_bounds__(256) void k_intra(
    const float* __restrict__ xbc, const float* __restrict__ dtb,
    const float* __restrict__ cum, const float* __restrict__ G,
    float* __restrict__ y, float* __restrict__ zx) {
    int bhc = blockIdx.x;                 // (b*16+h)*8+c
    int c = bhc & 7, h = (bhc >> 3) & 15, b = bhc >> 7;
    int t = threadIdx.x;
    const size_t row0 = (size_t)b * 1024 + c * 128;
    __shared__ float cl[128], wv[128], dtl[128];
    __shared__ __align__(16) float Us[128][68];
    __shared__ __align__(16) float Ms[16][132];
    __shared__ __align__(16) float Bs[16][132];

    if (t < 128) {
        cl[t]  = cum[(size_t)bhc * 128 + t];
        dtl[t] = dtb[(row0 + t) * 16 + h];
    }
    __syncthreads();
    if (t < 128) wv[t] = __expf(cl[127] - cl[t]);
#pragma unroll
    for (int rep = 0; rep < 8; rep++) {
        int j = (t >> 4) + rep * 16;
        int p = (t & 15) * 4;
        float4 xv = *(const float4*)(xbc + (row0 + j) * 1280 + h * 64 + p);
        float d = dtl[j];
        Us[j][p + 0] = xv.x * d; Us[j][p + 1] = xv.y * d;
        Us[j][p + 2] = xv.z * d; Us[j][p + 3] = xv.w * d;
    }
    __syncthreads();

    int tl = t >> 4, tp = t & 15;
    float acc[8][4] = {};
    const float* g = G + (size_t)(b * 8 + c) * 16384;
    for (int j0 = 0; j0 < 128; j0 += 16) {
#pragma unroll
        for (int pass = 0; pass < 2; pass++) {
            int l = (t >> 2) + pass * 64;
            int j4 = (t & 3) * 4;
            float4 gv = *(const float4*)(g + (size_t)l * 128 + j0 + j4);
            float cll = cl[l];
            float gvv[4] = {gv.x, gv.y, gv.z, gv.w};
#pragma unroll
            for (int i = 0; i < 4; i++) {
                int j = j0 + j4 + i;
                Ms[j4 + i][l] = (j <= l) ? gvv[i] * __expf(cll - cl[j]) : 0.f;
            }
        }
        __syncthreads();
#pragma unroll
        for (int k = 0; k < 16; k++) {
            float a[8], bb[4];
            *(float4*)&a[0] = *(const float4*)&Ms[k][tl * 8];
            *(float4*)&a[4] = *(const float4*)&Ms[k][tl * 8 + 4];
            *(float4*)&bb[0] = *(const float4*)&Us[j0 + k][tp * 4];
#pragma unroll
            for (int i = 0; i < 8; i++)
#pragma unroll
                for (int jj = 0; jj < 4; jj++) acc[i][jj] = fmaf(a[i], bb[jj], acc[i][jj]);
        }
        __syncthreads();
    }
#pragma unroll
    for (int i = 0; i < 8; i++) {
        size_t yo = (row0 + tl * 8 + i) * 1024 + h * 64 + tp * 4;
#pragma unroll
        for (int jj = 0; jj < 4; jj++) y[yo + jj] = acc[i][jj];
    }

    float acc2[4][8] = {};
    for (int j0 = 0; j0 < 128; j0 += 16) {
        {
            int j = t >> 4;
            int n = (t & 15) * 8;
            const float* src = xbc + (row0 + j0 + j) * 1280 + 1024 + n;
            float4 v0 = *(const float4*)(src);
            float4 v1 = *(const float4*)(src + 4);
            Bs[j][n + 0] = v0.x; Bs[j][n + 1] = v0.y; Bs[j][n + 2] = v0.z; Bs[j][n + 3] = v0.w;
            Bs[j][n + 4] = v1.x; Bs[j][n + 5] = v1.y; Bs[j][n + 6] = v1.z; Bs[j][n + 7] = v1.w;
        }
        __syncthreads();
#pragma unroll
        for (int k = 0; k < 16; k++) {
            float w = wv[j0 + k];
            float a[4], bb[8];
            *(float4*)&a[0] = *(const float4*)&Us[j0 + k][tp * 4];
            *(float4*)&bb[0] = *(const float4*)&Bs[k][tl * 8];
            *(float4*)&bb[4] = *(const float4*)&Bs[k][tl * 8 + 4];
#pragma unroll
            for (int i = 0; i < 4; i++) {
                float aw = w * a[i];
#pragma unroll
                for (int jj = 0; jj < 8; jj++) acc2[i][jj] = fmaf(aw, bb[jj], acc2[i][jj]);
            }
        }
        __syncthreads();
    }
#pragma unroll
    for (int i = 0; i < 4; i++) {
        int p = tp * 4 + i;
        size_t f = (size_t)bhc * 8192 + (size_t)p * 128 + tl * 8;
        float* dst = sc_addr(zx, f);
#pragma unroll
        for (int jj = 0; jj < 8; jj++) dst[jj] = acc2[i][jj];
    }
}

// sequential chunk-state recurrence
__global__ __launch_bounds__(512) void k_states(float* __restrict__ zx,
                                                const float* __restrict__ cum) {
    int bh = blockIdx.x;                  // b*16+h
    int t = threadIdx.x;
    float4 h0 = {0, 0, 0, 0}, h1 = h0, h2 = h0, h3 = h0;
    size_t o = (size_t)t * 16;
    for (int c = 0; c < 8; c++) {
        int bhc = bh * 8 + c;
        float Tc = __expf(cum[(size_t)bhc * 128 + 127]);
        float* p = sc_addr(zx, (size_t)bhc * 8192 + o);
        float4 s0 = *(float4*)(p + 0), s1 = *(float4*)(p + 4);
        float4 s2 = *(float4*)(p + 8), s3 = *(float4*)(p + 12);
        *(float4*)(p + 0) = h0; *(float4*)(p + 4) = h1;
        *(float4*)(p + 8) = h2; *(float4*)(p + 12) = h3;
        h0.x = fmaf(Tc, h0.x, s0.x); h0.y = fmaf(Tc, h0.y, s0.y);
        h0.z = fmaf(Tc, h0.z, s0.z); h0.w = fmaf(Tc, h0.w, s0.w);
        h1.x = fmaf(Tc, h1.x, s1.x); h1.y = fmaf(Tc, h1.y, s1.y);
        h1.z = fmaf(Tc, h1.z, s1.z); h1.w = fmaf(Tc, h1.w, s1.w);
        h2.x = fmaf(Tc, h2.x, s2.x); h2.y = fmaf(Tc, h2.y, s2.y);
        h2.z = fmaf(Tc, h2.z, s2.z); h2.w = fmaf(Tc, h2.w, s2.w);
        h3.x = fmaf(Tc, h3.x, s3.x); h3.y = fmaf(Tc, h3.y, s3.y);
        h3.z = fmaf(Tc, h3.z, s3.z); h3.w = fmaf(Tc, h3.w, s3.w);
    }
}

// y[l,p] += exp(cum[l]) * (C[l]·h_start[p,:]) + D*x[l,p]
__global__ __launch_bounds__(256) void k_inter(
    const float* __restrict__ xbc, const float* __restrict__ cum,
    const float* __restrict__ zx, const float* __restrict__ Dp,
    float* __restrict__ y) {
    int bhc = blockIdx.x;
    int c = bhc & 7, h = (bhc >> 3) & 15, b = bhc >> 7;
    int t = threadIdx.x;
    __shared__ __align__(16) float Cs[16][132];
    __shared__ __align__(16) float Hs[16][68];
    __shared__ float el[128];
    if (t < 128) el[t] = __expf(cum[(size_t)bhc * 128 + t]);
    float Dv = Dp[h];
    const size_t row0 = (size_t)b * 1024 + c * 128;
    int tl = t >> 4, tp = t & 15;
    float acc[8][4] = {};
    for (int n0 = 0; n0 < 128; n0 += 16) {
#pragma unroll
        for (int pass = 0; pass < 2; pass++) {
            int l = (t >> 2) + pass * 64, nn = (t & 3) * 4;
            float4 v = *(const float4*)(xbc + (row0 + l) * 1280 + 1152 + n0 + nn);
            Cs[nn + 0][l] = v.x; Cs[nn + 1][l] = v.y;
            Cs[nn + 2][l] = v.z; Cs[nn + 3][l] = v.w;
        }
        {
            int p = t >> 2, nn = (t & 3) * 4;
            const float* src = sc_addr_c(zx, (size_t)bhc * 8192 + (size_t)p * 128 + n0 + nn);
            float4 v = *(const float4*)src;
            Hs[nn + 0][p] = v.x; Hs[nn + 1][p] = v.y;
            Hs[nn + 2][p] = v.z; Hs[nn + 3][p] = v.w;
        }
        __syncthreads();
#pragma unroll
        for (int k = 0; k < 16; k++) {
            float a[8], bb[4];
            *(float4*)&a[0] = *(const float4*)&Cs[k][tl * 8];
            *(float4*)&a[4] = *(const float4*)&Cs[k][tl * 8 + 4];
            *(float4*)&bb[0] = *(const float4*)&Hs[k][tp * 4];
#pragma unroll
            for (int i = 0; i < 8; i++)
#pragma unroll
                for (int jj = 0; jj < 4; jj++) acc[i][jj] = fmaf(a[i], bb[jj], acc[i][jj]);
        }
        __syncthreads();
    }
#pragma unroll
    for (int i = 0; i < 8; i++) {
        int l = tl * 8 + i;
        size_t yo = (row0 + l) * 1024 + h * 64 + tp * 4;
        const float* xr = xbc + (row0 + l) * 1280 + h * 64 + tp * 4;
        float e = el[l];
#pragma unroll
        for (int jj = 0; jj < 4; jj++)
            y[yo + jj] = y[yo + jj] + e * acc[i][jj] + Dv * xr[jj];
    }
}

// ---------------- gate: ybf = bf16(rmsnorm(y * silu(z)) * norm_w) ----------------
__global__ __launch_bounds__(256) void k_gate(
    const float* __restrict__ y, const float* __restrict__ zx,
    const float* __restrict__ nw, u16* __restrict__ ybf) {
    __shared__ float sbuf[4];
    int bl = blockIdx.x;
    int t  = threadIdx.x;
    float4 yv = *(const float4*)(y + (size_t)bl * 1024 + t * 4);
    float4 zv = *(const float4*)(zx + (size_t)bl * 2320 + t * 4);
    float4 gv;
    gv.x = yv.x * siluf(zv.x);
    gv.y = yv.y * siluf(zv.y);
    gv.z = yv.z * siluf(zv.z);
    gv.w = yv.w * siluf(zv.w);
    float q = gv.x * gv.x + gv.y * gv.y + gv.z * gv.z + gv.w * gv.w;
    for (int off = 32; off; off >>= 1) q += __shfl_xor(q, off, 64);
    int wid = t >> 6, lane = t & 63;
    if (lane == 0) sbuf[wid] = q;
    __syncthreads();
    float tot = sbuf[0] + sbuf[1] + sbuf[2] + sbuf[3];
    float scale = 1.0f / sqrtf(tot * (1.f / 1024.f) + EPS);
    float4 nv = *(const float4*)(nw + t * 4);
    float4 o;
    o.x = gv.x * scale * nv.x;
    o.y = gv.y * scale * nv.y;
    o.z = gv.z * scale * nv.z;
    o.w = gv.w * scale * nv.w;
    *(u16x4*)(ybf + (size_t)bl * 1024 + t * 4) = f2bf4(o);
}

// ---------------- pool: 0.5*(mean_l + max_l) ----------------
__global__ __launch_bounds__(256) void k_pool(const float* __restrict__ x,
                                              float* __restrict__ pooled) {
    __shared__ float ss[256], sm[256];
    int b  = blockIdx.x >> 3;
    int d0 = (blockIdx.x & 7) * 64;
    int d   = threadIdx.x & 63;
    int seg = threadIdx.x >> 6;
    const float* px = x + (size_t)b * 1024 * 512 + d0 + d;
    float s = 0.f, mx = -3.0e38f;
    for (int l = seg * 256; l < (seg + 1) * 256; ++l) {
        float v = px[(size_t)l * 512];
        s += v;
        mx = fmaxf(mx, v);
    }
    ss[threadIdx.x] = s;
    sm[threadIdx.x] = mx;
    __syncthreads();
    if (threadIdx.x < 64) {
        float st = ss[d] + ss[64 + d] + ss[128 + d] + ss[192 + d];
        float mt = fmaxf(fmaxf(sm[d], sm[64 + d]), fmaxf(sm[128 + d], sm[192 + d]));
        pooled[b * 512 + d0 + d] = 0.5f * (st * (1.f / 1024.f) + mt);
    }
}

// ---------------- small FC ----------------
template <int ACT>
__global__ void k_fc(const float* __restrict__ in, const float* __restrict__ W,
                     const float* __restrict__ bias, float* __restrict__ out,
                     int BN, int N, int K) {
    int idx = blockIdx.x * 64 + threadIdx.x;
    if (idx >= BN) return;
    int b = idx / N, n = idx % N;
    const float* a = in + (size_t)b * K;
    const float* w = W + (size_t)n * K;
    float acc = 0.f;
    for (int k = 0; k < K; k += 4) {
        float4 av = *(const float4*)(a + k);
        float4 wv = *(const float4*)(w + k);
        acc += av.x * wv.x + av.y * wv.y + av.z * wv.z + av.w * wv.w;
    }
    float v = acc + bias[n];
    if (ACT == 1) v = geluf(v);
    out[idx] = v;
}

extern "C" void kernel_launch(void* const* d_in, const int* in_sizes, int n_in,
                              void* d_out, int out_size, void* d_ws, size_t ws_size,
                              hipStream_t stream) {
    (void)in_sizes; (void)n_in; (void)out_size; (void)ws_size;
    const int*   tok        = (const int*)  d_in[0];
    const float* mask       = (const float*)d_in[1];
    const float* emb        = (const float*)d_in[2];
    const float* pos        = (const float*)d_in[3];
    const float* inp_w      = (const float*)d_in[4];
    const float* inp_b      = (const float*)d_in[5];
    const float* ln_g       = (const float*)d_in[6];
    const float* ln_b       = (const float*)d_in[7];
    const float* in_proj_w  = (const float*)d_in[8];
    const float* conv_w     = (const float*)d_in[9];
    const float* conv_b     = (const float*)d_in[10];
    const float* dt_bias    = (const float*)d_in[11];
    const float* A_log      = (const float*)d_in[12];
    const float* Dparam     = (const float*)d_in[13];
    const float* norm_w     = (const float*)d_in[14];
    const float* out_proj_w = (const float*)d_in[15];
    const float* pooler_w   = (const float*)d_in[16];
    const float* pooler_b   = (const float*)d_in[17];
    const float* cls_w1     = (const float*)d_in[18];
    const float* cls_b1     = (const float*)d_in[19];
    const float* cls_w2     = (const float*)d_in[20];
    const float* cls_b2     = (const float*)d_in[21];
    float* out = (float*)d_out;

    float* ws   = (float*)d_ws;
    float* x    = ws;                                  // 8192*512
    float* zx   = x   + (size_t)8192 * 512;            // 8192*2320
    float* xbc  = zx  + (size_t)8192 * 2320;           // 8192*1280
    float* y    = xbc + (size_t)8192 * 1280;           // 8192*1024
    float* dtb  = y   + (size_t)8192 * 1024;           // 131072
    float* cum  = dtb + 131072;                        // 131072
    float* G    = cum + 131072;                        // 1048576
    float* pooled = G + 1048576;                       // 4096
    float* pbuf   = pooled + 4096;                     // 4096
    float* cbuf   = pbuf + 4096;                       // 2048
    u16* x_bf   = (u16*)(cbuf + 2048);                 // 8192*512 u16
    u16* wip_bf = x_bf + (size_t)8192 * 512;           // 4*2432*512 u16
    u16* wop_bf = wip_bf + (size_t)4 * 2432 * 512;     // 4*512*1024 u16
    u16* winp_bf = wop_bf + (size_t)4 * 512 * 1024;    // 512*512 u16
    // overlays (dead regions)
    u16* xe_bf = (u16*)zx;                             // embed output (prologue only)
    u16* y_bf  = (u16*)xbc;                            // gate output (xbc dead by then)

    // weight casts
    k_cast_pad<<<4864, 256, 0, stream>>>(in_proj_w, wip_bf);
    k_cast<<<2048, 256, 0, stream>>>(out_proj_w, wop_bf, 524288);
    k_cast<<<256, 256, 0, stream>>>(inp_w, winp_bf, 65536);

    // embedding + positional (bf16)
    k_embed<<<4096, 256, 0, stream>>>(tok, emb, pos, xe_bf);
    {   // x = embed @ inp_w^T + inp_b
        dim3 g(4, 64);
        k_gemm_mfma<1><<<g, 256, 0, stream>>>(xe_bf, winp_bf, inp_b, x, nullptr,
                                              nullptr, 8192, 512, 512);
    }
    k_layernorm<<<8192, 128, 0, stream>>>(x, ln_g, ln_b, mask, x_bf);

    for (int i = 0; i < 4; i++) {
        {   // zx = x @ in_proj_w[i]^T
            dim3 g(19, 64);
            k_gemm_mfma<0><<<g, 256, 0, stream>>>(x_bf, wip_bf + (size_t)i * 2432 * 512,
                                                  nullptr, zx, nullptr, nullptr,
                                                  8192, 2320, 512);
        }
        k_conv<<<40960, 256, 0, stream>>>(zx, conv_w + (size_t)i * 1280 * 4,
                                          conv_b + (size_t)i * 1280, xbc);
        k_dt<<<512, 256, 0, stream>>>(zx, dt_bias + i * 16, dtb);
        k_cum<<<1024, 128, 0, stream>>>(dtb, A_log + i * 16, cum);
        {
            dim3 g(2, 2, 64);
            k_gmat<<<g, 256, 0, stream>>>(xbc, G);
        }
        k_intra<<<1024, 256, 0, stream>>>(xbc, dtb, cum, G, y, zx);
        k_states<<<128, 512, 0, stream>>>(zx, cum);
        k_inter<<<1024, 256, 0, stream>>>(xbc, cum, zx, Dparam + (size_t)i * 16, y);
        k_gate<<<8192, 256, 0, stream>>>(y, zx, norm_w + (size_t)i * 1024, y_bf);
        {   // x = (x + y @ out_proj_w[i]^T) * mask ; x_bf mirror
            dim3 g(4, 64);
            k_gemm_mfma<2><<<g, 256, 0, stream>>>(y_bf, wop_bf + (size_t)i * 512 * 1024,
                                                  nullptr, x, x_bf, mask,
                                                  8192, 512, 1024);
        }
    }

    k_pool<<<64, 256, 0, stream>>>(x, pooled);
    k_fc<1><<<64, 64, 0, stream>>>(pooled, pooler_w, pooler_b, pbuf, 8 * 512, 512, 512);
    k_fc<1><<<32, 64, 0, stream>>>(pbuf, cls_w1, cls_b1, cbuf, 8 * 256, 256, 512);
    k_fc<0><<<1, 64, 0, stream>>>(cbuf, cls_w2, cls_b2, out, 8 * 2, 2, 256);
}

// Round 4
// 1237.522 us; speedup vs baseline: 4.7993x; 1.1537x over previous
//
#include <hip/hip_runtime.h>

#define EPS 1e-5f
typedef unsigned short u16;
typedef short s16x8 __attribute__((ext_vector_type(8)));
typedef float f32x4 __attribute__((ext_vector_type(4)));

__device__ __forceinline__ float siluf(float x) { return x / (1.0f + __expf(-x)); }
__device__ __forceinline__ float geluf(float x) {
    float u = 0.7978845608028654f * (x + 0.044715f * x * x * x);
    return 0.5f * x * (1.0f + tanhf(u));
}
__device__ __forceinline__ u16 f2bf(float f) {
    unsigned u = __float_as_uint(f);
    return (u16)((u + 0x7fffu + ((u >> 16) & 1u)) >> 16);
}
__device__ __forceinline__ float bf2f(u16 v) {
    return __uint_as_float(((unsigned)v) << 16);
}
struct u16x4 { u16 x, y, z, w; };
__device__ __forceinline__ u16x4 f2bf4(float4 v) {
    u16x4 r; r.x = f2bf(v.x); r.y = f2bf(v.y); r.z = f2bf(v.z); r.w = f2bf(v.w);
    return r;
}

#define GLOAD_LDS16(gp, lp) __builtin_amdgcn_global_load_lds( \
    (const __attribute__((address_space(1))) void*)(gp),      \
    (__attribute__((address_space(3))) void*)(lp), 16, 0, 0)

// ---------------- weight casts ----------------
__global__ void k_cast_pad(const float* __restrict__ src, u16* __restrict__ dst) {
    int idx = blockIdx.x * 256 + threadIdx.x;    // over 4*2432*512/4 = 1245184
    if (idx >= 1245184) return;
    int e4 = idx * 4;
    int layer = e4 / 1245184;
    int rem   = e4 - layer * 1245184;
    int row   = rem >> 9;
    int k     = rem & 511;
    float4 v = make_float4(0.f, 0.f, 0.f, 0.f);
    if (row < 2320)
        v = *(const float4*)(src + (size_t)layer * 1187840 + (size_t)row * 512 + k);
    *(u16x4*)(dst + e4) = f2bf4(v);
}
__global__ void k_cast(const float* __restrict__ src, u16* __restrict__ dst, int n4) {
    int idx = blockIdx.x * 256 + threadIdx.x;
    if (idx >= n4) return;
    float4 v = *(const float4*)(src + (size_t)idx * 4);
    *(u16x4*)(dst + (size_t)idx * 4) = f2bf4(v);
}

// ---------------- embedding + positional -> bf16 ----------------
__global__ void k_embed(const int* __restrict__ tok, const float* __restrict__ emb,
                        const float* __restrict__ pos, u16* __restrict__ out) {
    int idx = blockIdx.x * 256 + threadIdx.x;   // over 8192*512/4 = 1048576
    int d4 = idx & 127;
    int bl = idx >> 7;
    int l  = bl & 1023;
    float4 e = *(const float4*)(emb + tok[bl] * 512 + d4 * 4);
    float4 p = *(const float4*)(pos + l * 512 + d4 * 4);
    float4 v = make_float4(e.x + p.x, e.y + p.y, e.z + p.z, e.w + p.w);
    *(u16x4*)(out + (size_t)idx * 4) = f2bf4(v);
}

// ---------------- MFMA GEMM NT (projections) ----------------
template <int MODE>
__global__ __launch_bounds__(256) void k_gemm_mfma(
    const u16* __restrict__ A, const u16* __restrict__ B,
    const float* __restrict__ bias, float* __restrict__ C,
    u16* __restrict__ Cbf, const float* __restrict__ mask,
    int M, int N, int K) {
    __shared__ u16 Asm[4096];   // 8 groups x [kb4][row16][8]
    __shared__ u16 Bsm[4096];
    const int t = threadIdx.x;
    const int w = t >> 6, l = t & 63;
    const int wr = w >> 1, wc = w & 1;
    const int lr = l & 15, lk = (l >> 4) * 8;
    const int m0 = blockIdx.y * 128;
    const int n0 = blockIdx.x * 128;

    f32x4 acc[4][4] = {};

    for (int k0 = 0; k0 < K; k0 += 32) {
#pragma unroll
        for (int s = 0; s < 2; s++) {
            int g = w * 2 + s;
            const u16* ga = A + (size_t)(m0 + g * 16 + lr) * K + k0 + lk;
            GLOAD_LDS16(ga, &Asm[g * 512]);
            const u16* gb = B + (size_t)(n0 + g * 16 + lr) * K + k0 + lk;
            GLOAD_LDS16(gb, &Bsm[g * 512]);
        }
        __syncthreads();
        s16x8 af[4], bfr[4];
#pragma unroll
        for (int i = 0; i < 4; i++) {
            af[i]  = *(const s16x8*)&Asm[(wr * 4 + i) * 512 + l * 8];
            bfr[i] = *(const s16x8*)&Bsm[(wc * 4 + i) * 512 + l * 8];
        }
#pragma unroll
        for (int i = 0; i < 4; i++)
#pragma unroll
            for (int j = 0; j < 4; j++)
                acc[i][j] = __builtin_amdgcn_mfma_f32_16x16x32_bf16(af[i], bfr[j], acc[i][j], 0, 0, 0);
        __syncthreads();
    }

#pragma unroll
    for (int i = 0; i < 4; i++) {
        int mb = m0 + wr * 64 + i * 16 + (l >> 4) * 4;
#pragma unroll
        for (int j = 0; j < 4; j++) {
            int n = n0 + wc * 64 + j * 16 + (l & 15);
            if (n < N) {
#pragma unroll
                for (int r = 0; r < 4; r++) {
                    int m = mb + r;
                    float v = acc[i][j][r];
                    if (MODE == 1) v += bias[n];
                    size_t o = (size_t)m * N + n;
                    if (MODE == 2) {
                        v = (C[o] + v) * mask[m];
                        Cbf[o] = f2bf(v);
                    }
                    C[o] = v;
                }
            }
        }
    }
}

// ---------------- LayerNorm + mask + bf16 mirror ----------------
__global__ __launch_bounds__(128) void k_layernorm(
    float* __restrict__ x, const float* __restrict__ g,
    const float* __restrict__ b, const float* __restrict__ mask,
    u16* __restrict__ xbf) {
    __shared__ float2 sbuf[2];
    int bl = blockIdx.x;
    int t  = threadIdx.x;
    float4 v = *(float4*)(x + (size_t)bl * 512 + t * 4);
    float s = v.x + v.y + v.z + v.w;
    float q = v.x * v.x + v.y * v.y + v.z * v.z + v.w * v.w;
    for (int off = 32; off; off >>= 1) {
        s += __shfl_xor(s, off, 64);
        q += __shfl_xor(q, off, 64);
    }
    int wid = t >> 6, lane = t & 63;
    if (lane == 0) sbuf[wid] = make_float2(s, q);
    __syncthreads();
    float ts = sbuf[0].x + sbuf[1].x;
    float tq = sbuf[0].y + sbuf[1].y;
    float mu  = ts * (1.f / 512.f);
    float var = tq * (1.f / 512.f) - mu * mu;
    float inv = 1.0f / sqrtf(var + EPS);
    float mk  = mask[bl];
    float4 gg = *(const float4*)(g + t * 4);
    float4 bb = *(const float4*)(b + t * 4);
    float4 o;
    o.x = ((v.x - mu) * inv * gg.x + bb.x) * mk;
    o.y = ((v.y - mu) * inv * gg.y + bb.y) * mk;
    o.z = ((v.z - mu) * inv * gg.z + bb.z) * mk;
    o.w = ((v.w - mu) * inv * gg.w + bb.w) * mk;
    *(float4*)(x + (size_t)bl * 512 + t * 4) = o;
    *(u16x4*)(xbf + (size_t)bl * 512 + t * 4) = f2bf4(o);
}

// ---------------- causal depthwise conv (k=4) + bias + SiLU + bf16 B/C mirror ----
__global__ void k_conv(const float* __restrict__ zx, const float* __restrict__ cw,
                       const float* __restrict__ cb, float* __restrict__ xbc,
                       u16* __restrict__ bcbf) {
    int idx = blockIdx.x * 256 + threadIdx.x;   // 8*1024*1280 total, exact
    int c  = idx % 1280;
    int l  = (idx / 1280) & 1023;
    int bl = idx / 1280;
    float acc = cb[c];
    const float* w = cw + c * 4;
#pragma unroll
    for (int k = 0; k < 4; k++) {
        int ll = l + k - 3;
        if (ll >= 0) acc += zx[(size_t)(bl + k - 3) * 2320 + 1024 + c] * w[k];
    }
    float v = siluf(acc);
    xbc[idx] = v;
    if (c >= 1024) bcbf[(size_t)bl * 256 + (c - 1024)] = f2bf(v);
}

// ---------------- dt = softplus(raw + bias) ----------------
__global__ void k_dt(const float* __restrict__ zx, const float* __restrict__ dtbias,
                     float* __restrict__ dt) {
    int idx = blockIdx.x * 256 + threadIdx.x;   // 8192*16, exact
    int h  = idx & 15;
    int bl = idx >> 4;
    float raw = zx[(size_t)bl * 2320 + 2304 + h] + dtbias[h];
    float s = (raw > 20.f) ? raw : log1pf(__expf(raw));
    dt[idx] = s;
}

// ---------------- cum = cumsum(dt*A) per chunk ----------------
__global__ __launch_bounds__(128) void k_cum(const float* __restrict__ dtb,
                                             const float* __restrict__ alog,
                                             float* __restrict__ cum) {
    int bhc = blockIdx.x;                 // (b*16+h)*8+c
    int c = bhc & 7, h = (bhc >> 3) & 15, b = bhc >> 7;
    int l = threadIdx.x;
    float A = -__expf(alog[h]);
    float v = dtb[((size_t)(b * 1024 + c * 128 + l)) * 16 + h] * A;
    int lane = l & 63;
#pragma unroll
    for (int off = 1; off < 64; off <<= 1) {
        float o = __shfl_up(v, off, 64);
        if (lane >= off) v += o;
    }
    __shared__ float wsum;
    if (l == 63) wsum = v;
    __syncthreads();
    if (l >= 64) v += wsum;
    cum[(size_t)bhc * 128 + l] = v;
}

// Sc / h_start overlay into zx's dead region (cols 1024..2047)
__device__ __forceinline__ float* sc_addr(float* zx, size_t f) {
    return zx + (f >> 10) * 2320 + 1024 + (f & 1023);
}
__device__ __forceinline__ const float* sc_addr_c(const float* zx, size_t f) {
    return zx + (f >> 10) * 2320 + 1024 + (f & 1023);
}

// ============ fused SSD intra: S=C.B^T (MFMA), y_intra=P.U (MFMA), Sc=U^T.(wB) (MFMA)
__global__ __launch_bounds__(256) void k_ssd(
    const float* __restrict__ xbc, const u16* __restrict__ bcbf,
    const float* __restrict__ dtb, const float* __restrict__ cum,
    float* __restrict__ y, float* __restrict__ zx) {
    int bhc = blockIdx.x;                 // (b*16+h)*8+c
    int c = bhc & 7, h = (bhc >> 3) & 15, b = bhc >> 7;
    const size_t row0 = (size_t)b * 1024 + c * 128;
    const int t = threadIdx.x, w = t >> 6, l = t & 63;
    const int wr = w >> 1, wc = w & 1;
    const int lr = l & 15, lk8 = (l >> 4) * 8;

    __shared__ float cl[128], dtl[128], wv[128];
    // shA: phase1 = AStg[0..4095] + BStg[4096..8191]; later = UT[64][136]
    __shared__ __align__(16) u16 shA[8704];
    // shB: P-half view [128][72]; later BTw view [128][136]
    __shared__ __align__(16) u16 shB[17408];

    if (t < 128) {
        cl[t]  = cum[(size_t)bhc * 128 + t];
        dtl[t] = dtb[(row0 + t) * 16 + h];
    }
    __syncthreads();
    if (t < 128) wv[t] = __expf(cl[127] - cl[t]);

    // ---- phase 1: S = C.B^T  (M=l 128, N=j 128, K=n 128)
    f32x4 acc[4][4] = {};
    for (int ks = 0; ks < 4; ks++) {
        int k0 = ks * 32;
#pragma unroll
        for (int s = 0; s < 2; s++) {
            int g = w * 2 + s;
            GLOAD_LDS16(bcbf + (row0 + g * 16 + lr) * 256 + 128 + k0 + lk8, &shA[g * 512]);
            GLOAD_LDS16(bcbf + (row0 + g * 16 + lr) * 256 +       k0 + lk8, &shA[4096 + g * 512]);
        }
        __syncthreads();
        s16x8 af[4], bfr[4];
#pragma unroll
        for (int i = 0; i < 4; i++) {
            af[i]  = *(const s16x8*)&shA[(wr * 4 + i) * 512 + l * 8];
            bfr[i] = *(const s16x8*)&shA[4096 + (wc * 4 + i) * 512 + l * 8];
        }
#pragma unroll
        for (int i = 0; i < 4; i++)
#pragma unroll
            for (int j = 0; j < 4; j++)
                acc[i][j] = __builtin_amdgcn_mfma_f32_16x16x32_bf16(af[i], bfr[j], acc[i][j], 0, 0, 0);
        __syncthreads();
    }

    // ---- UT build (overwrites stage bufs): UT[p][j] = dt[j]*x[j][p], bf16
#pragma unroll
    for (int jj = 0; jj < 32; jj++) {
        int j = jj * 4 + w;
        float xv = xbc[(row0 + j) * 1280 + h * 64 + l];
        shA[l * 136 + j] = f2bf(dtl[j] * xv);
    }
    __syncthreads();

    // ---- phase 2: y = P.U  (M=l 128, N=p 64, K=j 128), P in 64-col halves
    f32x4 acc2[4][2] = {};
    for (int half = 0; half < 2; half++) {
        if (wc == half) {
#pragma unroll
            for (int i = 0; i < 4; i++) {
#pragma unroll
                for (int j = 0; j < 4; j++) {
                    int col = half * 64 + j * 16 + (l & 15);
#pragma unroll
                    for (int r = 0; r < 4; r++) {
                        int row = wr * 64 + i * 16 + (l >> 4) * 4 + r;
                        float e = __expf(fminf(cl[row] - cl[col], 0.f));
                        float pv = (col <= row) ? acc[i][j][r] * e : 0.f;
                        shB[row * 72 + j * 16 + (l & 15)] = f2bf(pv);
                    }
                }
            }
        }
        __syncthreads();
#pragma unroll
        for (int ks = 0; ks < 2; ks++) {
            int kof = ks * 32;
            s16x8 pa[4], ub[2];
#pragma unroll
            for (int i = 0; i < 4; i++)
                pa[i] = *(const s16x8*)&shB[(wr * 64 + i * 16 + lr) * 72 + kof + lk8];
#pragma unroll
            for (int jj = 0; jj < 2; jj++)
                ub[jj] = *(const s16x8*)&shA[(wc * 32 + jj * 16 + lr) * 136 + half * 64 + kof + lk8];
#pragma unroll
            for (int i = 0; i < 4; i++)
#pragma unroll
                for (int jj = 0; jj < 2; jj++)
                    acc2[i][jj] = __builtin_amdgcn_mfma_f32_16x16x32_bf16(pa[i], ub[jj], acc2[i][jj], 0, 0, 0);
        }
        __syncthreads();
    }
    // store y_intra
#pragma unroll
    for (int i = 0; i < 4; i++)
#pragma unroll
        for (int jj = 0; jj < 2; jj++) {
            int p = wc * 32 + jj * 16 + (l & 15);
#pragma unroll
            for (int r = 0; r < 4; r++) {
                int row = wr * 64 + i * 16 + (l >> 4) * 4 + r;
                y[(row0 + row) * 1024 + h * 64 + p] = acc2[i][jj][r];
            }
        }

    // ---- BTw build (overwrites P): BTw[n][j] = w[j]*B[j][n], bf16
#pragma unroll
    for (int s = 0; s < 64; s++) {
        int j = s * 2 + (w & 1);
        int n = (w >> 1) * 64 + l;
        float bvv = bf2f(bcbf[(row0 + j) * 256 + n]);
        shB[n * 136 + j] = f2bf(wv[j] * bvv);
    }
    __syncthreads();

    // ---- phase 3: Sc = UT.(BTw)^T-style NT  (M=p 64, N=n 128, K=j 128)
    f32x4 acc3[4][2] = {};
#pragma unroll
    for (int ks = 0; ks < 4; ks++) {
        int kof = ks * 32;
        s16x8 ua[4], bb[2];
#pragma unroll
        for (int i = 0; i < 4; i++)
            ua[i] = *(const s16x8*)&shA[(i * 16 + lr) * 136 + kof + lk8];
#pragma unroll
        for (int jj = 0; jj < 2; jj++)
            bb[jj] = *(const s16x8*)&shB[(w * 32 + jj * 16 + lr) * 136 + kof + lk8];
#pragma unroll
        for (int i = 0; i < 4; i++)
#pragma unroll
            for (int jj = 0; jj < 2; jj++)
                acc3[i][jj] = __builtin_amdgcn_mfma_f32_16x16x32_bf16(ua[i], bb[jj], acc3[i][jj], 0, 0, 0);
    }
#pragma unroll
    for (int i = 0; i < 4; i++)
#pragma unroll
        for (int jj = 0; jj < 2; jj++) {
            int n = w * 32 + jj * 16 + (l & 15);
#pragma unroll
            for (int r = 0; r < 4; r++) {
                int p = i * 16 + (l >> 4) * 4 + r;
                *sc_addr(zx, (size_t)bhc * 8192 + (size_t)p * 128 + n) = acc3[i][jj][r];
            }
        }
}

// sequential chunk-state recurrence (in place on overlay)
__global__ __launch_bounds__(512) void k_states(float* __restrict__ zx,
                                                const float* __restrict__ cum) {
    int bh = blockIdx.x;                  // b*16+h
    int t = threadIdx.x;
    float4 h0 = {0, 0, 0, 0}, h1 = h0, h2 = h0, h3 = h0;
    size_t o = (size_t)t * 16;
    for (int c = 0; c < 8; c++) {
        int bhc = bh * 8 + c;
        float Tc = __expf(cum[(size_t)bhc * 128 + 127]);
        float* p = sc_addr(zx, (size_t)bhc * 8192 + o);
        float4 s0 = *(float4*)(p + 0), s1 = *(float4*)(p + 4);
        float4 s2 = *(float4*)(p + 8), s3 = *(float4*)(p + 12);
        *(float4*)(p + 0) = h0; *(float4*)(p + 4) = h1;
        *(float4*)(p + 8) = h2; *(float4*)(p + 12) = h3;
        h0.x = fmaf(Tc, h0.x, s0.x); h0.y = fmaf(Tc, h0.y, s0.y);
        h0.z = fmaf(Tc, h0.z, s0.z); h0.w = fmaf(Tc, h0.w, s0.w);
        h1.x = fmaf(Tc, h1.x, s1.x); h1.y = fmaf(Tc, h1.y, s1.y);
        h1.z = fmaf(Tc, h1.z, s1.z); h1.w = fmaf(Tc, h1.w, s1.w);
        h2.x = fmaf(Tc, h2.x, s2.x); h2.y = fmaf(Tc, h2.y, s2.y);
        h2.z = fmaf(Tc, h2.z, s2.z); h2.w = fmaf(Tc, h2.w, s2.w);
        h3.x = fmaf(Tc, h3.x, s3.x); h3.y = fmaf(Tc, h3.y, s3.y);
        h3.z = fmaf(Tc, h3.z, s3.z); h3.w = fmaf(Tc, h3.w, s3.w);
    }
}

// ============ inter-chunk: y += exp(cum[l]) * (C @ h_start^T) + D*x  (MFMA)
__global__ __launch_bounds__(256) void k_inter(
    const float* __restrict__ xbc, const u16* __restrict__ bcbf,
    const float* __restrict__ cum, const float* __restrict__ zx,
    const float* __restrict__ Dp, float* __restrict__ y) {
    int bhc = blockIdx.x;
    int c = bhc & 7, h = (bhc >> 3) & 15, b = bhc >> 7;
    const size_t row0 = (size_t)b * 1024 + c * 128;
    const int t = threadIdx.x, w = t >> 6, l = t & 63;
    const int wr = w >> 1, wc = w & 1;
    const int lr = l & 15, lk8 = (l >> 4) * 8;
    __shared__ __align__(16) u16 CStg[4096];
    __shared__ __align__(16) u16 HStg[2048];
    __shared__ float el[128];
    if (t < 128) el[t] = __expf(cum[(size_t)bhc * 128 + t]);
    float Dv = Dp[h];

    f32x4 acc[4][2] = {};
    for (int ks = 0; ks < 4; ks++) {
        int k0 = ks * 32;
#pragma unroll
        for (int s = 0; s < 2; s++) {
            int g = w * 2 + s;
            GLOAD_LDS16(bcbf + (row0 + g * 16 + lr) * 256 + 128 + k0 + lk8, &CStg[g * 512]);
        }
        {   // stage H (f32 overlay -> bf16 frag layout)
            int g = t >> 6, pr = (t >> 2) & 15, kq = t & 3;
            int p = g * 16 + pr;
            const float* src = sc_addr_c(zx, (size_t)bhc * 8192 + (size_t)p * 128 + k0 + kq * 8);
            float4 v0 = *(const float4*)src;
            float4 v1 = *(const float4*)(src + 4);
            s16x8 hv;
            hv[0] = (short)f2bf(v0.x); hv[1] = (short)f2bf(v0.y);
            hv[2] = (short)f2bf(v0.z); hv[3] = (short)f2bf(v0.w);
            hv[4] = (short)f2bf(v1.x); hv[5] = (short)f2bf(v1.y);
            hv[6] = (short)f2bf(v1.z); hv[7] = (short)f2bf(v1.w);
            *(s16x8*)&HStg[g * 512 + kq * 128 + pr * 8] = hv;
        }
        __syncthreads();
        s16x8 ca[4], hb[2];
#pragma unroll
        for (int i = 0; i < 4; i++)
            ca[i] = *(const s16x8*)&CStg[(wr * 4 + i) * 512 + l * 8];
#pragma unroll
        for (int jj = 0; jj < 2; jj++)
            hb[jj] = *(const s16x8*)&HStg[(wc * 2 + jj) * 512 + l * 8];
#pragma unroll
        for (int i = 0; i < 4; i++)
#pragma unroll
            for (int jj = 0; jj < 2; jj++)
                acc[i][jj] = __builtin_amdgcn_mfma_f32_16x16x32_bf16(ca[i], hb[jj], acc[i][jj], 0, 0, 0);
        __syncthreads();
    }
#pragma unroll
    for (int i = 0; i < 4; i++)
#pragma unroll
        for (int jj = 0; jj < 2; jj++) {
            int p = wc * 32 + jj * 16 + (l & 15);
#pragma unroll
            for (int r = 0; r < 4; r++) {
                int lrow = wr * 64 + i * 16 + (l >> 4) * 4 + r;
                size_t yo = (row0 + lrow) * 1024 + h * 64 + p;
                y[yo] += el[lrow] * acc[i][jj][r]
                       + Dv * xbc[(row0 + lrow) * 1280 + h * 64 + p];
            }
        }
}

// ---------------- gate: ybf = bf16(rmsnorm(y * silu(z)) * norm_w) ----------------
__global__ __launch_bounds__(256) void k_gate(
    const float* __restrict__ y, const float* __restrict__ zx,
    const float* __restrict__ nw, u16* __restrict__ ybf) {
    __shared__ float sbuf[4];
    int bl = blockIdx.x;
    int t  = threadIdx.x;
    float4 yv = *(const float4*)(y + (size_t)bl * 1024 + t * 4);
    float4 zv = *(const float4*)(zx + (size_t)bl * 2320 + t * 4);
    float4 gv;
    gv.x = yv.x * siluf(zv.x);
    gv.y = yv.y * siluf(zv.y);
    gv.z = yv.z * siluf(zv.z);
    gv.w = yv.w * siluf(zv.w);
    float q = gv.x * gv.x + gv.y * gv.y + gv.z * gv.z + gv.w * gv.w;
    for (int off = 32; off; off >>= 1) q += __shfl_xor(q, off, 64);
    int wid = t >> 6, lane = t & 63;
    if (lane == 0) sbuf[wid] = q;
    __syncthreads();
    float tot = sbuf[0] + sbuf[1] + sbuf[2] + sbuf[3];
    float scale = 1.0f / sqrtf(tot * (1.f / 1024.f) + EPS);
    float4 nv = *(const float4*)(nw + t * 4);
    float4 o;
    o.x = gv.x * scale * nv.x;
    o.y = gv.y * scale * nv.y;
    o.z = gv.z * scale * nv.z;
    o.w = gv.w * scale * nv.w;
    *(u16x4*)(ybf + (size_t)bl * 1024 + t * 4) = f2bf4(o);
}

// ---------------- pool: 0.5*(mean_l + max_l) ----------------
__global__ __launch_bounds__(256) void k_pool(const float* __restrict__ x,
                                              float* __restrict__ pooled) {
    __shared__ float ss[256], sm[256];
    int b  = blockIdx.x >> 3;
    int d0 = (blockIdx.x & 7) * 64;
    int d   = threadIdx.x & 63;
    int seg = threadIdx.x >> 6;
    const float* px = x + (size_t)b * 1024 * 512 + d0 + d;
    float s = 0.f, mx = -3.0e38f;
    for (int l = seg * 256; l < (seg + 1) * 256; ++l) {
        float v = px[(size_t)l * 512];
        s += v;
        mx = fmaxf(mx, v);
    }
    ss[threadIdx.x] = s;
    sm[threadIdx.x] = mx;
    __syncthreads();
    if (threadIdx.x < 64) {
        float st = ss[d] + ss[64 + d] + ss[128 + d] + ss[192 + d];
        float mt = fmaxf(fmaxf(sm[d], sm[64 + d]), fmaxf(sm[128 + d], sm[192 + d]));
        pooled[b * 512 + d0 + d] = 0.5f * (st * (1.f / 1024.f) + mt);
    }
}

// ---------------- small FC ----------------
template <int ACT>
__global__ void k_fc(const float* __restrict__ in, const float* __restrict__ W,
                     const float* __restrict__ bias, float* __restrict__ out,
                     int BN, int N, int K) {
    int idx = blockIdx.x * 64 + threadIdx.x;
    if (idx >= BN) return;
    int b = idx / N, n = idx % N;
    const float* a = in + (size_t)b * K;
    const float* w = W + (size_t)n * K;
    float acc = 0.f;
    for (int k = 0; k < K; k += 4) {
        float4 av = *(const float4*)(a + k);
        float4 wv = *(const float4*)(w + k);
        acc += av.x * wv.x + av.y * wv.y + av.z * wv.z + av.w * wv.w;
    }
    float v = acc + bias[n];
    if (ACT == 1) v = geluf(v);
    out[idx] = v;
}

extern "C" void kernel_launch(void* const* d_in, const int* in_sizes, int n_in,
                              void* d_out, int out_size, void* d_ws, size_t ws_size,
                              hipStream_t stream) {
    (void)in_sizes; (void)n_in; (void)out_size; (void)ws_size;
    const int*   tok        = (const int*)  d_in[0];
    const float* mask       = (const float*)d_in[1];
    const float* emb        = (const float*)d_in[2];
    const float* pos        = (const float*)d_in[3];
    const float* inp_w      = (const float*)d_in[4];
    const float* inp_b      = (const float*)d_in[5];
    const float* ln_g       = (const float*)d_in[6];
    const float* ln_b       = (const float*)d_in[7];
    const float* in_proj_w  = (const float*)d_in[8];
    const float* conv_w     = (const float*)d_in[9];
    const float* conv_b     = (const float*)d_in[10];
    const float* dt_bias    = (const float*)d_in[11];
    const float* A_log      = (const float*)d_in[12];
    const float* Dparam     = (const float*)d_in[13];
    const float* norm_w     = (const float*)d_in[14];
    const float* out_proj_w = (const float*)d_in[15];
    const float* pooler_w   = (const float*)d_in[16];
    const float* pooler_b   = (const float*)d_in[17];
    const float* cls_w1     = (const float*)d_in[18];
    const float* cls_b1     = (const float*)d_in[19];
    const float* cls_w2     = (const float*)d_in[20];
    const float* cls_b2     = (const float*)d_in[21];
    float* out = (float*)d_out;

    float* ws   = (float*)d_ws;
    float* x    = ws;                                  // 8192*512
    float* zx   = x   + (size_t)8192 * 512;            // 8192*2320
    float* xbc  = zx  + (size_t)8192 * 2320;           // 8192*1280
    float* y    = xbc + (size_t)8192 * 1280;           // 8192*1024
    float* dtb  = y   + (size_t)8192 * 1024;           // 131072
    float* cum  = dtb + 131072;                        // 131072
    float* G    = cum + 131072;                        // 1048576 (repurposed: bcbf)
    float* pooled = G + 1048576;                       // 4096
    float* pbuf   = pooled + 4096;                     // 4096
    float* cbuf   = pbuf + 4096;                       // 2048
    u16* x_bf   = (u16*)(cbuf + 2048);                 // 8192*512 u16
    u16* wip_bf = x_bf + (size_t)8192 * 512;           // 4*2432*512 u16
    u16* wop_bf = wip_bf + (size_t)4 * 2432 * 512;     // 4*512*1024 u16
    u16* winp_bf = wop_bf + (size_t)4 * 512 * 1024;    // 512*512 u16
    u16* bcbf   = (u16*)G;                             // 8192*256 u16 (= 4 MB, exact)
    // overlays (dead regions)
    u16* xe_bf = (u16*)zx;                             // embed output (prologue only)
    u16* y_bf  = (u16*)xbc;                            // gate output (xbc dead by then)

    // weight casts
    k_cast_pad<<<4864, 256, 0, stream>>>(in_proj_w, wip_bf);
    k_cast<<<2048, 256, 0, stream>>>(out_proj_w, wop_bf, 524288);
    k_cast<<<256, 256, 0, stream>>>(inp_w, winp_bf, 65536);

    // embedding + positional (bf16)
    k_embed<<<4096, 256, 0, stream>>>(tok, emb, pos, xe_bf);
    {   // x = embed @ inp_w^T + inp_b
        dim3 g(4, 64);
        k_gemm_mfma<1><<<g, 256, 0, stream>>>(xe_bf, winp_bf, inp_b, x, nullptr,
                                              nullptr, 8192, 512, 512);
    }
    k_layernorm<<<8192, 128, 0, stream>>>(x, ln_g, ln_b, mask, x_bf);

    for (int i = 0; i < 4; i++) {
        {   // zx = x @ in_proj_w[i]^T
            dim3 g(19, 64);
            k_gemm_mfma<0><<<g, 256, 0, stream>>>(x_bf, wip_bf + (size_t)i * 2432 * 512,
                                                  nullptr, zx, nullptr, nullptr,
                                                  8192, 2320, 512);
        }
        k_conv<<<40960, 256, 0, stream>>>(zx, conv_w + (size_t)i * 1280 * 4,
                                          conv_b + (size_t)i * 1280, xbc, bcbf);
        k_dt<<<512, 256, 0, stream>>>(zx, dt_bias + i * 16, dtb);
        k_cum<<<1024, 128, 0, stream>>>(dtb, A_log + i * 16, cum);
        k_ssd<<<1024, 256, 0, stream>>>(xbc, bcbf, dtb, cum, y, zx);
        k_states<<<128, 512, 0, stream>>>(zx, cum);
        k_inter<<<1024, 256, 0, stream>>>(xbc, bcbf, cum, zx, Dparam + (size_t)i * 16, y);
        k_gate<<<8192, 256, 0, stream>>>(y, zx, norm_w + (size_t)i * 1024, y_bf);
        {   // x = (x + y @ out_proj_w[i]^T) * mask ; x_bf mirror
            dim3 g(4, 64);
            k_gemm_mfma<2><<<g, 256, 0, stream>>>(y_bf, wop_bf + (size_t)i * 512 * 1024,
                                                  nullptr, x, x_bf, mask,
                                                  8192, 512, 1024);
        }
    }

    k_pool<<<64, 256, 0, stream>>>(x, pooled);
    k_fc<1><<<64, 64, 0, stream>>>(pooled, pooler_w, pooler_b, pbuf, 8 * 512, 512, 512);
    k_fc<1><<<32, 64, 0, stream>>>(pbuf, cls_w1, cls_b1, cbuf, 8 * 256, 256, 512);
    k_fc<0><<<1, 64, 0, stream>>>(cbuf, cls_w2, cls_b2, out, 8 * 2, 2, 256);
}

// Round 5
// 1218.862 us; speedup vs baseline: 4.8728x; 1.0153x over previous
//
#include <hip/hip_runtime.h>

#define EPS 1e-5f
typedef unsigned short u16;
typedef short s16x8 __attribute__((ext_vector_type(8)));
typedef float f32x4 __attribute__((ext_vector_type(4)));

__device__ __forceinline__ float siluf(float x) { return x / (1.0f + __expf(-x)); }
__device__ __forceinline__ float geluf(float x) {
    float u = 0.7978845608028654f * (x + 0.044715f * x * x * x);
    return 0.5f * x * (1.0f + tanhf(u));
}
__device__ __forceinline__ u16 f2bf(float f) {
    unsigned u = __float_as_uint(f);
    return (u16)((u + 0x7fffu + ((u >> 16) & 1u)) >> 16);
}
__device__ __forceinline__ float bf2f(u16 v) {
    return __uint_as_float(((unsigned)v) << 16);
}
struct u16x4 { u16 x, y, z, w; };
__device__ __forceinline__ u16x4 f2bf4(float4 v) {
    u16x4 r; r.x = f2bf(v.x); r.y = f2bf(v.y); r.z = f2bf(v.z); r.w = f2bf(v.w);
    return r;
}

#define GLOAD_LDS16(gp, lp) __builtin_amdgcn_global_load_lds( \
    (const __attribute__((address_space(1))) void*)(gp),      \
    (__attribute__((address_space(3))) void*)(lp), 16, 0, 0)

// ---------------- weight casts ----------------
__global__ void k_cast_pad(const float* __restrict__ src, u16* __restrict__ dst) {
    int idx = blockIdx.x * 256 + threadIdx.x;    // over 4*2432*512/4 = 1245184
    if (idx >= 1245184) return;
    int e4 = idx * 4;
    int layer = e4 / 1245184;
    int rem   = e4 - layer * 1245184;
    int row   = rem >> 9;
    int k     = rem & 511;
    float4 v = make_float4(0.f, 0.f, 0.f, 0.f);
    if (row < 2320)
        v = *(const float4*)(src + (size_t)layer * 1187840 + (size_t)row * 512 + k);
    *(u16x4*)(dst + e4) = f2bf4(v);
}
__global__ void k_cast(const float* __restrict__ src, u16* __restrict__ dst, int n4) {
    int idx = blockIdx.x * 256 + threadIdx.x;
    if (idx >= n4) return;
    float4 v = *(const float4*)(src + (size_t)idx * 4);
    *(u16x4*)(dst + (size_t)idx * 4) = f2bf4(v);
}

// ---------------- embedding + positional -> bf16 ----------------
__global__ void k_embed(const int* __restrict__ tok, const float* __restrict__ emb,
                        const float* __restrict__ pos, u16* __restrict__ out) {
    int idx = blockIdx.x * 256 + threadIdx.x;   // over 8192*512/4 = 1048576
    int d4 = idx & 127;
    int bl = idx >> 7;
    int l  = bl & 1023;
    float4 e = *(const float4*)(emb + tok[bl] * 512 + d4 * 4);
    float4 p = *(const float4*)(pos + l * 512 + d4 * 4);
    float4 v = make_float4(e.x + p.x, e.y + p.y, e.z + p.z, e.w + p.w);
    *(u16x4*)(out + (size_t)idx * 4) = f2bf4(v);
}

// ---------------- MFMA GEMM NT (projections) ----------------
template <int MODE>
__global__ __launch_bounds__(256) void k_gemm_mfma(
    const u16* __restrict__ A, const u16* __restrict__ B,
    const float* __restrict__ bias, float* __restrict__ C,
    u16* __restrict__ Cbf, const float* __restrict__ mask,
    int M, int N, int K) {
    __shared__ u16 Asm[4096];   // 8 groups x [kb4][row16][8]
    __shared__ u16 Bsm[4096];
    const int t = threadIdx.x;
    const int w = t >> 6, l = t & 63;
    const int wr = w >> 1, wc = w & 1;
    const int lr = l & 15, lk = (l >> 4) * 8;
    const int m0 = blockIdx.y * 128;
    const int n0 = blockIdx.x * 128;

    f32x4 acc[4][4] = {};

    for (int k0 = 0; k0 < K; k0 += 32) {
#pragma unroll
        for (int s = 0; s < 2; s++) {
            int g = w * 2 + s;
            const u16* ga = A + (size_t)(m0 + g * 16 + lr) * K + k0 + lk;
            GLOAD_LDS16(ga, &Asm[g * 512]);
            const u16* gb = B + (size_t)(n0 + g * 16 + lr) * K + k0 + lk;
            GLOAD_LDS16(gb, &Bsm[g * 512]);
        }
        __syncthreads();
        s16x8 af[4], bfr[4];
#pragma unroll
        for (int i = 0; i < 4; i++) {
            af[i]  = *(const s16x8*)&Asm[(wr * 4 + i) * 512 + l * 8];
            bfr[i] = *(const s16x8*)&Bsm[(wc * 4 + i) * 512 + l * 8];
        }
#pragma unroll
        for (int i = 0; i < 4; i++)
#pragma unroll
            for (int j = 0; j < 4; j++)
                acc[i][j] = __builtin_amdgcn_mfma_f32_16x16x32_bf16(af[i], bfr[j], acc[i][j], 0, 0, 0);
        __syncthreads();
    }

#pragma unroll
    for (int i = 0; i < 4; i++) {
        int mb = m0 + wr * 64 + i * 16 + (l >> 4) * 4;
#pragma unroll
        for (int j = 0; j < 4; j++) {
            int n = n0 + wc * 64 + j * 16 + (l & 15);
            if (n < N) {
#pragma unroll
                for (int r = 0; r < 4; r++) {
                    int m = mb + r;
                    float v = acc[i][j][r];
                    if (MODE == 1) v += bias[n];
                    size_t o = (size_t)m * N + n;
                    if (MODE == 2) {
                        v = (C[o] + v) * mask[m];
                        Cbf[o] = f2bf(v);
                    }
                    C[o] = v;
                }
            }
        }
    }
}

// ---------------- LayerNorm + mask + bf16 mirror ----------------
__global__ __launch_bounds__(128) void k_layernorm(
    float* __restrict__ x, const float* __restrict__ g,
    const float* __restrict__ b, const float* __restrict__ mask,
    u16* __restrict__ xbf) {
    __shared__ float2 sbuf[2];
    int bl = blockIdx.x;
    int t  = threadIdx.x;
    float4 v = *(float4*)(x + (size_t)bl * 512 + t * 4);
    float s = v.x + v.y + v.z + v.w;
    float q = v.x * v.x + v.y * v.y + v.z * v.z + v.w * v.w;
    for (int off = 32; off; off >>= 1) {
        s += __shfl_xor(s, off, 64);
        q += __shfl_xor(q, off, 64);
    }
    int wid = t >> 6, lane = t & 63;
    if (lane == 0) sbuf[wid] = make_float2(s, q);
    __syncthreads();
    float ts = sbuf[0].x + sbuf[1].x;
    float tq = sbuf[0].y + sbuf[1].y;
    float mu  = ts * (1.f / 512.f);
    float var = tq * (1.f / 512.f) - mu * mu;
    float inv = 1.0f / sqrtf(var + EPS);
    float mk  = mask[bl];
    float4 gg = *(const float4*)(g + t * 4);
    float4 bb = *(const float4*)(b + t * 4);
    float4 o;
    o.x = ((v.x - mu) * inv * gg.x + bb.x) * mk;
    o.y = ((v.y - mu) * inv * gg.y + bb.y) * mk;
    o.z = ((v.z - mu) * inv * gg.z + bb.z) * mk;
    o.w = ((v.w - mu) * inv * gg.w + bb.w) * mk;
    *(float4*)(x + (size_t)bl * 512 + t * 4) = o;
    *(u16x4*)(xbf + (size_t)bl * 512 + t * 4) = f2bf4(o);
}

// ------- causal depthwise conv (k=4) + bias + SiLU -> bf16 (xh | B/C) -------
__global__ void k_conv(const float* __restrict__ zx, const float* __restrict__ cw,
                       const float* __restrict__ cb, u16* __restrict__ xhbf,
                       u16* __restrict__ bcbf) {
    int idx = blockIdx.x * 256 + threadIdx.x;   // over 8*1024*320 = 2621440
    int c4 = (idx % 320) * 4;
    int bl = idx / 320;
    int l  = bl & 1023;
    float4 acc = *(const float4*)(cb + c4);
#pragma unroll
    for (int k = 0; k < 4; k++) {
        if (l + k - 3 >= 0) {
            float4 v = *(const float4*)(zx + (size_t)(bl + k - 3) * 2320 + 1024 + c4);
            acc.x = fmaf(v.x, cw[(c4 + 0) * 4 + k], acc.x);
            acc.y = fmaf(v.y, cw[(c4 + 1) * 4 + k], acc.y);
            acc.z = fmaf(v.z, cw[(c4 + 2) * 4 + k], acc.z);
            acc.w = fmaf(v.w, cw[(c4 + 3) * 4 + k], acc.w);
        }
    }
    float4 o = make_float4(siluf(acc.x), siluf(acc.y), siluf(acc.z), siluf(acc.w));
    if (c4 < 1024)
        *(u16x4*)(xhbf + (size_t)bl * 1024 + c4) = f2bf4(o);
    else
        *(u16x4*)(bcbf + (size_t)bl * 256 + (c4 - 1024)) = f2bf4(o);
}

// Sc / h_start overlay into zx's dead region (cols 1024..2047)
__device__ __forceinline__ float* sc_addr(float* zx, size_t f) {
    return zx + (f >> 10) * 2320 + 1024 + (f & 1023);
}
__device__ __forceinline__ const float* sc_addr_c(const float* zx, size_t f) {
    return zx + (f >> 10) * 2320 + 1024 + (f & 1023);
}

// ============ fused SSD intra (+ inline dt-softplus + cumsum + exp->elbuf) ====
__global__ __launch_bounds__(256) void k_ssd(
    const u16* __restrict__ xhbf, const u16* __restrict__ bcbf,
    const float* __restrict__ dtbias, const float* __restrict__ alog,
    float* __restrict__ elbuf, float* __restrict__ y, float* zx) {
    int bhc = blockIdx.x;                 // (b*16+h)*8+c
    int c = bhc & 7, h = (bhc >> 3) & 15, b = bhc >> 7;
    const size_t row0 = (size_t)b * 1024 + c * 128;
    const int t = threadIdx.x, w = t >> 6, l = t & 63;
    const int wr = w >> 1, wc = w & 1;
    const int lr = l & 15, lk8 = (l >> 4) * 8;

    __shared__ float cl[128], dtl[128], wv[128];
    __shared__ float csh;
    __shared__ __align__(16) u16 shA[8704];
    __shared__ __align__(16) u16 shB[17408];

    // ---- dt = softplus(zx_dt + bias); cl = cumsum(dt*A); elbuf = exp(cl)
    float A = -__expf(alog[h]);
    float v = 0.f;
    if (t < 128) {
        float raw = zx[(row0 + t) * 2320 + 2304 + h] + dtbias[h];
        float s = (raw > 20.f) ? raw : log1pf(__expf(raw));
        dtl[t] = s;
        v = s * A;
        int lane = t & 63;
#pragma unroll
        for (int off = 1; off < 64; off <<= 1) {
            float o = __shfl_up(v, off, 64);
            if (lane >= off) v += o;
        }
        if (t == 63) csh = v;
    }
    __syncthreads();
    if (t >= 64 && t < 128) v += csh;
    if (t < 128) {
        cl[t] = v;
        elbuf[(size_t)bhc * 128 + t] = __expf(v);
    }
    __syncthreads();
    if (t < 128) wv[t] = __expf(cl[127] - cl[t]);

    // ---- phase 1: S = C.B^T  (M=l 128, N=j 128, K=n 128)
    f32x4 acc[4][4] = {};
    for (int ks = 0; ks < 4; ks++) {
        int k0 = ks * 32;
#pragma unroll
        for (int s = 0; s < 2; s++) {
            int g = w * 2 + s;
            GLOAD_LDS16(bcbf + (row0 + g * 16 + lr) * 256 + 128 + k0 + lk8, &shA[g * 512]);
            GLOAD_LDS16(bcbf + (row0 + g * 16 + lr) * 256 +       k0 + lk8, &shA[4096 + g * 512]);
        }
        __syncthreads();
        s16x8 af[4], bfr[4];
#pragma unroll
        for (int i = 0; i < 4; i++) {
            af[i]  = *(const s16x8*)&shA[(wr * 4 + i) * 512 + l * 8];
            bfr[i] = *(const s16x8*)&shA[4096 + (wc * 4 + i) * 512 + l * 8];
        }
#pragma unroll
        for (int i = 0; i < 4; i++)
#pragma unroll
            for (int j = 0; j < 4; j++)
                acc[i][j] = __builtin_amdgcn_mfma_f32_16x16x32_bf16(af[i], bfr[j], acc[i][j], 0, 0, 0);
        __syncthreads();
    }

    // ---- UT build: UT[p][j] = dt[j]*x[j][p], bf16
#pragma unroll
    for (int jj = 0; jj < 32; jj++) {
        int j = jj * 4 + w;
        float xv = bf2f(xhbf[(row0 + j) * 1024 + h * 64 + l]);
        shA[l * 136 + j] = f2bf(dtl[j] * xv);
    }
    __syncthreads();

    // ---- phase 2: y = P.U  (M=l 128, N=p 64, K=j 128), P in 64-col halves
    f32x4 acc2[4][2] = {};
    for (int half = 0; half < 2; half++) {
        if (wc == half) {
#pragma unroll
            for (int i = 0; i < 4; i++) {
#pragma unroll
                for (int j = 0; j < 4; j++) {
                    int col = half * 64 + j * 16 + (l & 15);
#pragma unroll
                    for (int r = 0; r < 4; r++) {
                        int row = wr * 64 + i * 16 + (l >> 4) * 4 + r;
                        float e = __expf(fminf(cl[row] - cl[col], 0.f));
                        float pv = (col <= row) ? acc[i][j][r] * e : 0.f;
                        shB[row * 72 + j * 16 + (l & 15)] = f2bf(pv);
                    }
                }
            }
        }
        __syncthreads();
#pragma unroll
        for (int ks = 0; ks < 2; ks++) {
            int kof = ks * 32;
            s16x8 pa[4], ub[2];
#pragma unroll
            for (int i = 0; i < 4; i++)
                pa[i] = *(const s16x8*)&shB[(wr * 64 + i * 16 + lr) * 72 + kof + lk8];
#pragma unroll
            for (int jj = 0; jj < 2; jj++)
                ub[jj] = *(const s16x8*)&shA[(wc * 32 + jj * 16 + lr) * 136 + half * 64 + kof + lk8];
#pragma unroll
            for (int i = 0; i < 4; i++)
#pragma unroll
                for (int jj = 0; jj < 2; jj++)
                    acc2[i][jj] = __builtin_amdgcn_mfma_f32_16x16x32_bf16(pa[i], ub[jj], acc2[i][jj], 0, 0, 0);
        }
        __syncthreads();
    }
    // store y_intra
#pragma unroll
    for (int i = 0; i < 4; i++)
#pragma unroll
        for (int jj = 0; jj < 2; jj++) {
            int p = wc * 32 + jj * 16 + (l & 15);
#pragma unroll
            for (int r = 0; r < 4; r++) {
                int row = wr * 64 + i * 16 + (l >> 4) * 4 + r;
                y[(row0 + row) * 1024 + h * 64 + p] = acc2[i][jj][r];
            }
        }

    // ---- BTw build (overwrites P): BTw[n][j] = w[j]*B[j][n], bf16
#pragma unroll
    for (int s = 0; s < 64; s++) {
        int j = s * 2 + (w & 1);
        int n = (w >> 1) * 64 + l;
        float bvv = bf2f(bcbf[(row0 + j) * 256 + n]);
        shB[n * 136 + j] = f2bf(wv[j] * bvv);
    }
    __syncthreads();

    // ---- phase 3: Sc = UT.(BTw) NT  (M=p 64, N=n 128, K=j 128)
    f32x4 acc3[4][2] = {};
#pragma unroll
    for (int ks = 0; ks < 4; ks++) {
        int kof = ks * 32;
        s16x8 ua[4], bb[2];
#pragma unroll
        for (int i = 0; i < 4; i++)
            ua[i] = *(const s16x8*)&shA[(i * 16 + lr) * 136 + kof + lk8];
#pragma unroll
        for (int jj = 0; jj < 2; jj++)
            bb[jj] = *(const s16x8*)&shB[(w * 32 + jj * 16 + lr) * 136 + kof + lk8];
#pragma unroll
        for (int i = 0; i < 4; i++)
#pragma unroll
            for (int jj = 0; jj < 2; jj++)
                acc3[i][jj] = __builtin_amdgcn_mfma_f32_16x16x32_bf16(ua[i], bb[jj], acc3[i][jj], 0, 0, 0);
    }
#pragma unroll
    for (int i = 0; i < 4; i++)
#pragma unroll
        for (int jj = 0; jj < 2; jj++) {
            int n = w * 32 + jj * 16 + (l & 15);
#pragma unroll
            for (int r = 0; r < 4; r++) {
                int p = i * 16 + (l >> 4) * 4 + r;
                *sc_addr(zx, (size_t)bhc * 8192 + (size_t)p * 128 + n) = acc3[i][jj][r];
            }
        }
}

// sequential chunk-state recurrence (in place on overlay)
__global__ __launch_bounds__(512) void k_states(float* __restrict__ zx,
                                                const float* __restrict__ elbuf) {
    int bh = blockIdx.x;                  // b*16+h
    int t = threadIdx.x;
    float4 h0 = {0, 0, 0, 0}, h1 = h0, h2 = h0, h3 = h0;
    size_t o = (size_t)t * 16;
    for (int c = 0; c < 8; c++) {
        int bhc = bh * 8 + c;
        float Tc = elbuf[(size_t)bhc * 128 + 127];
        float* p = sc_addr(zx, (size_t)bhc * 8192 + o);
        float4 s0 = *(float4*)(p + 0), s1 = *(float4*)(p + 4);
        float4 s2 = *(float4*)(p + 8), s3 = *(float4*)(p + 12);
        *(float4*)(p + 0) = h0; *(float4*)(p + 4) = h1;
        *(float4*)(p + 8) = h2; *(float4*)(p + 12) = h3;
        h0.x = fmaf(Tc, h0.x, s0.x); h0.y = fmaf(Tc, h0.y, s0.y);
        h0.z = fmaf(Tc, h0.z, s0.z); h0.w = fmaf(Tc, h0.w, s0.w);
        h1.x = fmaf(Tc, h1.x, s1.x); h1.y = fmaf(Tc, h1.y, s1.y);
        h1.z = fmaf(Tc, h1.z, s1.z); h1.w = fmaf(Tc, h1.w, s1.w);
        h2.x = fmaf(Tc, h2.x, s2.x); h2.y = fmaf(Tc, h2.y, s2.y);
        h2.z = fmaf(Tc, h2.z, s2.z); h2.w = fmaf(Tc, h2.w, s2.w);
        h3.x = fmaf(Tc, h3.x, s3.x); h3.y = fmaf(Tc, h3.y, s3.y);
        h3.z = fmaf(Tc, h3.z, s3.z); h3.w = fmaf(Tc, h3.w, s3.w);
    }
}

// ============ inter-chunk: y += el[l] * (C @ h_start^T) + D*x  (MFMA)
__global__ __launch_bounds__(256) void k_inter(
    const u16* __restrict__ xhbf, const u16* __restrict__ bcbf,
    const float* __restrict__ elbuf, const float* __restrict__ zx,
    const float* __restrict__ Dp, float* __restrict__ y) {
    int bhc = blockIdx.x;
    int c = bhc & 7, h = (bhc >> 3) & 15, b = bhc >> 7;
    const size_t row0 = (size_t)b * 1024 + c * 128;
    const int t = threadIdx.x, w = t >> 6, l = t & 63;
    const int wr = w >> 1, wc = w & 1;
    const int lr = l & 15, lk8 = (l >> 4) * 8;
    __shared__ __align__(16) u16 CStg[4096];
    __shared__ __align__(16) u16 HStg[2048];
    __shared__ float el[128];
    if (t < 128) el[t] = elbuf[(size_t)bhc * 128 + t];
    float Dv = Dp[h];

    f32x4 acc[4][2] = {};
    for (int ks = 0; ks < 4; ks++) {
        int k0 = ks * 32;
#pragma unroll
        for (int s = 0; s < 2; s++) {
            int g = w * 2 + s;
            GLOAD_LDS16(bcbf + (row0 + g * 16 + lr) * 256 + 128 + k0 + lk8, &CStg[g * 512]);
        }
        {   // stage H (f32 overlay -> bf16 frag layout)
            int g = t >> 6, pr = (t >> 2) & 15, kq = t & 3;
            int p = g * 16 + pr;
            const float* src = sc_addr_c(zx, (size_t)bhc * 8192 + (size_t)p * 128 + k0 + kq * 8);
            float4 v0 = *(const float4*)src;
            float4 v1 = *(const float4*)(src + 4);
            s16x8 hv;
            hv[0] = (short)f2bf(v0.x); hv[1] = (short)f2bf(v0.y);
            hv[2] = (short)f2bf(v0.z); hv[3] = (short)f2bf(v0.w);
            hv[4] = (short)f2bf(v1.x); hv[5] = (short)f2bf(v1.y);
            hv[6] = (short)f2bf(v1.z); hv[7] = (short)f2bf(v1.w);
            *(s16x8*)&HStg[g * 512 + kq * 128 + pr * 8] = hv;
        }
        __syncthreads();
        s16x8 ca[4], hb[2];
#pragma unroll
        for (int i = 0; i < 4; i++)
            ca[i] = *(const s16x8*)&CStg[(wr * 4 + i) * 512 + l * 8];
#pragma unroll
        for (int jj = 0; jj < 2; jj++)
            hb[jj] = *(const s16x8*)&HStg[(wc * 2 + jj) * 512 + l * 8];
#pragma unroll
        for (int i = 0; i < 4; i++)
#pragma unroll
            for (int jj = 0; jj < 2; jj++)
                acc[i][jj] = __builtin_amdgcn_mfma_f32_16x16x32_bf16(ca[i], hb[jj], acc[i][jj], 0, 0, 0);
        __syncthreads();
    }
#pragma unroll
    for (int i = 0; i < 4; i++)
#pragma unroll
        for (int jj = 0; jj < 2; jj++) {
            int p = wc * 32 + jj * 16 + (l & 15);
#pragma unroll
            for (int r = 0; r < 4; r++) {
                int lrow = wr * 64 + i * 16 + (l >> 4) * 4 + r;
                size_t yo = (row0 + lrow) * 1024 + h * 64 + p;
                y[yo] += el[lrow] * acc[i][jj][r]
                       + Dv * bf2f(xhbf[(row0 + lrow) * 1024 + h * 64 + p]);
            }
        }
}

// ---------------- gate: ybf = bf16(rmsnorm(y * silu(z)) * norm_w) ----------------
__global__ __launch_bounds__(256) void k_gate(
    const float* __restrict__ y, const float* __restrict__ zx,
    const float* __restrict__ nw, u16* __restrict__ ybf) {
    __shared__ float sbuf[4];
    int bl = blockIdx.x;
    int t  = threadIdx.x;
    float4 yv = *(const float4*)(y + (size_t)bl * 1024 + t * 4);
    float4 zv = *(const float4*)(zx + (size_t)bl * 2320 + t * 4);
    float4 gv;
    gv.x = yv.x * siluf(zv.x);
    gv.y = yv.y * siluf(zv.y);
    gv.z = yv.z * siluf(zv.z);
    gv.w = yv.w * siluf(zv.w);
    float q = gv.x * gv.x + gv.y * gv.y + gv.z * gv.z + gv.w * gv.w;
    for (int off = 32; off; off >>= 1) q += __shfl_xor(q, off, 64);
    int wid = t >> 6, lane = t & 63;
    if (lane == 0) sbuf[wid] = q;
    __syncthreads();
    float tot = sbuf[0] + sbuf[1] + sbuf[2] + sbuf[3];
    float scale = 1.0f / sqrtf(tot * (1.f / 1024.f) + EPS);
    float4 nv = *(const float4*)(nw + t * 4);
    float4 o;
    o.x = gv.x * scale * nv.x;
    o.y = gv.y * scale * nv.y;
    o.z = gv.z * scale * nv.z;
    o.w = gv.w * scale * nv.w;
    *(u16x4*)(ybf + (size_t)bl * 1024 + t * 4) = f2bf4(o);
}

// ---------------- pool stage 1: per (b, 16-row chunk) partial sum/max ----------
__global__ __launch_bounds__(256) void k_pool1(const float* __restrict__ x,
                                               float* __restrict__ psum,
                                               float* __restrict__ pmax) {
    int blk = blockIdx.x;          // b*64 + lc
    int b = blk >> 6, lc = blk & 63;
    int t = threadIdx.x;
    const float* px = x + (size_t)b * 524288 + (size_t)lc * 16 * 512;
    float s0 = 0.f, s1 = 0.f, m0 = -3.0e38f, m1 = -3.0e38f;
#pragma unroll
    for (int r = 0; r < 16; r++) {
        float v0 = px[r * 512 + t];
        float v1 = px[r * 512 + t + 256];
        s0 += v0; s1 += v1;
        m0 = fmaxf(m0, v0); m1 = fmaxf(m1, v1);
    }
    psum[(size_t)blk * 512 + t]       = s0;
    psum[(size_t)blk * 512 + t + 256] = s1;
    pmax[(size_t)blk * 512 + t]       = m0;
    pmax[(size_t)blk * 512 + t + 256] = m1;
}

// ---------------- pool stage 2: combine 64 chunks ----------------
__global__ __launch_bounds__(256) void k_pool2(const float* __restrict__ psum,
                                               const float* __restrict__ pmax,
                                               float* __restrict__ pooled) {
    int idx = blockIdx.x * 256 + threadIdx.x;   // 4096 exact
    int b = idx >> 9, d = idx & 511;
    float s = 0.f, m = -3.0e38f;
    for (int c = 0; c < 64; c++) {
        s += psum[((size_t)b * 64 + c) * 512 + d];
        m = fmaxf(m, pmax[((size_t)b * 64 + c) * 512 + d]);
    }
    pooled[idx] = 0.5f * (s * (1.f / 1024.f) + m);
}

// ---------------- small FC ----------------
template <int ACT>
__global__ void k_fc(const float* __restrict__ in, const float* __restrict__ W,
                     const float* __restrict__ bias, float* __restrict__ out,
                     int BN, int N, int K) {
    int idx = blockIdx.x * 64 + threadIdx.x;
    if (idx >= BN) return;
    int b = idx / N, n = idx % N;
    const float* a = in + (size_t)b * K;
    const float* w = W + (size_t)n * K;
    float acc = 0.f;
    for (int k = 0; k < K; k += 4) {
        float4 av = *(const float4*)(a + k);
        float4 wv = *(const float4*)(w + k);
        acc += av.x * wv.x + av.y * wv.y + av.z * wv.z + av.w * wv.w;
    }
    float v = acc + bias[n];
    if (ACT == 1) v = geluf(v);
    out[idx] = v;
}

extern "C" void kernel_launch(void* const* d_in, const int* in_sizes, int n_in,
                              void* d_out, int out_size, void* d_ws, size_t ws_size,
                              hipStream_t stream) {
    (void)in_sizes; (void)n_in; (void)out_size; (void)ws_size;
    const int*   tok        = (const int*)  d_in[0];
    const float* mask       = (const float*)d_in[1];
    const float* emb        = (const float*)d_in[2];
    const float* pos        = (const float*)d_in[3];
    const float* inp_w      = (const float*)d_in[4];
    const float* inp_b      = (const float*)d_in[5];
    const float* ln_g       = (const float*)d_in[6];
    const float* ln_b       = (const float*)d_in[7];
    const float* in_proj_w  = (const float*)d_in[8];
    const float* conv_w     = (const float*)d_in[9];
    const float* conv_b     = (const float*)d_in[10];
    const float* dt_bias    = (const float*)d_in[11];
    const float* A_log      = (const float*)d_in[12];
    const float* Dparam     = (const float*)d_in[13];
    const float* norm_w     = (const float*)d_in[14];
    const float* out_proj_w = (const float*)d_in[15];
    const float* pooler_w   = (const float*)d_in[16];
    const float* pooler_b   = (const float*)d_in[17];
    const float* cls_w1     = (const float*)d_in[18];
    const float* cls_b1     = (const float*)d_in[19];
    const float* cls_w2     = (const float*)d_in[20];
    const float* cls_b2     = (const float*)d_in[21];
    float* out = (float*)d_out;

    float* ws    = (float*)d_ws;
    float* x     = ws;                                 // 8192*512
    float* zx    = x + (size_t)8192 * 512;             // 8192*2320
    float* y     = zx + (size_t)8192 * 2320;           // 8192*1024
    float* elbuf = y + (size_t)8192 * 1024;            // 131072
    float* psum  = elbuf + 131072;                     // 262144
    float* pmax  = psum + 262144;                      // 262144
    float* pooled = pmax + 262144;                     // 4096
    float* pbuf   = pooled + 4096;                     // 4096
    float* cbuf   = pbuf + 4096;                       // 2048
    u16* x_bf    = (u16*)(cbuf + 2048);                // 8192*512
    u16* xhbf    = x_bf + (size_t)8192 * 512;          // 8192*1024
    u16* y_bf    = xhbf + (size_t)8192 * 1024;         // 8192*1024
    u16* bcbf    = y_bf + (size_t)8192 * 1024;         // 8192*256
    u16* wip_bf  = bcbf + (size_t)8192 * 256;          // 4*2432*512
    u16* wop_bf  = wip_bf + (size_t)4 * 2432 * 512;    // 4*512*1024
    u16* winp_bf = wop_bf + (size_t)4 * 512 * 1024;    // 512*512
    // overlay (dead region during prologue)
    u16* xe_bf = (u16*)zx;

    // weight casts
    k_cast_pad<<<4864, 256, 0, stream>>>(in_proj_w, wip_bf);
    k_cast<<<2048, 256, 0, stream>>>(out_proj_w, wop_bf, 524288);
    k_cast<<<256, 256, 0, stream>>>(inp_w, winp_bf, 65536);

    // embedding + positional (bf16)
    k_embed<<<4096, 256, 0, stream>>>(tok, emb, pos, xe_bf);
    {   // x = embed @ inp_w^T + inp_b
        dim3 g(4, 64);
        k_gemm_mfma<1><<<g, 256, 0, stream>>>(xe_bf, winp_bf, inp_b, x, nullptr,
                                              nullptr, 8192, 512, 512);
    }
    k_layernorm<<<8192, 128, 0, stream>>>(x, ln_g, ln_b, mask, x_bf);

    for (int i = 0; i < 4; i++) {
        {   // zx = x @ in_proj_w[i]^T
            dim3 g(19, 64);
            k_gemm_mfma<0><<<g, 256, 0, stream>>>(x_bf, wip_bf + (size_t)i * 2432 * 512,
                                                  nullptr, zx, nullptr, nullptr,
                                                  8192, 2320, 512);
        }
        k_conv<<<10240, 256, 0, stream>>>(zx, conv_w + (size_t)i * 1280 * 4,
                                          conv_b + (size_t)i * 1280, xhbf, bcbf);
        k_ssd<<<1024, 256, 0, stream>>>(xhbf, bcbf, dt_bias + i * 16, A_log + i * 16,
                                        elbuf, y, zx);
        k_states<<<128, 512, 0, stream>>>(zx, elbuf);
        k_inter<<<1024, 256, 0, stream>>>(xhbf, bcbf, elbuf, zx,
                                          Dparam + (size_t)i * 16, y);
        k_gate<<<8192, 256, 0, stream>>>(y, zx, norm_w + (size_t)i * 1024, y_bf);
        {   // x = (x + y @ out_proj_w[i]^T) * mask ; x_bf mirror
            dim3 g(4, 64);
            k_gemm_mfma<2><<<g, 256, 0, stream>>>(y_bf, wop_bf + (size_t)i * 512 * 1024,
                                                  nullptr, x, x_bf, mask,
                                                  8192, 512, 1024);
        }
    }

    k_pool1<<<512, 256, 0, stream>>>(x, psum, pmax);
    k_pool2<<<16, 256, 0, stream>>>(psum, pmax, pooled);
    k_fc<1><<<64, 64, 0, stream>>>(pooled, pooler_w, pooler_b, pbuf, 8 * 512, 512, 512);
    k_fc<1><<<32, 64, 0, stream>>>(pbuf, cls_w1, cls_b1, cbuf, 8 * 256, 256, 512);
    k_fc<0><<<1, 64, 0, stream>>>(cbuf, cls_w2, cls_b2, out, 8 * 2, 2, 256);
}

// Round 6
// 1047.779 us; speedup vs baseline: 5.6684x; 1.1633x over previous
//
#include <hip/hip_runtime.h>

#define EPS 1e-5f
typedef unsigned short u16;
typedef short s16x8 __attribute__((ext_vector_type(8)));
typedef float f32x4 __attribute__((ext_vector_type(4)));

__device__ __forceinline__ float siluf(float x) { return x / (1.0f + __expf(-x)); }
__device__ __forceinline__ float geluf(float x) {
    float u = 0.7978845608028654f * (x + 0.044715f * x * x * x);
    return 0.5f * x * (1.0f + tanhf(u));
}
__device__ __forceinline__ u16 f2bf(float f) {
    unsigned u = __float_as_uint(f);
    return (u16)((u + 0x7fffu + ((u >> 16) & 1u)) >> 16);
}
__device__ __forceinline__ float bf2f(u16 v) {
    return __uint_as_float(((unsigned)v) << 16);
}
struct u16x4 { u16 x, y, z, w; };
__device__ __forceinline__ u16x4 f2bf4(float4 v) {
    u16x4 r; r.x = f2bf(v.x); r.y = f2bf(v.y); r.z = f2bf(v.z); r.w = f2bf(v.w);
    return r;
}

#define GLOAD_LDS16(gp, lp) __builtin_amdgcn_global_load_lds( \
    (const __attribute__((address_space(1))) void*)(gp),      \
    (__attribute__((address_space(3))) void*)(lp), 16, 0, 0)

// ---------------- weight casts ----------------
__global__ void k_cast_pad(const float* __restrict__ src, u16* __restrict__ dst) {
    int idx = blockIdx.x * 256 + threadIdx.x;    // over 4*2432*512/4 = 1245184
    if (idx >= 1245184) return;
    int e4 = idx * 4;
    int layer = e4 / 1245184;
    int rem   = e4 - layer * 1245184;
    int row   = rem >> 9;
    int k     = rem & 511;
    float4 v = make_float4(0.f, 0.f, 0.f, 0.f);
    if (row < 2320)
        v = *(const float4*)(src + (size_t)layer * 1187840 + (size_t)row * 512 + k);
    *(u16x4*)(dst + e4) = f2bf4(v);
}
__global__ void k_cast(const float* __restrict__ src, u16* __restrict__ dst, int n4) {
    int idx = blockIdx.x * 256 + threadIdx.x;
    if (idx >= n4) return;
    float4 v = *(const float4*)(src + (size_t)idx * 4);
    *(u16x4*)(dst + (size_t)idx * 4) = f2bf4(v);
}

// ---------------- embedding + positional -> bf16 ----------------
__global__ void k_embed(const int* __restrict__ tok, const float* __restrict__ emb,
                        const float* __restrict__ pos, u16* __restrict__ out) {
    int idx = blockIdx.x * 256 + threadIdx.x;   // over 8192*512/4 = 1048576
    int d4 = idx & 127;
    int bl = idx >> 7;
    int l  = bl & 1023;
    float4 e = *(const float4*)(emb + tok[bl] * 512 + d4 * 4);
    float4 p = *(const float4*)(pos + l * 512 + d4 * 4);
    float4 v = make_float4(e.x + p.x, e.y + p.y, e.z + p.z, e.w + p.w);
    *(u16x4*)(out + (size_t)idx * 4) = f2bf4(v);
}

// ---------------- MFMA GEMM NT (projections) ----------------
// MODE 0: plain f32 store   MODE 1: +bias[n]
// MODE 2: C=(C+acc)*mask[m], bf16 mirror Cbf
// MODE 3: split in_proj: n<1024 -> C (f32, ld 1024); 1024<=n<2304 -> Cbf (bf16, ld 1280);
//         2304<=n<2320 -> dtw (f32, ld 16)
template <int MODE>
__global__ __launch_bounds__(256) void k_gemm_mfma(
    const u16* __restrict__ A, const u16* __restrict__ B,
    const float* __restrict__ bias, float* __restrict__ C,
    u16* __restrict__ Cbf, const float* __restrict__ mask,
    float* __restrict__ dtw, int M, int N, int K) {
    __shared__ u16 Asm[4096];   // 8 groups x [kb4][row16][8]
    __shared__ u16 Bsm[4096];
    const int t = threadIdx.x;
    const int w = t >> 6, l = t & 63;
    const int wr = w >> 1, wc = w & 1;
    const int lr = l & 15, lk = (l >> 4) * 8;
    const int m0 = blockIdx.y * 128;
    const int n0 = blockIdx.x * 128;

    f32x4 acc[4][4] = {};

    for (int k0 = 0; k0 < K; k0 += 32) {
#pragma unroll
        for (int s = 0; s < 2; s++) {
            int g = w * 2 + s;
            const u16* ga = A + (size_t)(m0 + g * 16 + lr) * K + k0 + lk;
            GLOAD_LDS16(ga, &Asm[g * 512]);
            const u16* gb = B + (size_t)(n0 + g * 16 + lr) * K + k0 + lk;
            GLOAD_LDS16(gb, &Bsm[g * 512]);
        }
        __syncthreads();
        s16x8 af[4], bfr[4];
#pragma unroll
        for (int i = 0; i < 4; i++) {
            af[i]  = *(const s16x8*)&Asm[(wr * 4 + i) * 512 + l * 8];
            bfr[i] = *(const s16x8*)&Bsm[(wc * 4 + i) * 512 + l * 8];
        }
#pragma unroll
        for (int i = 0; i < 4; i++)
#pragma unroll
            for (int j = 0; j < 4; j++)
                acc[i][j] = __builtin_amdgcn_mfma_f32_16x16x32_bf16(af[i], bfr[j], acc[i][j], 0, 0, 0);
        __syncthreads();
    }

#pragma unroll
    for (int i = 0; i < 4; i++) {
        int mb = m0 + wr * 64 + i * 16 + (l >> 4) * 4;
#pragma unroll
        for (int j = 0; j < 4; j++) {
            int n = n0 + wc * 64 + j * 16 + (l & 15);
#pragma unroll
            for (int r = 0; r < 4; r++) {
                int m = mb + r;
                float v = acc[i][j][r];
                if (MODE == 3) {
                    if (n < 1024)      C[(size_t)m * 1024 + n] = v;
                    else if (n < 2304) Cbf[(size_t)m * 1280 + (n - 1024)] = f2bf(v);
                    else if (n < 2320) dtw[(size_t)m * 16 + (n - 2304)] = v;
                } else if (n < N) {
                    if (MODE == 1) v += bias[n];
                    size_t o = (size_t)m * N + n;
                    if (MODE == 2) {
                        v = (C[o] + v) * mask[m];
                        Cbf[o] = f2bf(v);
                    }
                    C[o] = v;
                }
            }
        }
    }
}

// ---------------- LayerNorm + mask + bf16 mirror ----------------
__global__ __launch_bounds__(128) void k_layernorm(
    float* __restrict__ x, const float* __restrict__ g,
    const float* __restrict__ b, const float* __restrict__ mask,
    u16* __restrict__ xbf) {
    __shared__ float2 sbuf[2];
    int bl = blockIdx.x;
    int t  = threadIdx.x;
    float4 v = *(float4*)(x + (size_t)bl * 512 + t * 4);
    float s = v.x + v.y + v.z + v.w;
    float q = v.x * v.x + v.y * v.y + v.z * v.z + v.w * v.w;
    for (int off = 32; off; off >>= 1) {
        s += __shfl_xor(s, off, 64);
        q += __shfl_xor(q, off, 64);
    }
    int wid = t >> 6, lane = t & 63;
    if (lane == 0) sbuf[wid] = make_float2(s, q);
    __syncthreads();
    float ts = sbuf[0].x + sbuf[1].x;
    float tq = sbuf[0].y + sbuf[1].y;
    float mu  = ts * (1.f / 512.f);
    float var = tq * (1.f / 512.f) - mu * mu;
    float inv = 1.0f / sqrtf(var + EPS);
    float mk  = mask[bl];
    float4 gg = *(const float4*)(g + t * 4);
    float4 bb = *(const float4*)(b + t * 4);
    float4 o;
    o.x = ((v.x - mu) * inv * gg.x + bb.x) * mk;
    o.y = ((v.y - mu) * inv * gg.y + bb.y) * mk;
    o.z = ((v.z - mu) * inv * gg.z + bb.z) * mk;
    o.w = ((v.w - mu) * inv * gg.w + bb.w) * mk;
    *(float4*)(x + (size_t)bl * 512 + t * 4) = o;
    *(u16x4*)(xbf + (size_t)bl * 512 + t * 4) = f2bf4(o);
}

// --- causal depthwise conv (k=4, bf16 in) + bias + SiLU -> bf16 (xh | B/C) ---
// one block per (b,l) row; XCD-bijective swizzle keeps each batch on one XCD
__global__ __launch_bounds__(320) void k_conv(
    const u16* __restrict__ xbc_in, const float* __restrict__ cw,
    const float* __restrict__ cb, u16* __restrict__ xhbf,
    u16* __restrict__ bcbf) {
    int bid = blockIdx.x;
    int bl = (bid & 7) * 1024 + (bid >> 3);    // 8192 rows, bijective
    int l  = bl & 1023;
    int c  = threadIdx.x * 4;
    float4 w0 = *(const float4*)(cw + (c + 0) * 4);
    float4 w1 = *(const float4*)(cw + (c + 1) * 4);
    float4 w2 = *(const float4*)(cw + (c + 2) * 4);
    float4 w3 = *(const float4*)(cw + (c + 3) * 4);
    float4 a  = *(const float4*)(cb + c);
#pragma unroll
    for (int k = 0; k < 4; k++) {
        if (l + k - 3 >= 0) {
            u16x4 v = *(const u16x4*)(xbc_in + (size_t)(bl + k - 3) * 1280 + c);
            const float* wk0 = (const float*)&w0;
            const float* wk1 = (const float*)&w1;
            const float* wk2 = (const float*)&w2;
            const float* wk3 = (const float*)&w3;
            a.x = fmaf(bf2f(v.x), wk0[k], a.x);
            a.y = fmaf(bf2f(v.y), wk1[k], a.y);
            a.z = fmaf(bf2f(v.z), wk2[k], a.z);
            a.w = fmaf(bf2f(v.w), wk3[k], a.w);
        }
    }
    float4 o = make_float4(siluf(a.x), siluf(a.y), siluf(a.z), siluf(a.w));
    if (c < 1024)
        *(u16x4*)(xhbf + (size_t)bl * 1024 + c) = f2bf4(o);
    else
        *(u16x4*)(bcbf + (size_t)bl * 256 + (c - 1024)) = f2bf4(o);
}

// ============ fused SSD intra (+ inline dt-softplus + cumsum + exp->elbuf) ====
__global__ __launch_bounds__(256) void k_ssd(
    const u16* __restrict__ xhbf, const u16* __restrict__ bcbf,
    const float* __restrict__ dt_raw, const float* __restrict__ dtbias,
    const float* __restrict__ alog, float* __restrict__ elbuf,
    float* __restrict__ y, float* __restrict__ scbuf) {
    int bid = blockIdx.x;
    int bhc = (bid & 7) * 128 + (bid >> 3);   // bijective; batch b stays on one XCD
    int c = bhc & 7, h = (bhc >> 3) & 15, b = bhc >> 7;
    const size_t row0 = (size_t)b * 1024 + c * 128;
    const int t = threadIdx.x, w = t >> 6, l = t & 63;
    const int wr = w >> 1, wc = w & 1;
    const int lr = l & 15, lk8 = (l >> 4) * 8;

    __shared__ float cl[128], dtl[128], wv[128];
    __shared__ float csh;
    __shared__ __align__(16) u16 shA[8704];
    __shared__ __align__(16) u16 shB[17408];

    // ---- dt = softplus(raw + bias); cl = cumsum(dt*A); elbuf = exp(cl)
    float A = -__expf(alog[h]);
    float v = 0.f;
    if (t < 128) {
        float raw = dt_raw[(row0 + t) * 16 + h] + dtbias[h];
        float s = (raw > 20.f) ? raw : log1pf(__expf(raw));
        dtl[t] = s;
        v = s * A;
        int lane = t & 63;
#pragma unroll
        for (int off = 1; off < 64; off <<= 1) {
            float o = __shfl_up(v, off, 64);
            if (lane >= off) v += o;
        }
        if (t == 63) csh = v;
    }
    __syncthreads();
    if (t >= 64 && t < 128) v += csh;
    if (t < 128) {
        cl[t] = v;
        elbuf[(size_t)bhc * 128 + t] = __expf(v);
    }
    __syncthreads();
    if (t < 128) wv[t] = __expf(cl[127] - cl[t]);

    // ---- phase 1: S = C.B^T  (M=l 128, N=j 128, K=n 128)
    f32x4 acc[4][4] = {};
    for (int ks = 0; ks < 4; ks++) {
        int k0 = ks * 32;
#pragma unroll
        for (int s = 0; s < 2; s++) {
            int g = w * 2 + s;
            GLOAD_LDS16(bcbf + (row0 + g * 16 + lr) * 256 + 128 + k0 + lk8, &shA[g * 512]);
            GLOAD_LDS16(bcbf + (row0 + g * 16 + lr) * 256 +       k0 + lk8, &shA[4096 + g * 512]);
        }
        __syncthreads();
        s16x8 af[4], bfr[4];
#pragma unroll
        for (int i = 0; i < 4; i++) {
            af[i]  = *(const s16x8*)&shA[(wr * 4 + i) * 512 + l * 8];
            bfr[i] = *(const s16x8*)&shA[4096 + (wc * 4 + i) * 512 + l * 8];
        }
#pragma unroll
        for (int i = 0; i < 4; i++)
#pragma unroll
            for (int j = 0; j < 4; j++)
                acc[i][j] = __builtin_amdgcn_mfma_f32_16x16x32_bf16(af[i], bfr[j], acc[i][j], 0, 0, 0);
        __syncthreads();
    }

    // ---- UT build: UT[p][j] = dt[j]*x[j][p], bf16
#pragma unroll
    for (int jj = 0; jj < 32; jj++) {
        int j = jj * 4 + w;
        float xv = bf2f(xhbf[(row0 + j) * 1024 + h * 64 + l]);
        shA[l * 136 + j] = f2bf(dtl[j] * xv);
    }
    __syncthreads();

    // ---- phase 2: y = P.U  (M=l 128, N=p 64, K=j 128), P in 64-col halves
    f32x4 acc2[4][2] = {};
    for (int half = 0; half < 2; half++) {
        if (wc == half) {
#pragma unroll
            for (int i = 0; i < 4; i++) {
#pragma unroll
                for (int j = 0; j < 4; j++) {
                    int col = half * 64 + j * 16 + (l & 15);
#pragma unroll
                    for (int r = 0; r < 4; r++) {
                        int row = wr * 64 + i * 16 + (l >> 4) * 4 + r;
                        float e = __expf(fminf(cl[row] - cl[col], 0.f));
                        float pv = (col <= row) ? acc[i][j][r] * e : 0.f;
                        shB[row * 72 + j * 16 + (l & 15)] = f2bf(pv);
                    }
                }
            }
        }
        __syncthreads();
#pragma unroll
        for (int ks = 0; ks < 2; ks++) {
            int kof = ks * 32;
            s16x8 pa[4], ub[2];
#pragma unroll
            for (int i = 0; i < 4; i++)
                pa[i] = *(const s16x8*)&shB[(wr * 64 + i * 16 + lr) * 72 + kof + lk8];
#pragma unroll
            for (int jj = 0; jj < 2; jj++)
                ub[jj] = *(const s16x8*)&shA[(wc * 32 + jj * 16 + lr) * 136 + half * 64 + kof + lk8];
#pragma unroll
            for (int i = 0; i < 4; i++)
#pragma unroll
                for (int jj = 0; jj < 2; jj++)
                    acc2[i][jj] = __builtin_amdgcn_mfma_f32_16x16x32_bf16(pa[i], ub[jj], acc2[i][jj], 0, 0, 0);
        }
        __syncthreads();
    }
    // store y_intra
#pragma unroll
    for (int i = 0; i < 4; i++)
#pragma unroll
        for (int jj = 0; jj < 2; jj++) {
            int p = wc * 32 + jj * 16 + (l & 15);
#pragma unroll
            for (int r = 0; r < 4; r++) {
                int row = wr * 64 + i * 16 + (l >> 4) * 4 + r;
                y[(row0 + row) * 1024 + h * 64 + p] = acc2[i][jj][r];
            }
        }

    // ---- BTw build (overwrites P): BTw[n][j] = w[j]*B[j][n], bf16
#pragma unroll
    for (int s = 0; s < 64; s++) {
        int j = s * 2 + (w & 1);
        int n = (w >> 1) * 64 + l;
        float bvv = bf2f(bcbf[(row0 + j) * 256 + n]);
        shB[n * 136 + j] = f2bf(wv[j] * bvv);
    }
    __syncthreads();

    // ---- phase 3: Sc = UT.(BTw) NT  (M=p 64, N=n 128, K=j 128)
    f32x4 acc3[4][2] = {};
#pragma unroll
    for (int ks = 0; ks < 4; ks++) {
        int kof = ks * 32;
        s16x8 ua[4], bb[2];
#pragma unroll
        for (int i = 0; i < 4; i++)
            ua[i] = *(const s16x8*)&shA[(i * 16 + lr) * 136 + kof + lk8];
#pragma unroll
        for (int jj = 0; jj < 2; jj++)
            bb[jj] = *(const s16x8*)&shB[(w * 32 + jj * 16 + lr) * 136 + kof + lk8];
#pragma unroll
        for (int i = 0; i < 4; i++)
#pragma unroll
            for (int jj = 0; jj < 2; jj++)
                acc3[i][jj] = __builtin_amdgcn_mfma_f32_16x16x32_bf16(ua[i], bb[jj], acc3[i][jj], 0, 0, 0);
    }
#pragma unroll
    for (int i = 0; i < 4; i++)
#pragma unroll
        for (int jj = 0; jj < 2; jj++) {
            int n = w * 32 + jj * 16 + (l & 15);
#pragma unroll
            for (int r = 0; r < 4; r++) {
                int p = i * 16 + (l >> 4) * 4 + r;
                scbuf[(size_t)bhc * 8192 + (size_t)p * 128 + n] = acc3[i][jj][r];
            }
        }
}

// sequential chunk-state recurrence (in place on scbuf)
__global__ __launch_bounds__(512) void k_states(float* __restrict__ scbuf,
                                                const float* __restrict__ elbuf) {
    int bh = blockIdx.x;                  // b*16+h
    int t = threadIdx.x;
    float4 h0 = {0, 0, 0, 0}, h1 = h0, h2 = h0, h3 = h0;
    size_t o = (size_t)t * 16;
    for (int c = 0; c < 8; c++) {
        int bhc = bh * 8 + c;
        float Tc = elbuf[(size_t)bhc * 128 + 127];
        float* p = scbuf + (size_t)bhc * 8192 + o;
        float4 s0 = *(float4*)(p + 0), s1 = *(float4*)(p + 4);
        float4 s2 = *(float4*)(p + 8), s3 = *(float4*)(p + 12);
        *(float4*)(p + 0) = h0; *(float4*)(p + 4) = h1;
        *(float4*)(p + 8) = h2; *(float4*)(p + 12) = h3;
        h0.x = fmaf(Tc, h0.x, s0.x); h0.y = fmaf(Tc, h0.y, s0.y);
        h0.z = fmaf(Tc, h0.z, s0.z); h0.w = fmaf(Tc, h0.w, s0.w);
        h1.x = fmaf(Tc, h1.x, s1.x); h1.y = fmaf(Tc, h1.y, s1.y);
        h1.z = fmaf(Tc, h1.z, s1.z); h1.w = fmaf(Tc, h1.w, s1.w);
        h2.x = fmaf(Tc, h2.x, s2.x); h2.y = fmaf(Tc, h2.y, s2.y);
        h2.z = fmaf(Tc, h2.z, s2.z); h2.w = fmaf(Tc, h2.w, s2.w);
        h3.x = fmaf(Tc, h3.x, s3.x); h3.y = fmaf(Tc, h3.y, s3.y);
        h3.z = fmaf(Tc, h3.z, s3.z); h3.w = fmaf(Tc, h3.w, s3.w);
    }
}

// ============ inter-chunk: y += el[l] * (C @ h_start^T) + D*x  (MFMA)
__global__ __launch_bounds__(256) void k_inter(
    const u16* __restrict__ xhbf, const u16* __restrict__ bcbf,
    const float* __restrict__ elbuf, const float* __restrict__ scbuf,
    const float* __restrict__ Dp, float* __restrict__ y) {
    int bid = blockIdx.x;
    int bhc = (bid & 7) * 128 + (bid >> 3);
    int c = bhc & 7, h = (bhc >> 3) & 15, b = bhc >> 7;
    const size_t row0 = (size_t)b * 1024 + c * 128;
    const int t = threadIdx.x, w = t >> 6, l = t & 63;
    const int wr = w >> 1, wc = w & 1;
    const int lr = l & 15, lk8 = (l >> 4) * 8;
    __shared__ __align__(16) u16 CStg[4096];
    __shared__ __align__(16) u16 HStg[2048];
    __shared__ float el[128];
    if (t < 128) el[t] = elbuf[(size_t)bhc * 128 + t];
    float Dv = Dp[h];

    f32x4 acc[4][2] = {};
    for (int ks = 0; ks < 4; ks++) {
        int k0 = ks * 32;
#pragma unroll
        for (int s = 0; s < 2; s++) {
            int g = w * 2 + s;
            GLOAD_LDS16(bcbf + (row0 + g * 16 + lr) * 256 + 128 + k0 + lk8, &CStg[g * 512]);
        }
        {   // stage H (f32 -> bf16 frag layout)
            int g = t >> 6, pr = (t >> 2) & 15, kq = t & 3;
            int p = g * 16 + pr;
            const float* src = scbuf + (size_t)bhc * 8192 + (size_t)p * 128 + k0 + kq * 8;
            float4 v0 = *(const float4*)src;
            float4 v1 = *(const float4*)(src + 4);
            s16x8 hv;
            hv[0] = (short)f2bf(v0.x); hv[1] = (short)f2bf(v0.y);
            hv[2] = (short)f2bf(v0.z); hv[3] = (short)f2bf(v0.w);
            hv[4] = (short)f2bf(v1.x); hv[5] = (short)f2bf(v1.y);
            hv[6] = (short)f2bf(v1.z); hv[7] = (short)f2bf(v1.w);
            *(s16x8*)&HStg[g * 512 + kq * 128 + pr * 8] = hv;
        }
        __syncthreads();
        s16x8 ca[4], hb[2];
#pragma unroll
        for (int i = 0; i < 4; i++)
            ca[i] = *(const s16x8*)&CStg[(wr * 4 + i) * 512 + l * 8];
#pragma unroll
        for (int jj = 0; jj < 2; jj++)
            hb[jj] = *(const s16x8*)&HStg[(wc * 2 + jj) * 512 + l * 8];
#pragma unroll
        for (int i = 0; i < 4; i++)
#pragma unroll
            for (int jj = 0; jj < 2; jj++)
                acc[i][jj] = __builtin_amdgcn_mfma_f32_16x16x32_bf16(ca[i], hb[jj], acc[i][jj], 0, 0, 0);
        __syncthreads();
    }
#pragma unroll
    for (int i = 0; i < 4; i++)
#pragma unroll
        for (int jj = 0; jj < 2; jj++) {
            int p = wc * 32 + jj * 16 + (l & 15);
#pragma unroll
            for (int r = 0; r < 4; r++) {
                int lrow = wr * 64 + i * 16 + (l >> 4) * 4 + r;
                size_t yo = (row0 + lrow) * 1024 + h * 64 + p;
                y[yo] += el[lrow] * acc[i][jj][r]
                       + Dv * bf2f(xhbf[(row0 + lrow) * 1024 + h * 64 + p]);
            }
        }
}

// ---------------- gate: ybf = bf16(rmsnorm(y * silu(z)) * norm_w) ----------------
__global__ __launch_bounds__(256) void k_gate(
    const float* __restrict__ y, const float* __restrict__ zz,
    const float* __restrict__ nw, u16* __restrict__ ybf) {
    __shared__ float sbuf[4];
    int bl = blockIdx.x;
    int t  = threadIdx.x;
    float4 yv = *(const float4*)(y + (size_t)bl * 1024 + t * 4);
    float4 zv = *(const float4*)(zz + (size_t)bl * 1024 + t * 4);
    float4 gv;
    gv.x = yv.x * siluf(zv.x);
    gv.y = yv.y * siluf(zv.y);
    gv.z = yv.z * siluf(zv.z);
    gv.w = yv.w * siluf(zv.w);
    float q = gv.x * gv.x + gv.y * gv.y + gv.z * gv.z + gv.w * gv.w;
    for (int off = 32; off; off >>= 1) q += __shfl_xor(q, off, 64);
    int wid = t >> 6, lane = t & 63;
    if (lane == 0) sbuf[wid] = q;
    __syncthreads();
    float tot = sbuf[0] + sbuf[1] + sbuf[2] + sbuf[3];
    float scale = 1.0f / sqrtf(tot * (1.f / 1024.f) + EPS);
    float4 nv = *(const float4*)(nw + t * 4);
    float4 o;
    o.x = gv.x * scale * nv.x;
    o.y = gv.y * scale * nv.y;
    o.z = gv.z * scale * nv.z;
    o.w = gv.w * scale * nv.w;
    *(u16x4*)(ybf + (size_t)bl * 1024 + t * 4) = f2bf4(o);
}

// ---------------- pool stage 1 ----------------
__global__ __launch_bounds__(256) void k_pool1(const float* __restrict__ x,
                                               float* __restrict__ psum,
                                               float* __restrict__ pmax) {
    int blk = blockIdx.x;          // b*64 + lc
    int b = blk >> 6, lc = blk & 63;
    int t = threadIdx.x;
    const float* px = x + (size_t)b * 524288 + (size_t)lc * 16 * 512;
    float s0 = 0.f, s1 = 0.f, m0 = -3.0e38f, m1 = -3.0e38f;
#pragma unroll
    for (int r = 0; r < 16; r++) {
        float v0 = px[r * 512 + t];
        float v1 = px[r * 512 + t + 256];
        s0 += v0; s1 += v1;
        m0 = fmaxf(m0, v0); m1 = fmaxf(m1, v1);
    }
    psum[(size_t)blk * 512 + t]       = s0;
    psum[(size_t)blk * 512 + t + 256] = s1;
    pmax[(size_t)blk * 512 + t]       = m0;
    pmax[(size_t)blk * 512 + t + 256] = m1;
}

// ---------------- pool stage 2 ----------------
__global__ __launch_bounds__(256) void k_pool2(const float* __restrict__ psum,
                                               const float* __restrict__ pmax,
                                               float* __restrict__ pooled) {
    int idx = blockIdx.x * 256 + threadIdx.x;   // 4096 exact
    int b = idx >> 9, d = idx & 511;
    float s = 0.f, m = -3.0e38f;
    for (int c = 0; c < 64; c++) {
        s += psum[((size_t)b * 64 + c) * 512 + d];
        m = fmaxf(m, pmax[((size_t)b * 64 + c) * 512 + d]);
    }
    pooled[idx] = 0.5f * (s * (1.f / 1024.f) + m);
}

// ---------------- small FC ----------------
template <int ACT>
__global__ void k_fc(const float* __restrict__ in, const float* __restrict__ W,
                     const float* __restrict__ bias, float* __restrict__ out,
                     int BN, int N, int K) {
    int idx = blockIdx.x * 64 + threadIdx.x;
    if (idx >= BN) return;
    int b = idx / N, n = idx % N;
    const float* a = in + (size_t)b * K;
    const float* w = W + (size_t)n * K;
    float acc = 0.f;
    for (int k = 0; k < K; k += 4) {
        float4 av = *(const float4*)(a + k);
        float4 wv = *(const float4*)(w + k);
        acc += av.x * wv.x + av.y * wv.y + av.z * wv.z + av.w * wv.w;
    }
    float v = acc + bias[n];
    if (ACT == 1) v = geluf(v);
    out[idx] = v;
}

extern "C" void kernel_launch(void* const* d_in, const int* in_sizes, int n_in,
                              void* d_out, int out_size, void* d_ws, size_t ws_size,
                              hipStream_t stream) {
    (void)in_sizes; (void)n_in; (void)out_size; (void)ws_size;
    const int*   tok        = (const int*)  d_in[0];
    const float* mask       = (const float*)d_in[1];
    const float* emb        = (const float*)d_in[2];
    const float* pos        = (const float*)d_in[3];
    const float* inp_w      = (const float*)d_in[4];
    const float* inp_b      = (const float*)d_in[5];
    const float* ln_g       = (const float*)d_in[6];
    const float* ln_b       = (const float*)d_in[7];
    const float* in_proj_w  = (const float*)d_in[8];
    const float* conv_w     = (const float*)d_in[9];
    const float* conv_b     = (const float*)d_in[10];
    const float* dt_bias    = (const float*)d_in[11];
    const float* A_log      = (const float*)d_in[12];
    const float* Dparam     = (const float*)d_in[13];
    const float* norm_w     = (const float*)d_in[14];
    const float* out_proj_w = (const float*)d_in[15];
    const float* pooler_w   = (const float*)d_in[16];
    const float* pooler_b   = (const float*)d_in[17];
    const float* cls_w1     = (const float*)d_in[18];
    const float* cls_b1     = (const float*)d_in[19];
    const float* cls_w2     = (const float*)d_in[20];
    const float* cls_b2     = (const float*)d_in[21];
    float* out = (float*)d_out;

    float* ws     = (float*)d_ws;
    float* x      = ws;                                // 8192*512
    float* zz     = x + (size_t)8192 * 512;            // 8192*1024 (z cols, fp32)
    float* dt_raw = zz + (size_t)8192 * 1024;          // 8192*16
    float* y      = dt_raw + (size_t)8192 * 16;        // 8192*1024
    float* elbuf  = y + (size_t)8192 * 1024;           // 131072
    float* psum   = elbuf + 131072;                    // 262144
    float* pmax   = psum + 262144;                     // 262144
    float* pooled = pmax + 262144;                     // 4096
    float* pbuf   = pooled + 4096;                     // 4096
    float* cbuf   = pbuf + 4096;                       // 2048
    u16* x_bf    = (u16*)(cbuf + 2048);                // 8192*512
    u16* xbc_in  = x_bf + (size_t)8192 * 512;          // 8192*1280 (conv input bf16)
    u16* y_bf    = xbc_in + (size_t)8192 * 1280;       // 8192*1024
    u16* xhbf    = y_bf + (size_t)8192 * 1024;         // 8192*1024
    u16* bcbf    = xhbf + (size_t)8192 * 1024;         // 8192*256
    u16* wip_bf  = bcbf + (size_t)8192 * 256;          // 4*2432*512
    u16* wop_bf  = wip_bf + (size_t)4 * 2432 * 512;    // 4*512*1024
    u16* winp_bf = wop_bf + (size_t)4 * 512 * 1024;    // 512*512
    // overlays in dead windows:
    u16* xe_bf   = (u16*)zz;                           // prologue only
    float* scbuf = (float*)xbc_in;                     // 33.5MB over xbc_in+y_bf (both
                                                       // dead between k_ssd and k_gate)

    // weight casts
    k_cast_pad<<<4864, 256, 0, stream>>>(in_proj_w, wip_bf);
    k_cast<<<2048, 256, 0, stream>>>(out_proj_w, wop_bf, 524288);
    k_cast<<<256, 256, 0, stream>>>(inp_w, winp_bf, 65536);

    // embedding + positional (bf16)
    k_embed<<<4096, 256, 0, stream>>>(tok, emb, pos, xe_bf);
    {   // x = embed @ inp_w^T + inp_b
        dim3 g(4, 64);
        k_gemm_mfma<1><<<g, 256, 0, stream>>>(xe_bf, winp_bf, inp_b, x, nullptr,
                                              nullptr, nullptr, 8192, 512, 512);
    }
    k_layernorm<<<8192, 128, 0, stream>>>(x, ln_g, ln_b, mask, x_bf);

    for (int i = 0; i < 4; i++) {
        {   // split in_proj: zz (f32) | xbc_in (bf16) | dt_raw (f32)
            dim3 g(19, 64);
            k_gemm_mfma<3><<<g, 256, 0, stream>>>(x_bf, wip_bf + (size_t)i * 2432 * 512,
                                                  nullptr, zz, xbc_in, nullptr,
                                                  dt_raw, 8192, 2320, 512);
        }
        k_conv<<<8192, 320, 0, stream>>>(xbc_in, conv_w + (size_t)i * 1280 * 4,
                                         conv_b + (size_t)i * 1280, xhbf, bcbf);
        k_ssd<<<1024, 256, 0, stream>>>(xhbf, bcbf, dt_raw, dt_bias + i * 16,
                                        A_log + i * 16, elbuf, y, scbuf);
        k_states<<<128, 512, 0, stream>>>(scbuf, elbuf);
        k_inter<<<1024, 256, 0, stream>>>(xhbf, bcbf, elbuf, scbuf,
                                          Dparam + (size_t)i * 16, y);
        k_gate<<<8192, 256, 0, stream>>>(y, zz, norm_w + (size_t)i * 1024, y_bf);
        {   // x = (x + y @ out_proj_w[i]^T) * mask ; x_bf mirror
            dim3 g(4, 64);
            k_gemm_mfma<2><<<g, 256, 0, stream>>>(y_bf, wop_bf + (size_t)i * 512 * 1024,
                                                  nullptr, x, x_bf, mask,
                                                  nullptr, 8192, 512, 1024);
        }
    }

    k_pool1<<<512, 256, 0, stream>>>(x, psum, pmax);
    k_pool2<<<16, 256, 0, stream>>>(psum, pmax, pooled);
    k_fc<1><<<64, 64, 0, stream>>>(pooled, pooler_w, pooler_b, pbuf, 8 * 512, 512, 512);
    k_fc<1><<<32, 64, 0, stream>>>(pbuf, cls_w1, cls_b1, cbuf, 8 * 256, 256, 512);
    k_fc<0><<<1, 64, 0, stream>>>(cbuf, cls_w2, cls_b2, out, 8 * 2, 2, 256);
}

// Round 7
// 1030.933 us; speedup vs baseline: 5.7610x; 1.0163x over previous
//
#include <hip/hip_runtime.h>

#define EPS 1e-5f
typedef unsigned short u16;
typedef short s16x8 __attribute__((ext_vector_type(8)));
typedef float f32x4 __attribute__((ext_vector_type(4)));

__device__ __forceinline__ float siluf(float x) { return x / (1.0f + __expf(-x)); }
__device__ __forceinline__ float geluf(float x) {
    float u = 0.7978845608028654f * (x + 0.044715f * x * x * x);
    return 0.5f * x * (1.0f + tanhf(u));
}
__device__ __forceinline__ u16 f2bf(float f) {
    unsigned u = __float_as_uint(f);
    return (u16)((u + 0x7fffu + ((u >> 16) & 1u)) >> 16);
}
__device__ __forceinline__ float bf2f(u16 v) {
    return __uint_as_float(((unsigned)v) << 16);
}
struct u16x4 { u16 x, y, z, w; };
__device__ __forceinline__ u16x4 f2bf4(float4 v) {
    u16x4 r; r.x = f2bf(v.x); r.y = f2bf(v.y); r.z = f2bf(v.z); r.w = f2bf(v.w);
    return r;
}

#define GLOAD_LDS16(gp, lp) __builtin_amdgcn_global_load_lds( \
    (const __attribute__((address_space(1))) void*)(gp),      \
    (__attribute__((address_space(3))) void*)(lp), 16, 0, 0)

// ---------------- weight casts ----------------
__global__ void k_cast_pad(const float* __restrict__ src, u16* __restrict__ dst) {
    int idx = blockIdx.x * 256 + threadIdx.x;    // over 4*2432*512/4 = 1245184
    if (idx >= 1245184) return;
    int e4 = idx * 4;
    int layer = e4 / 1245184;
    int rem   = e4 - layer * 1245184;
    int row   = rem >> 9;
    int k     = rem & 511;
    float4 v = make_float4(0.f, 0.f, 0.f, 0.f);
    if (row < 2320)
        v = *(const float4*)(src + (size_t)layer * 1187840 + (size_t)row * 512 + k);
    *(u16x4*)(dst + e4) = f2bf4(v);
}
__global__ void k_cast(const float* __restrict__ src, u16* __restrict__ dst, int n4) {
    int idx = blockIdx.x * 256 + threadIdx.x;
    if (idx >= n4) return;
    float4 v = *(const float4*)(src + (size_t)idx * 4);
    *(u16x4*)(dst + (size_t)idx * 4) = f2bf4(v);
}

// ---------------- embedding + positional -> bf16 ----------------
__global__ void k_embed(const int* __restrict__ tok, const float* __restrict__ emb,
                        const float* __restrict__ pos, u16* __restrict__ out) {
    int idx = blockIdx.x * 256 + threadIdx.x;   // over 8192*512/4 = 1048576
    int d4 = idx & 127;
    int bl = idx >> 7;
    int l  = bl & 1023;
    float4 e = *(const float4*)(emb + tok[bl] * 512 + d4 * 4);
    float4 p = *(const float4*)(pos + l * 512 + d4 * 4);
    float4 v = make_float4(e.x + p.x, e.y + p.y, e.z + p.z, e.w + p.w);
    *(u16x4*)(out + (size_t)idx * 4) = f2bf4(v);
}

// ---------------- MFMA GEMM NT (projections), 2-phase dbuf + XCD swizzle ------
// MODE 1: C = acc + bias[n] (f32)
// MODE 2: C = (C + acc) * mask[m] (f32) + bf16 mirror Cbf
// MODE 3: split in_proj: n<1024 -> zbf (bf16, ld1024); 1024<=n<2304 -> Cbf
//         (bf16, ld1280); 2304<=n<2320 -> dtw (f32, ld16)
#define STAGE(buf, k0) do {                                                     \
    _Pragma("unroll")                                                           \
    for (int s_ = 0; s_ < 2; s_++) {                                            \
        int g_ = w * 2 + s_;                                                    \
        GLOAD_LDS16(A + (size_t)(m0 + g_ * 16 + lr) * K + (k0) + lk,            \
                    &Asm[buf][g_ * 512]);                                       \
        GLOAD_LDS16(B + (size_t)(n0 + g_ * 16 + lr) * K + (k0) + lk,            \
                    &Bsm[buf][g_ * 512]);                                       \
    } } while (0)

template <int MODE>
__global__ __launch_bounds__(256) void k_gemm_mfma(
    const u16* __restrict__ A, const u16* __restrict__ B,
    const float* __restrict__ bias, float* __restrict__ C,
    u16* __restrict__ Cbf, u16* __restrict__ zbf, const float* __restrict__ mask,
    float* __restrict__ dtw, int M, int N, int K, int gx) {
    __shared__ u16 Asm[2][4096];
    __shared__ u16 Bsm[2][4096];
    const int t = threadIdx.x;
    const int w = t >> 6, l = t & 63;
    const int wr = w >> 1, wc = w & 1;
    const int lr = l & 15, lk = (l >> 4) * 8;
    // bijective XCD swizzle: each XCD gets a contiguous wgid chunk (A-panel reuse)
    const int nwg = gridDim.x;
    const int q = nwg >> 3, r = nwg & 7;
    const int x8 = blockIdx.x & 7, d8 = blockIdx.x >> 3;
    const int wgid = (x8 < r) ? x8 * (q + 1) + d8 : r * (q + 1) + (x8 - r) * q + d8;
    const int m0 = (wgid / gx) * 128;
    const int n0 = (wgid % gx) * 128;

    f32x4 acc[4][4] = {};

    STAGE(0, 0);
    __syncthreads();
    int cur = 0;
    for (int k0 = 0; k0 < K; k0 += 32) {
        if (k0 + 32 < K) STAGE(cur ^ 1, k0 + 32);
        s16x8 af[4], bfr[4];
#pragma unroll
        for (int i = 0; i < 4; i++) {
            af[i]  = *(const s16x8*)&Asm[cur][(wr * 4 + i) * 512 + l * 8];
            bfr[i] = *(const s16x8*)&Bsm[cur][(wc * 4 + i) * 512 + l * 8];
        }
#pragma unroll
        for (int i = 0; i < 4; i++)
#pragma unroll
            for (int j = 0; j < 4; j++)
                acc[i][j] = __builtin_amdgcn_mfma_f32_16x16x32_bf16(af[i], bfr[j], acc[i][j], 0, 0, 0);
        __syncthreads();
        cur ^= 1;
    }

#pragma unroll
    for (int i = 0; i < 4; i++) {
        int mb = m0 + wr * 64 + i * 16 + (l >> 4) * 4;
#pragma unroll
        for (int j = 0; j < 4; j++) {
            int n = n0 + wc * 64 + j * 16 + (l & 15);
#pragma unroll
            for (int r2 = 0; r2 < 4; r2++) {
                int m = mb + r2;
                float v = acc[i][j][r2];
                if (MODE == 3) {
                    if (n < 1024)      zbf[(size_t)m * 1024 + n] = f2bf(v);
                    else if (n < 2304) Cbf[(size_t)m * 1280 + (n - 1024)] = f2bf(v);
                    else if (n < 2320) dtw[(size_t)m * 16 + (n - 2304)] = v;
                } else if (n < N) {
                    if (MODE == 1) v += bias[n];
                    size_t o = (size_t)m * N + n;
                    if (MODE == 2) {
                        v = (C[o] + v) * mask[m];
                        Cbf[o] = f2bf(v);
                    }
                    C[o] = v;
                }
            }
        }
    }
}

// ---------------- LayerNorm + mask + bf16 mirror ----------------
__global__ __launch_bounds__(128) void k_layernorm(
    float* __restrict__ x, const float* __restrict__ g,
    const float* __restrict__ b, const float* __restrict__ mask,
    u16* __restrict__ xbf) {
    __shared__ float2 sbuf[2];
    int bl = blockIdx.x;
    int t  = threadIdx.x;
    float4 v = *(float4*)(x + (size_t)bl * 512 + t * 4);
    float s = v.x + v.y + v.z + v.w;
    float q = v.x * v.x + v.y * v.y + v.z * v.z + v.w * v.w;
    for (int off = 32; off; off >>= 1) {
        s += __shfl_xor(s, off, 64);
        q += __shfl_xor(q, off, 64);
    }
    int wid = t >> 6, lane = t & 63;
    if (lane == 0) sbuf[wid] = make_float2(s, q);
    __syncthreads();
    float ts = sbuf[0].x + sbuf[1].x;
    float tq = sbuf[0].y + sbuf[1].y;
    float mu  = ts * (1.f / 512.f);
    float var = tq * (1.f / 512.f) - mu * mu;
    float inv = 1.0f / sqrtf(var + EPS);
    float mk  = mask[bl];
    float4 gg = *(const float4*)(g + t * 4);
    float4 bb = *(const float4*)(b + t * 4);
    float4 o;
    o.x = ((v.x - mu) * inv * gg.x + bb.x) * mk;
    o.y = ((v.y - mu) * inv * gg.y + bb.y) * mk;
    o.z = ((v.z - mu) * inv * gg.z + bb.z) * mk;
    o.w = ((v.w - mu) * inv * gg.w + bb.w) * mk;
    *(float4*)(x + (size_t)bl * 512 + t * 4) = o;
    *(u16x4*)(xbf + (size_t)bl * 512 + t * 4) = f2bf4(o);
}

// --- causal depthwise conv (k=4, bf16 in) + bias + SiLU -> bf16 (xh | B/C) ---
__global__ __launch_bounds__(320) void k_conv(
    const u16* __restrict__ xbc_in, const float* __restrict__ cw,
    const float* __restrict__ cb, u16* __restrict__ xhbf,
    u16* __restrict__ bcbf) {
    int bid = blockIdx.x;
    int bl = (bid & 7) * 1024 + (bid >> 3);    // 8192 rows, bijective
    int l  = bl & 1023;
    int c  = threadIdx.x * 4;
    float4 w0 = *(const float4*)(cw + (c + 0) * 4);
    float4 w1 = *(const float4*)(cw + (c + 1) * 4);
    float4 w2 = *(const float4*)(cw + (c + 2) * 4);
    float4 w3 = *(const float4*)(cw + (c + 3) * 4);
    float4 a  = *(const float4*)(cb + c);
#pragma unroll
    for (int k = 0; k < 4; k++) {
        if (l + k - 3 >= 0) {
            u16x4 v = *(const u16x4*)(xbc_in + (size_t)(bl + k - 3) * 1280 + c);
            const float* wk0 = (const float*)&w0;
            const float* wk1 = (const float*)&w1;
            const float* wk2 = (const float*)&w2;
            const float* wk3 = (const float*)&w3;
            a.x = fmaf(bf2f(v.x), wk0[k], a.x);
            a.y = fmaf(bf2f(v.y), wk1[k], a.y);
            a.z = fmaf(bf2f(v.z), wk2[k], a.z);
            a.w = fmaf(bf2f(v.w), wk3[k], a.w);
        }
    }
    float4 o = make_float4(siluf(a.x), siluf(a.y), siluf(a.z), siluf(a.w));
    if (c < 1024)
        *(u16x4*)(xhbf + (size_t)bl * 1024 + c) = f2bf4(o);
    else
        *(u16x4*)(bcbf + (size_t)bl * 256 + (c - 1024)) = f2bf4(o);
}

// ============ fused SSD intra (+ inline dt-softplus + cumsum + exp->elbuf) ====
__global__ __launch_bounds__(256) void k_ssd(
    const u16* __restrict__ xhbf, const u16* __restrict__ bcbf,
    const float* __restrict__ dt_raw, const float* __restrict__ dtbias,
    const float* __restrict__ alog, float* __restrict__ elbuf,
    float* __restrict__ y, float* __restrict__ scbuf) {
    int bid = blockIdx.x;
    int bhc = (bid & 7) * 128 + (bid >> 3);   // bijective; batch b stays on one XCD
    int c = bhc & 7, h = (bhc >> 3) & 15, b = bhc >> 7;
    const size_t row0 = (size_t)b * 1024 + c * 128;
    const int t = threadIdx.x, w = t >> 6, l = t & 63;
    const int wr = w >> 1, wc = w & 1;
    const int lr = l & 15, lk8 = (l >> 4) * 8;

    __shared__ float cl[128], dtl[128], wv[128];
    __shared__ float csh;
    __shared__ __align__(16) u16 shA[8704];
    __shared__ __align__(16) u16 shB[17408];

    // ---- dt = softplus(raw + bias); cl = cumsum(dt*A); elbuf = exp(cl)
    float A = -__expf(alog[h]);
    float v = 0.f;
    if (t < 128) {
        float raw = dt_raw[(row0 + t) * 16 + h] + dtbias[h];
        float s = (raw > 20.f) ? raw : log1pf(__expf(raw));
        dtl[t] = s;
        v = s * A;
        int lane = t & 63;
#pragma unroll
        for (int off = 1; off < 64; off <<= 1) {
            float o = __shfl_up(v, off, 64);
            if (lane >= off) v += o;
        }
        if (t == 63) csh = v;
    }
    __syncthreads();
    if (t >= 64 && t < 128) v += csh;
    if (t < 128) {
        cl[t] = v;
        elbuf[(size_t)bhc * 128 + t] = __expf(v);
    }
    __syncthreads();
    if (t < 128) wv[t] = __expf(cl[127] - cl[t]);

    // ---- phase 1: S = C.B^T  (M=l 128, N=j 128, K=n 128)
    f32x4 acc[4][4] = {};
    for (int ks = 0; ks < 4; ks++) {
        int k0 = ks * 32;
#pragma unroll
        for (int s = 0; s < 2; s++) {
            int g = w * 2 + s;
            GLOAD_LDS16(bcbf + (row0 + g * 16 + lr) * 256 + 128 + k0 + lk8, &shA[g * 512]);
            GLOAD_LDS16(bcbf + (row0 + g * 16 + lr) * 256 +       k0 + lk8, &shA[4096 + g * 512]);
        }
        __syncthreads();
        s16x8 af[4], bfr[4];
#pragma unroll
        for (int i = 0; i < 4; i++) {
            af[i]  = *(const s16x8*)&shA[(wr * 4 + i) * 512 + l * 8];
            bfr[i] = *(const s16x8*)&shA[4096 + (wc * 4 + i) * 512 + l * 8];
        }
#pragma unroll
        for (int i = 0; i < 4; i++)
#pragma unroll
            for (int j = 0; j < 4; j++)
                acc[i][j] = __builtin_amdgcn_mfma_f32_16x16x32_bf16(af[i], bfr[j], acc[i][j], 0, 0, 0);
        __syncthreads();
    }

    // ---- UT build: UT[p][j] = dt[j]*x[j][p], bf16
#pragma unroll
    for (int jj = 0; jj < 32; jj++) {
        int j = jj * 4 + w;
        float xv = bf2f(xhbf[(row0 + j) * 1024 + h * 64 + l]);
        shA[l * 136 + j] = f2bf(dtl[j] * xv);
    }
    __syncthreads();

    // ---- phase 2: y = P.U  (M=l 128, N=p 64, K=j 128), P in 64-col halves
    f32x4 acc2[4][2] = {};
    for (int half = 0; half < 2; half++) {
        if (wc == half) {
#pragma unroll
            for (int i = 0; i < 4; i++) {
#pragma unroll
                for (int j = 0; j < 4; j++) {
                    int col = half * 64 + j * 16 + (l & 15);
#pragma unroll
                    for (int r = 0; r < 4; r++) {
                        int row = wr * 64 + i * 16 + (l >> 4) * 4 + r;
                        float e = __expf(fminf(cl[row] - cl[col], 0.f));
                        float pv = (col <= row) ? acc[i][j][r] * e : 0.f;
                        shB[row * 72 + j * 16 + (l & 15)] = f2bf(pv);
                    }
                }
            }
        }
        __syncthreads();
#pragma unroll
        for (int ks = 0; ks < 2; ks++) {
            int kof = ks * 32;
            s16x8 pa[4], ub[2];
#pragma unroll
            for (int i = 0; i < 4; i++)
                pa[i] = *(const s16x8*)&shB[(wr * 64 + i * 16 + lr) * 72 + kof + lk8];
#pragma unroll
            for (int jj = 0; jj < 2; jj++)
                ub[jj] = *(const s16x8*)&shA[(wc * 32 + jj * 16 + lr) * 136 + half * 64 + kof + lk8];
#pragma unroll
            for (int i = 0; i < 4; i++)
#pragma unroll
                for (int jj = 0; jj < 2; jj++)
                    acc2[i][jj] = __builtin_amdgcn_mfma_f32_16x16x32_bf16(pa[i], ub[jj], acc2[i][jj], 0, 0, 0);
        }
        __syncthreads();
    }
    // store y_intra
#pragma unroll
    for (int i = 0; i < 4; i++)
#pragma unroll
        for (int jj = 0; jj < 2; jj++) {
            int p = wc * 32 + jj * 16 + (l & 15);
#pragma unroll
            for (int r = 0; r < 4; r++) {
                int row = wr * 64 + i * 16 + (l >> 4) * 4 + r;
                y[(row0 + row) * 1024 + h * 64 + p] = acc2[i][jj][r];
            }
        }

    // ---- BTw build (overwrites P): BTw[n][j] = w[j]*B[j][n], bf16
#pragma unroll
    for (int s = 0; s < 64; s++) {
        int j = s * 2 + (w & 1);
        int n = (w >> 1) * 64 + l;
        float bvv = bf2f(bcbf[(row0 + j) * 256 + n]);
        shB[n * 136 + j] = f2bf(wv[j] * bvv);
    }
    __syncthreads();

    // ---- phase 3: Sc = UT.(BTw) NT  (M=p 64, N=n 128, K=j 128)
    f32x4 acc3[4][2] = {};
#pragma unroll
    for (int ks = 0; ks < 4; ks++) {
        int kof = ks * 32;
        s16x8 ua[4], bb[2];
#pragma unroll
        for (int i = 0; i < 4; i++)
            ua[i] = *(const s16x8*)&shA[(i * 16 + lr) * 136 + kof + lk8];
#pragma unroll
        for (int jj = 0; jj < 2; jj++)
            bb[jj] = *(const s16x8*)&shB[(w * 32 + jj * 16 + lr) * 136 + kof + lk8];
#pragma unroll
        for (int i = 0; i < 4; i++)
#pragma unroll
            for (int jj = 0; jj < 2; jj++)
                acc3[i][jj] = __builtin_amdgcn_mfma_f32_16x16x32_bf16(ua[i], bb[jj], acc3[i][jj], 0, 0, 0);
    }
#pragma unroll
    for (int i = 0; i < 4; i++)
#pragma unroll
        for (int jj = 0; jj < 2; jj++) {
            int n = w * 32 + jj * 16 + (l & 15);
#pragma unroll
            for (int r = 0; r < 4; r++) {
                int p = i * 16 + (l >> 4) * 4 + r;
                scbuf[(size_t)bhc * 8192 + (size_t)p * 128 + n] = acc3[i][jj][r];
            }
        }
}

// sequential chunk-state recurrence (in place on scbuf)
__global__ __launch_bounds__(512) void k_states(float* __restrict__ scbuf,
                                                const float* __restrict__ elbuf) {
    int bh = blockIdx.x;                  // b*16+h
    int t = threadIdx.x;
    float4 h0 = {0, 0, 0, 0}, h1 = h0, h2 = h0, h3 = h0;
    size_t o = (size_t)t * 16;
    for (int c = 0; c < 8; c++) {
        int bhc = bh * 8 + c;
        float Tc = elbuf[(size_t)bhc * 128 + 127];
        float* p = scbuf + (size_t)bhc * 8192 + o;
        float4 s0 = *(float4*)(p + 0), s1 = *(float4*)(p + 4);
        float4 s2 = *(float4*)(p + 8), s3 = *(float4*)(p + 12);
        *(float4*)(p + 0) = h0; *(float4*)(p + 4) = h1;
        *(float4*)(p + 8) = h2; *(float4*)(p + 12) = h3;
        h0.x = fmaf(Tc, h0.x, s0.x); h0.y = fmaf(Tc, h0.y, s0.y);
        h0.z = fmaf(Tc, h0.z, s0.z); h0.w = fmaf(Tc, h0.w, s0.w);
        h1.x = fmaf(Tc, h1.x, s1.x); h1.y = fmaf(Tc, h1.y, s1.y);
        h1.z = fmaf(Tc, h1.z, s1.z); h1.w = fmaf(Tc, h1.w, s1.w);
        h2.x = fmaf(Tc, h2.x, s2.x); h2.y = fmaf(Tc, h2.y, s2.y);
        h2.z = fmaf(Tc, h2.z, s2.z); h2.w = fmaf(Tc, h2.w, s2.w);
        h3.x = fmaf(Tc, h3.x, s3.x); h3.y = fmaf(Tc, h3.y, s3.y);
        h3.z = fmaf(Tc, h3.z, s3.z); h3.w = fmaf(Tc, h3.w, s3.w);
    }
}

// ============ inter-chunk: y += el[l] * (C @ h_start^T) + D*x  (MFMA)
__global__ __launch_bounds__(256) void k_inter(
    const u16* __restrict__ xhbf, const u16* __restrict__ bcbf,
    const float* __restrict__ elbuf, const float* __restrict__ scbuf,
    const float* __restrict__ Dp, float* __restrict__ y) {
    int bid = blockIdx.x;
    int bhc = (bid & 7) * 128 + (bid >> 3);
    int c = bhc & 7, h = (bhc >> 3) & 15, b = bhc >> 7;
    const size_t row0 = (size_t)b * 1024 + c * 128;
    const int t = threadIdx.x, w = t >> 6, l = t & 63;
    const int wr = w >> 1, wc = w & 1;
    const int lr = l & 15, lk8 = (l >> 4) * 8;
    __shared__ __align__(16) u16 CStg[4096];
    __shared__ __align__(16) u16 HStg[2048];
    __shared__ float el[128];
    if (t < 128) el[t] = elbuf[(size_t)bhc * 128 + t];
    float Dv = Dp[h];

    f32x4 acc[4][2] = {};
    for (int ks = 0; ks < 4; ks++) {
        int k0 = ks * 32;
#pragma unroll
        for (int s = 0; s < 2; s++) {
            int g = w * 2 + s;
            GLOAD_LDS16(bcbf + (row0 + g * 16 + lr) * 256 + 128 + k0 + lk8, &CStg[g * 512]);
        }
        {   // stage H (f32 -> bf16 frag layout)
            int g = t >> 6, pr = (t >> 2) & 15, kq = t & 3;
            int p = g * 16 + pr;
            const float* src = scbuf + (size_t)bhc * 8192 + (size_t)p * 128 + k0 + kq * 8;
            float4 v0 = *(const float4*)src;
            float4 v1 = *(const float4*)(src + 4);
            s16x8 hv;
            hv[0] = (short)f2bf(v0.x); hv[1] = (short)f2bf(v0.y);
            hv[2] = (short)f2bf(v0.z); hv[3] = (short)f2bf(v0.w);
            hv[4] = (short)f2bf(v1.x); hv[5] = (short)f2bf(v1.y);
            hv[6] = (short)f2bf(v1.z); hv[7] = (short)f2bf(v1.w);
            *(s16x8*)&HStg[g * 512 + kq * 128 + pr * 8] = hv;
        }
        __syncthreads();
        s16x8 ca[4], hb[2];
#pragma unroll
        for (int i = 0; i < 4; i++)
            ca[i] = *(const s16x8*)&CStg[(wr * 4 + i) * 512 + l * 8];
#pragma unroll
        for (int jj = 0; jj < 2; jj++)
            hb[jj] = *(const s16x8*)&HStg[(wc * 2 + jj) * 512 + l * 8];
#pragma unroll
        for (int i = 0; i < 4; i++)
#pragma unroll
            for (int jj = 0; jj < 2; jj++)
                acc[i][jj] = __builtin_amdgcn_mfma_f32_16x16x32_bf16(ca[i], hb[jj], acc[i][jj], 0, 0, 0);
        __syncthreads();
    }
#pragma unroll
    for (int i = 0; i < 4; i++)
#pragma unroll
        for (int jj = 0; jj < 2; jj++) {
            int p = wc * 32 + jj * 16 + (l & 15);
#pragma unroll
            for (int r = 0; r < 4; r++) {
                int lrow = wr * 64 + i * 16 + (l >> 4) * 4 + r;
                size_t yo = (row0 + lrow) * 1024 + h * 64 + p;
                y[yo] += el[lrow] * acc[i][jj][r]
                       + Dv * bf2f(xhbf[(row0 + lrow) * 1024 + h * 64 + p]);
            }
        }
}

// ---------------- gate: ybf = bf16(rmsnorm(y * silu(z)) * norm_w) ----------------
__global__ __launch_bounds__(256) void k_gate(
    const float* __restrict__ y, const u16* __restrict__ zbf,
    const float* __restrict__ nw, u16* __restrict__ ybf) {
    __shared__ float sbuf[4];
    int bl = blockIdx.x;
    int t  = threadIdx.x;
    float4 yv = *(const float4*)(y + (size_t)bl * 1024 + t * 4);
    u16x4 zv4 = *(const u16x4*)(zbf + (size_t)bl * 1024 + t * 4);
    float4 gv;
    gv.x = yv.x * siluf(bf2f(zv4.x));
    gv.y = yv.y * siluf(bf2f(zv4.y));
    gv.z = yv.z * siluf(bf2f(zv4.z));
    gv.w = yv.w * siluf(bf2f(zv4.w));
    float q = gv.x * gv.x + gv.y * gv.y + gv.z * gv.z + gv.w * gv.w;
    for (int off = 32; off; off >>= 1) q += __shfl_xor(q, off, 64);
    int wid = t >> 6, lane = t & 63;
    if (lane == 0) sbuf[wid] = q;
    __syncthreads();
    float tot = sbuf[0] + sbuf[1] + sbuf[2] + sbuf[3];
    float scale = 1.0f / sqrtf(tot * (1.f / 1024.f) + EPS);
    float4 nv = *(const float4*)(nw + t * 4);
    float4 o;
    o.x = gv.x * scale * nv.x;
    o.y = gv.y * scale * nv.y;
    o.z = gv.z * scale * nv.z;
    o.w = gv.w * scale * nv.w;
    *(u16x4*)(ybf + (size_t)bl * 1024 + t * 4) = f2bf4(o);
}

// ---------------- pool stage 1 ----------------
__global__ __launch_bounds__(256) void k_pool1(const float* __restrict__ x,
                                               float* __restrict__ psum,
                                               float* __restrict__ pmax) {
    int blk = blockIdx.x;          // b*64 + lc
    int b = blk >> 6, lc = blk & 63;
    int t = threadIdx.x;
    const float* px = x + (size_t)b * 524288 + (size_t)lc * 16 * 512;
    float s0 = 0.f, s1 = 0.f, m0 = -3.0e38f, m1 = -3.0e38f;
#pragma unroll
    for (int r = 0; r < 16; r++) {
        float v0 = px[r * 512 + t];
        float v1 = px[r * 512 + t + 256];
        s0 += v0; s1 += v1;
        m0 = fmaxf(m0, v0); m1 = fmaxf(m1, v1);
    }
    psum[(size_t)blk * 512 + t]       = s0;
    psum[(size_t)blk * 512 + t + 256] = s1;
    pmax[(size_t)blk * 512 + t]       = m0;
    pmax[(size_t)blk * 512 + t + 256] = m1;
}

// ---------------- pool stage 2 ----------------
__global__ __launch_bounds__(256) void k_pool2(const float* __restrict__ psum,
                                               const float* __restrict__ pmax,
                                               float* __restrict__ pooled) {
    int idx = blockIdx.x * 256 + threadIdx.x;   // 4096 exact
    int b = idx >> 9, d = idx & 511;
    float s = 0.f, m = -3.0e38f;
    for (int c = 0; c < 64; c++) {
        s += psum[((size_t)b * 64 + c) * 512 + d];
        m = fmaxf(m, pmax[((size_t)b * 64 + c) * 512 + d]);
    }
    pooled[idx] = 0.5f * (s * (1.f / 1024.f) + m);
}

// ---------------- small FC ----------------
template <int ACT>
__global__ void k_fc(const float* __restrict__ in, const float* __restrict__ W,
                     const float* __restrict__ bias, float* __restrict__ out,
                     int BN, int N, int K) {
    int idx = blockIdx.x * 64 + threadIdx.x;
    if (idx >= BN) return;
    int b = idx / N, n = idx % N;
    const float* a = in + (size_t)b * K;
    const float* w = W + (size_t)n * K;
    float acc = 0.f;
    for (int k = 0; k < K; k += 4) {
        float4 av = *(const float4*)(a + k);
        float4 wv = *(const float4*)(w + k);
        acc += av.x * wv.x + av.y * wv.y + av.z * wv.z + av.w * wv.w;
    }
    float v = acc + bias[n];
    if (ACT == 1) v = geluf(v);
    out[idx] = v;
}

extern "C" void kernel_launch(void* const* d_in, const int* in_sizes, int n_in,
                              void* d_out, int out_size, void* d_ws, size_t ws_size,
                              hipStream_t stream) {
    (void)in_sizes; (void)n_in; (void)out_size; (void)ws_size;
    const int*   tok        = (const int*)  d_in[0];
    const float* mask       = (const float*)d_in[1];
    const float* emb        = (const float*)d_in[2];
    const float* pos        = (const float*)d_in[3];
    const float* inp_w      = (const float*)d_in[4];
    const float* inp_b      = (const float*)d_in[5];
    const float* ln_g       = (const float*)d_in[6];
    const float* ln_b       = (const float*)d_in[7];
    const float* in_proj_w  = (const float*)d_in[8];
    const float* conv_w     = (const float*)d_in[9];
    const float* conv_b     = (const float*)d_in[10];
    const float* dt_bias    = (const float*)d_in[11];
    const float* A_log      = (const float*)d_in[12];
    const float* Dparam     = (const float*)d_in[13];
    const float* norm_w     = (const float*)d_in[14];
    const float* out_proj_w = (const float*)d_in[15];
    const float* pooler_w   = (const float*)d_in[16];
    const float* pooler_b   = (const float*)d_in[17];
    const float* cls_w1     = (const float*)d_in[18];
    const float* cls_b1     = (const float*)d_in[19];
    const float* cls_w2     = (const float*)d_in[20];
    const float* cls_b2     = (const float*)d_in[21];
    float* out = (float*)d_out;

    float* ws     = (float*)d_ws;
    float* x      = ws;                                // 8192*512
    float* dt_raw = x + (size_t)8192 * 512;            // 8192*16
    float* y      = dt_raw + (size_t)8192 * 16;        // 8192*1024
    float* elbuf  = y + (size_t)8192 * 1024;           // 131072
    float* psum   = elbuf + 131072;                    // 262144
    float* pmax   = psum + 262144;                     // 262144
    float* pooled = pmax + 262144;                     // 4096
    float* pbuf   = pooled + 4096;                     // 4096
    float* cbuf   = pbuf + 4096;                       // 2048
    u16* x_bf    = (u16*)(cbuf + 2048);                // 8192*512
    u16* z_bf    = x_bf + (size_t)8192 * 512;          // 8192*1024
    u16* xbc_in  = z_bf + (size_t)8192 * 1024;         // 8192*1280 (conv input bf16)
    u16* y_bf    = xbc_in + (size_t)8192 * 1280;       // 8192*1024
    u16* xhbf    = y_bf + (size_t)8192 * 1024;         // 8192*1024
    u16* bcbf    = xhbf + (size_t)8192 * 1024;         // 8192*256
    u16* wip_bf  = bcbf + (size_t)8192 * 256;          // 4*2432*512
    u16* wop_bf  = wip_bf + (size_t)4 * 2432 * 512;    // 4*512*1024
    u16* winp_bf = wop_bf + (size_t)4 * 512 * 1024;    // 512*512
    // overlays in dead windows:
    u16* xe_bf   = (u16*)y;                            // prologue only (y dead)
    float* scbuf = (float*)xbc_in;                     // 32MB over xbc_in+y_bf (both
                                                       // dead between k_ssd and k_gate)

    // weight casts
    k_cast_pad<<<4864, 256, 0, stream>>>(in_proj_w, wip_bf);
    k_cast<<<2048, 256, 0, stream>>>(out_proj_w, wop_bf, 524288);
    k_cast<<<256, 256, 0, stream>>>(inp_w, winp_bf, 65536);

    // embedding + positional (bf16)
    k_embed<<<4096, 256, 0, stream>>>(tok, emb, pos, xe_bf);
    // x = embed @ inp_w^T + inp_b
    k_gemm_mfma<1><<<256, 256, 0, stream>>>(xe_bf, winp_bf, inp_b, x, nullptr,
                                            nullptr, nullptr, nullptr,
                                            8192, 512, 512, 4);
    k_layernorm<<<8192, 128, 0, stream>>>(x, ln_g, ln_b, mask, x_bf);

    for (int i = 0; i < 4; i++) {
        // split in_proj: z_bf | xbc_in (bf16) | dt_raw (f32)
        k_gemm_mfma<3><<<1216, 256, 0, stream>>>(x_bf, wip_bf + (size_t)i * 2432 * 512,
                                                 nullptr, nullptr, xbc_in, z_bf,
                                                 nullptr, dt_raw, 8192, 2432, 512, 19);
        k_conv<<<8192, 320, 0, stream>>>(xbc_in, conv_w + (size_t)i * 1280 * 4,
                                         conv_b + (size_t)i * 1280, xhbf, bcbf);
        k_ssd<<<1024, 256, 0, stream>>>(xhbf, bcbf, dt_raw, dt_bias + i * 16,
                                        A_log + i * 16, elbuf, y, scbuf);
        k_states<<<128, 512, 0, stream>>>(scbuf, elbuf);
        k_inter<<<1024, 256, 0, stream>>>(xhbf, bcbf, elbuf, scbuf,
                                          Dparam + (size_t)i * 16, y);
        k_gate<<<8192, 256, 0, stream>>>(y, z_bf, norm_w + (size_t)i * 1024, y_bf);
        // x = (x + y @ out_proj_w[i]^T) * mask ; x_bf mirror
        k_gemm_mfma<2><<<256, 256, 0, stream>>>(y_bf, wop_bf + (size_t)i * 512 * 1024,
                                                nullptr, x, x_bf, nullptr, mask,
                                                nullptr, 8192, 512, 1024, 4);
    }

    k_pool1<<<512, 256, 0, stream>>>(x, psum, pmax);
    k_pool2<<<16, 256, 0, stream>>>(psum, pmax, pooled);
    k_fc<1><<<64, 64, 0, stream>>>(pooled, pooler_w, pooler_b, pbuf, 8 * 512, 512, 512);
    k_fc<1><<<32, 64, 0, stream>>>(pbuf, cls_w1, cls_b1, cbuf, 8 * 256, 256, 512);
    k_fc<0><<<1, 64, 0, stream>>>(cbuf, cls_w2, cls_b2, out, 8 * 2, 2, 256);
}